// Round 11
// baseline (495.361 us; speedup 1.0000x reference)
//
#include <hip/hip_runtime.h>
#include <cstdint>
#include <cstddef>

typedef unsigned short u16;
typedef unsigned int u32;
typedef __attribute__((ext_vector_type(8))) short shortx8;
typedef __attribute__((ext_vector_type(4))) float floatx4;

__device__ __forceinline__ u16 f2b(float f) {
    u32 b = __float_as_uint(f);
    b += 0x7fffu + ((b >> 16) & 1u);   // RNE
    return (u16)(b >> 16);
}
__device__ __forceinline__ float b2f(u16 u) {
    return __uint_as_float(((u32)u) << 16);
}

// ================= u-precompute: u31 = W31@Wr3[0:64], u32 = W32@Wr3[64:128], c3 =================
__global__ void uprep(const float* __restrict__ W31, const float* __restrict__ W32,
                      const float* __restrict__ b31, const float* __restrict__ b32,
                      const float* __restrict__ Wr3, const float* __restrict__ br3,
                      float* __restrict__ u31, float* __restrict__ u32, float* __restrict__ c3) {
    __shared__ float s[64];
    int t = threadIdx.x;
    if (t < 128) {
        float a = 0.f, b = 0.f;
        for (int c = 0; c < 64; ++c) {
            a = fmaf(W31[t * 64 + c], Wr3[c], a);
            b = fmaf(W32[t * 64 + c], Wr3[64 + c], b);
        }
        u31[t] = a;
        u32[t] = b;
    }
    if (t < 64) s[t] = b31[t] * Wr3[t] + b32[t] * Wr3[64 + t];
    __syncthreads();
    if (t < 32) s[t] += s[t + 32];
    __syncthreads();
    if (t == 0) {
        float acc = 0.f;
        for (int i = 0; i < 32; ++i) acc += s[i];
        c3[0] = acc + br3[0];
    }
}

// ================= CSR build — LDS atomics only (global atomics write through HBM @~25G/s) =======
// hist: grid = 4 ranges x 128 slices. Block (rid,s): packed u32 LDS histogram (2 bins/word)
// of its 25600-bin range over edge-slice s; writes per-(slice,bin) u16 counts to priv.
__global__ __launch_bounds__(256) void hist(const int* __restrict__ c1, const int* __restrict__ c2,
                                            u16* __restrict__ priv, int N, int E1, int E2) {
    __shared__ u32 h[12800];
    int b = blockIdx.x;
    int rid = b >> 7;          // 0..3
    int s = b & 127;
    int set2 = rid >> 1;
    int lo = (rid & 1) * 25600;
    const int* col = set2 ? c2 : c1;
    int E = set2 ? E2 : E1;
    int hi = lo + 25600; if (hi > N) hi = N;
    if (lo >= hi) return;                         // uniform per block
    int nw = (hi - lo + 1) >> 1;
    for (int i = threadIdx.x; i < nw; i += 256) h[i] = 0;
    __syncthreads();
    int esz = (E + 127) >> 7;
    int e0 = s * esz, e1 = min(e0 + esz, E);
    for (int e = e0 + threadIdx.x; e < e1; e += 256) {
        int c = col[e];
        if (c >= lo && c < hi) {
            int off = c - lo;
            atomicAdd(&h[off >> 1], 1u << ((off & 1) << 4));
        }
    }
    __syncthreads();
    int N2 = 2 * N;
    u32* pout = (u32*)(priv + (size_t)s * N2 + set2 * N + lo);  // even offsets -> aligned
    for (int i = threadIdx.x; i < nw; i += 256) pout[i] = h[i];
}

// psum: per-bin exclusive prefix over the 128 slices (in place); also degc + dinv.
__global__ void psum(u16* __restrict__ priv, int* __restrict__ degc,
                     float* __restrict__ d1, float* __restrict__ d2, int N) {
    int i = blockIdx.x * blockDim.x + threadIdx.x;
    int N2 = 2 * N;
    if (i >= N2) return;
    u32 run = 0;
    for (int s = 0; s < 128; ++s) {
        size_t idx = (size_t)s * N2 + i;
        u16 v = priv[idx];
        priv[idx] = (u16)run;
        run += v;
    }
    degc[i] = (int)run;
    float vv = run > 0 ? rsqrtf((float)run) : 0.f;
    if (i < N) d1[i] = vv;
    else d2[i - N] = vv;
}

__global__ void scan1(const int* __restrict__ deg, int* __restrict__ partial, int n) {
    __shared__ int s[256];
    int i = blockIdx.x * 256 + threadIdx.x;
    s[threadIdx.x] = (i < n) ? deg[i] : 0;
    __syncthreads();
    for (int off = 128; off > 0; off >>= 1) {
        if (threadIdx.x < off) s[threadIdx.x] += s[threadIdx.x + off];
        __syncthreads();
    }
    if (threadIdx.x == 0) partial[blockIdx.x] = s[0];
}

__global__ void scan2(int* __restrict__ partial, int nb, int* __restrict__ starts, int n) {
    __shared__ int s[256];
    __shared__ int carry;
    int t = threadIdx.x;
    if (t == 0) carry = 0;
    __syncthreads();
    for (int c0 = 0; c0 < nb; c0 += 256) {
        int i = c0 + t;
        int v = (i < nb) ? partial[i] : 0;
        s[t] = v;
        __syncthreads();
        for (int off = 1; off < 256; off <<= 1) {
            int u = (t >= off) ? s[t - off] : 0;
            __syncthreads();
            s[t] += u;
            __syncthreads();
        }
        if (i < nb) partial[i] = carry + s[t] - v;   // exclusive
        __syncthreads();
        if (t == 255) carry += s[255];
        __syncthreads();
    }
    if (t == 0) starts[n] = carry;
}

__global__ void scan3(const int* __restrict__ deg, const int* __restrict__ partial,
                      int* __restrict__ starts, int n) {
    __shared__ int s[256];
    int i = blockIdx.x * 256 + threadIdx.x;
    int v = (i < n) ? deg[i] : 0;
    s[threadIdx.x] = v;
    __syncthreads();
    for (int off = 1; off < 256; off <<= 1) {
        int u = (threadIdx.x >= off) ? s[threadIdx.x - off] : 0;
        __syncthreads();
        s[threadIdx.x] += u;
        __syncthreads();
    }
    if (i < n) starts[i] = partial[blockIdx.x] + s[threadIdx.x] - v;
}

// fillr: one range (<=12544 bins) of one edge set; grid = 128 slices. LDS cursor from
// starts+priv prefix; LDS atomicAdd slot handout; zero global atomics. Launched per-range
// serially so the live csr write region (~1.6 MB) stays L2-resident.
__global__ __launch_bounds__(256) void fillr(const int* __restrict__ rows,
                                             const int* __restrict__ cols,
                                             const float* __restrict__ dinv,
                                             const int* __restrict__ starts,
                                             const u16* __restrict__ priv,
                                             int2* __restrict__ csr,
                                             int N2, int gbase, int lo, int nbins, int E) {
    __shared__ u32 cur[12544];
    int s = blockIdx.x;
    for (int i = threadIdx.x; i < nbins; i += 256)
        cur[i] = (u32)starts[gbase + i] + (u32)priv[(size_t)s * N2 + gbase + i];
    __syncthreads();
    int esz = (E + 127) >> 7;
    int e0 = s * esz, e1 = min(e0 + esz, E);
    int hi = lo + nbins;
    for (int e = e0 + threadIdx.x; e < e1; e += 256) {
        int c = cols[e];
        if (c >= lo && c < hi) {
            int r = rows[e];
            u32 pos = atomicAdd(&cur[c - lo], 1u);
            csr[pos] = make_int2(r, __float_as_int(dinv[r] * dinv[c]));
        }
    }
}

// ================= mm_in: R0 = relu(x@W_in + b_in); fused readout0 + outacc init (fp32) ==========
__global__ __launch_bounds__(256) void mm_in(const float* __restrict__ A, const float* __restrict__ W,
                                             const float* __restrict__ bias, float* __restrict__ C,
                                             const float* __restrict__ Wr0, const float* __restrict__ br0,
                                             const float* __restrict__ br1, const float* __restrict__ br2,
                                             const float* __restrict__ w0, const float* __restrict__ w1,
                                             const float* __restrict__ w2, const float* __restrict__ w3,
                                             const float* __restrict__ c3, float* __restrict__ outacc,
                                             int n) {
    __shared__ float As[64][68];
    __shared__ float Ws[64][68];
    const int tid = threadIdx.x;
    const int r0 = blockIdx.x * 64;

    for (int idx = tid; idx < 64 * 16; idx += 256) {
        int k = idx >> 4, cq = (idx & 15) * 4;
        *(float4*)&Ws[k][cq] = *(const float4*)&W[k * 64 + cq];
    }

    const int tr = (tid >> 4) * 4;
    const int tc = (tid & 15) * 4;
    float4 acc0 = {0,0,0,0}, acc1 = {0,0,0,0}, acc2 = {0,0,0,0}, acc3 = {0,0,0,0};

    __syncthreads();
#pragma unroll
    for (int it = 0; it < 4; ++it) {
        int r = (tid >> 4) + it * 16;
        int cq = (tid & 15) * 4;
        int gr = r0 + r;
        float4 v = {0,0,0,0};
        if (gr < n) v = *(const float4*)&A[(size_t)gr * 64 + cq];
        *(float4*)&As[r][cq] = v;
    }
    __syncthreads();
#pragma unroll
    for (int k = 0; k < 64; k += 4) {
        float4 a0 = *(const float4*)&As[tr + 0][k];
        float4 a1 = *(const float4*)&As[tr + 1][k];
        float4 a2 = *(const float4*)&As[tr + 2][k];
        float4 a3 = *(const float4*)&As[tr + 3][k];
        float4 b0 = *(const float4*)&Ws[k + 0][tc];
        float4 b1 = *(const float4*)&Ws[k + 1][tc];
        float4 b2 = *(const float4*)&Ws[k + 2][tc];
        float4 b3 = *(const float4*)&Ws[k + 3][tc];
#define DK(comp, B)                                                                   \
        acc0.x = fmaf(a0.comp, B.x, acc0.x); acc0.y = fmaf(a0.comp, B.y, acc0.y);     \
        acc0.z = fmaf(a0.comp, B.z, acc0.z); acc0.w = fmaf(a0.comp, B.w, acc0.w);     \
        acc1.x = fmaf(a1.comp, B.x, acc1.x); acc1.y = fmaf(a1.comp, B.y, acc1.y);     \
        acc1.z = fmaf(a1.comp, B.z, acc1.z); acc1.w = fmaf(a1.comp, B.w, acc1.w);     \
        acc2.x = fmaf(a2.comp, B.x, acc2.x); acc2.y = fmaf(a2.comp, B.y, acc2.y);     \
        acc2.z = fmaf(a2.comp, B.z, acc2.z); acc2.w = fmaf(a2.comp, B.w, acc2.w);     \
        acc3.x = fmaf(a3.comp, B.x, acc3.x); acc3.y = fmaf(a3.comp, B.y, acc3.y);     \
        acc3.z = fmaf(a3.comp, B.z, acc3.z); acc3.w = fmaf(a3.comp, B.w, acc3.w);
        DK(x, b0) DK(y, b1) DK(z, b2) DK(w, b3)
#undef DK
    }

    float4 bv = *(const float4*)&bias[tc];
    float4 wr = *(const float4*)&Wr0[tc];
    float4 accs[4] = {acc0, acc1, acc2, acc3};
    float part[4];
#pragma unroll
    for (int i = 0; i < 4; ++i) {
        float4 v = accs[i];
        v.x = fmaxf(v.x + bv.x, 0.f); v.y = fmaxf(v.y + bv.y, 0.f);
        v.z = fmaxf(v.z + bv.z, 0.f); v.w = fmaxf(v.w + bv.w, 0.f);
        int gr = r0 + tr + i;
        if (gr < n) *(float4*)&C[(size_t)gr * 64 + tc] = v;
        part[i] = v.x * wr.x + v.y * wr.y + v.z * wr.z + v.w * wr.w;
    }
#pragma unroll
    for (int off = 8; off > 0; off >>= 1) {
#pragma unroll
        for (int i = 0; i < 4; ++i) part[i] += __shfl_down(part[i], off);
    }
    if ((tid & 15) == 0) {
        float W0 = w0[0];
        float CONST = W0 * br0[0] + w1[0] * br1[0] + w2[0] * br2[0] + w3[0] * c3[0];
#pragma unroll
        for (int i = 0; i < 4; ++i) {
            int gr = r0 + tr + i;
            if (gr < n) outacc[gr] = W0 * part[i] + CONST;
        }
    }
}

// ================= mmfma: Y16[:, coff:coff+64] = bf16(A) @ bf16(W) via MFMA 16x16x32 ==============
template <int K>
__global__ __launch_bounds__(256) void mmfma(const float* __restrict__ A, const float* __restrict__ W,
                                             u16* __restrict__ Y16, int coff, int n) {
    constexpr int LDA = K + 8;
    __shared__ u16 As[64 * LDA];
    __shared__ u16 Wt[64 * LDA];          // Wt[n][k]
    const int tid = threadIdx.x;
    const int r0 = blockIdx.x * 64;

    for (int idx = tid; idx < 16 * K; idx += 256) {
        int r = idx / (K / 4);
        int qc = idx % (K / 4);
        int gr = r0 + r;
        float4 v = {0,0,0,0};
        if (gr < n) v = *(const float4*)&A[(size_t)gr * K + 4 * qc];
        ushort4 o = {f2b(v.x), f2b(v.y), f2b(v.z), f2b(v.w)};
        *(ushort4*)&As[r * LDA + 4 * qc] = o;
    }
    for (int idx = tid; idx < 16 * K; idx += 256) {
        int k = idx >> 4;
        int qc = idx & 15;
        float4 v = *(const float4*)&W[k * 64 + 4 * qc];
        Wt[(4*qc+0) * LDA + k] = f2b(v.x);
        Wt[(4*qc+1) * LDA + k] = f2b(v.y);
        Wt[(4*qc+2) * LDA + k] = f2b(v.z);
        Wt[(4*qc+3) * LDA + k] = f2b(v.w);
    }
    __syncthreads();

    const int wave = tid >> 6;
    const int lane = tid & 63;
    const int m = lane & 15;
    const int ko = (lane >> 4) * 8;
    floatx4 z4 = {0.f, 0.f, 0.f, 0.f};
    floatx4 acc[4] = {z4, z4, z4, z4};

#pragma unroll
    for (int kc = 0; kc < K; kc += 32) {
        shortx8 af = *(shortx8*)&As[(wave * 16 + m) * LDA + kc + ko];
#pragma unroll
        for (int nt = 0; nt < 4; ++nt) {
            shortx8 bf = *(shortx8*)&Wt[(nt * 16 + m) * LDA + kc + ko];
            acc[nt] = __builtin_amdgcn_mfma_f32_16x16x32_bf16(af, bf, acc[nt], 0, 0, 0);
        }
    }

    const int rbase = r0 + wave * 16 + (lane >> 4) * 4;
#pragma unroll
    for (int nt = 0; nt < 4; ++nt) {
#pragma unroll
        for (int rg = 0; rg < 4; ++rg) {
            int gr = rbase + rg;
            if (gr < n) Y16[(size_t)gr * 128 + coff + nt * 16 + m] = f2b(acc[nt][rg]);
        }
    }
}

// ================= gather + fused readout (+ optional z-projection, optional dest store) ==========
template <bool STORE, bool ZCOMP>
__global__ __launch_bounds__(256) void gatherRO(const int* __restrict__ starts,
                                                const int2* __restrict__ csr,
                                                const u16* __restrict__ Y16,
                                                const float* __restrict__ bA,
                                                const float* __restrict__ bB,
                                                float* __restrict__ dest,
                                                const float* __restrict__ Wr,
                                                const float* __restrict__ wl,
                                                const float* __restrict__ u31,
                                                const float* __restrict__ u32v,
                                                const float* __restrict__ w3,
                                                float* __restrict__ z1,
                                                float* __restrict__ z2,
                                                float* __restrict__ outacc, int N) {
    int wave = (blockIdx.x * blockDim.x + threadIdx.x) >> 6;
    int lane = threadIdx.x & 63;
    if (wave >= 2 * N) return;
    int set2 = wave >= N;
    int d = set2 ? wave - N : wave;
    int base = set2 ? N : 0;
    int yoff = set2 ? 64 : 0;
    int q = lane >> 4;
    int m = lane & 15;

    int s0 = __builtin_amdgcn_readfirstlane(starts[base + d]);
    int s1 = __builtin_amdgcn_readfirstlane(starts[base + d + 1]);

    float a0 = 0.f, a1 = 0.f, a2 = 0.f, a3 = 0.f;
    int j = s0;
    for (; j + 8 <= s1; j += 8) {
        int2 e0 = csr[j + q];
        int2 e1 = csr[j + 4 + q];
        uint2 ya = *(const uint2*)&Y16[(size_t)e0.x * 128 + yoff + 4 * m];
        uint2 yb = *(const uint2*)&Y16[(size_t)e1.x * 128 + yoff + 4 * m];
        float w0 = __int_as_float(e0.y), w1 = __int_as_float(e1.y);
        a0 = fmaf(w0, b2f((u16)ya.x), a0); a1 = fmaf(w0, b2f((u16)(ya.x >> 16)), a1);
        a2 = fmaf(w0, b2f((u16)ya.y), a2); a3 = fmaf(w0, b2f((u16)(ya.y >> 16)), a3);
        a0 = fmaf(w1, b2f((u16)yb.x), a0); a1 = fmaf(w1, b2f((u16)(yb.x >> 16)), a1);
        a2 = fmaf(w1, b2f((u16)yb.y), a2); a3 = fmaf(w1, b2f((u16)(yb.y >> 16)), a3);
    }
    if (j + 4 <= s1) {
        int2 e = csr[j + q];
        uint2 y = *(const uint2*)&Y16[(size_t)e.x * 128 + yoff + 4 * m];
        float w = __int_as_float(e.y);
        a0 = fmaf(w, b2f((u16)y.x), a0); a1 = fmaf(w, b2f((u16)(y.x >> 16)), a1);
        a2 = fmaf(w, b2f((u16)y.y), a2); a3 = fmaf(w, b2f((u16)(y.y >> 16)), a3);
        j += 4;
    }
    if (j + q < s1) {
        int2 e = csr[j + q];
        uint2 y = *(const uint2*)&Y16[(size_t)e.x * 128 + yoff + 4 * m];
        float w = __int_as_float(e.y);
        a0 = fmaf(w, b2f((u16)y.x), a0); a1 = fmaf(w, b2f((u16)(y.x >> 16)), a1);
        a2 = fmaf(w, b2f((u16)y.y), a2); a3 = fmaf(w, b2f((u16)(y.y >> 16)), a3);
    }
    a0 += __shfl_down(a0, 32); a1 += __shfl_down(a1, 32);
    a2 += __shfl_down(a2, 32); a3 += __shfl_down(a3, 32);
    a0 += __shfl_down(a0, 16); a1 += __shfl_down(a1, 16);
    a2 += __shfl_down(a2, 16); a3 += __shfl_down(a3, 16);

    if (q == 0) {
        float4 bv = *(const float4*)&(set2 ? bB : bA)[4 * m];
        float v0 = a0 + bv.x, v1 = a1 + bv.y, v2 = a2 + bv.z, v3 = a3 + bv.w;
        if (STORE) {
            float4 o = {v0, v1, v2, v3};
            *(float4*)&dest[(size_t)d * 128 + yoff + 4 * m] = o;
        }
        float4 wr = *(const float4*)&Wr[yoff + 4 * m];
        float p = v0 * wr.x + v1 * wr.y + v2 * wr.z + v3 * wr.w;
        float p1 = 0.f, p2 = 0.f;
        if (ZCOMP) {
            float4 ua = *(const float4*)&u31[yoff + 4 * m];
            float4 ub = *(const float4*)&u32v[yoff + 4 * m];
            p1 = v0 * ua.x + v1 * ua.y + v2 * ua.z + v3 * ua.w;
            p2 = v0 * ub.x + v1 * ub.y + v2 * ub.z + v3 * ub.w;
        }
#pragma unroll
        for (int off = 8; off > 0; off >>= 1) {
            p += __shfl_down(p, off);
            if (ZCOMP) { p1 += __shfl_down(p1, off); p2 += __shfl_down(p2, off); }
        }
        if (m == 0) {
            atomicAdd(&outacc[d], wl[0] * p);
            if (ZCOMP) {
                float W3 = w3[0];
                atomicAdd(&z1[d], W3 * p1);
                atomicAdd(&z2[d], W3 * p2);
            }
        }
    }
}

// ================= gather3: out[d] = outacc[d] + sum_e1 wt*z1[src] + sum_e2 wt*z2[src] ============
__global__ __launch_bounds__(256) void gather3(const int* __restrict__ starts,
                                               const int2* __restrict__ csr,
                                               const float* __restrict__ z1,
                                               const float* __restrict__ z2,
                                               const float* __restrict__ outacc,
                                               float* __restrict__ out, int N) {
    int d = (blockIdx.x * blockDim.x + threadIdx.x) >> 6;
    int lane = threadIdx.x & 63;
    if (d >= N) return;
    int a0 = __builtin_amdgcn_readfirstlane(starts[d]);
    int a1 = __builtin_amdgcn_readfirstlane(starts[d + 1]);
    int b0 = __builtin_amdgcn_readfirstlane(starts[N + d]);
    int b1 = __builtin_amdgcn_readfirstlane(starts[N + d + 1]);
    float acc = 0.f;
    for (int j = a0 + lane; j < a1; j += 64) {
        int2 e = csr[j];
        acc = fmaf(__int_as_float(e.y), z1[e.x], acc);
    }
    for (int j = b0 + lane; j < b1; j += 64) {
        int2 e = csr[j];
        acc = fmaf(__int_as_float(e.y), z2[e.x], acc);
    }
#pragma unroll
    for (int off = 32; off > 0; off >>= 1) acc += __shfl_down(acc, off);
    if (lane == 0) out[d] = outacc[d] + acc;
}

// ================= host =================
static inline char* carve(char*& p, size_t bytes) {
    char* r = p;
    p += (bytes + 255) & ~(size_t)255;
    return r;
}

extern "C" void kernel_launch(void* const* d_in, const int* in_sizes, int n_in,
                              void* d_out, int out_size, void* d_ws, size_t ws_size,
                              hipStream_t stream) {
    const float* x    = (const float*)d_in[0];
    const int*   ei1  = (const int*)d_in[1];
    const int*   ei2  = (const int*)d_in[2];
    const float* W_in = (const float*)d_in[3];  const float* b_in = (const float*)d_in[4];
    const float* W11  = (const float*)d_in[5];
    const float* b11  = (const float*)d_in[6];
    const float* W12  = (const float*)d_in[7];  const float* b12  = (const float*)d_in[8];
    const float* W21  = (const float*)d_in[9];  const float* b21  = (const float*)d_in[10];
    const float* W22  = (const float*)d_in[11]; const float* b22  = (const float*)d_in[12];
    const float* W31  = (const float*)d_in[13]; const float* b31  = (const float*)d_in[14];
    const float* W32  = (const float*)d_in[15]; const float* b32  = (const float*)d_in[16];
    const float* Wr0  = (const float*)d_in[17]; const float* br0  = (const float*)d_in[18];
    const float* Wr1  = (const float*)d_in[19]; const float* br1  = (const float*)d_in[20];
    const float* Wr2  = (const float*)d_in[21]; const float* br2  = (const float*)d_in[22];
    const float* Wr3  = (const float*)d_in[23]; const float* br3  = (const float*)d_in[24];
    const float* w0   = (const float*)d_in[25];
    const float* w1   = (const float*)d_in[26];
    const float* w2   = (const float*)d_in[27];
    const float* w3   = (const float*)d_in[28];

    const int N  = in_sizes[0] / 64;   // 50000
    const int E1 = in_sizes[1] / 2;    // 800000
    const int E2 = in_sizes[2] / 2;
    const int N2 = 2 * N;

    char* p = (char*)d_ws;
    float* dinv1   = (float*)carve(p, (size_t)N * 4);
    float* dinv2   = (float*)carve(p, (size_t)N * 4);
    u16*   priv    = (u16*)  carve(p, (size_t)128 * N2 * 2);  // per-(slice,bin) counts/prefixes
    int*   degc    = (int*)  carve(p, (size_t)N2 * 4);
    int*   starts  = (int*)  carve(p, ((size_t)N2 + 1) * 4);
    int*   partial = (int*)  carve(p, 2048 * 4);
    float* uws     = (float*)carve(p, (128 + 128 + 1) * 4);   // u31, u32, c3
    float* z       = (float*)carve(p, (size_t)N2 * 4);        // z1 | z2
    int2*  csr     = (int2*) carve(p, (size_t)(E1 + E2) * 8);
    float* R0      = (float*)carve(p, (size_t)N * 64 * 4);
    float* P       = (float*)carve(p, (size_t)N * 128 * 4);
    u16*   Y16     = (u16*)  carve(p, (size_t)N * 128 * 2);
    float* outacc  = (float*)carve(p, (size_t)N * 4);
    float* u31 = uws, *u32v = uws + 128, *c3 = uws + 256;
    float* z1 = z, *z2 = z + N;
    (void)ws_size; (void)n_in; (void)out_size;

    const int B = 256;
    dim3 blk(B);
    int gN2  = (N2 + B - 1) / B;
    int gMM  = (N + 63) / 64;
    int gGa  = (int)(((long long)N2 * 64 + B - 1) / B);
    int gG3  = (int)(((long long)N * 64 + B - 1) / B);
    int nb   = (N2 + 255) / 256;

    // ---- CSR build (LDS-atomic counting sort) + u-precompute ----
    hipMemsetAsync(z, 0, (size_t)N2 * 4, stream);
    uprep<<<1, 128, 0, stream>>>(W31, W32, b31, b32, Wr3, br3, u31, u32v, c3);
    hist<<<4 * 128, blk, 0, stream>>>(ei1 + E1, ei2 + E2, priv, N, E1, E2);
    psum<<<gN2, blk, 0, stream>>>(priv, degc, dinv1, dinv2, N);
    scan1<<<nb, blk, 0, stream>>>(degc, partial, N2);
    scan2<<<1, 256, 0, stream>>>(partial, nb, starts, N2);
    scan3<<<nb, blk, 0, stream>>>(degc, partial, starts, N2);
    // 8 serialized range fills (4 per edge set), LDS cursors, csr region L2-resident
    int rb = (N + 3) / 4;                 // range size within a set (<= 12544 for N<=50176)
    for (int set = 0; set < 2; ++set) {
        const int* rows = set ? ei2 : ei1;
        const int* cols = set ? ei2 + E2 : ei1 + E1;
        const float* dv = set ? dinv2 : dinv1;
        int E = set ? E2 : E1;
        for (int rr = 0; rr < 4; ++rr) {
            int lo = rr * rb;
            int nbins = (lo + rb <= N) ? rb : (N - lo);
            if (nbins <= 0) continue;
            fillr<<<128, blk, 0, stream>>>(rows, cols, dv, starts, priv, csr,
                                           N2, set * N + lo, lo, nbins, E);
        }
    }

    // ---- R0 = relu(x @ W_in + b_in); outacc = w0*readout0 + CONST ----
    mm_in<<<gMM, blk, 0, stream>>>(x, W_in, b_in, R0, Wr0, br0, br1, br2,
                                   w0, w1, w2, w3, c3, outacc, N);

    // ---- layer 1: P = R1; readout1 fused ----
    mmfma<64><<<gMM, blk, 0, stream>>>(R0, W11, Y16, 0, N);
    mmfma<64><<<gMM, blk, 0, stream>>>(R0, W12, Y16, 64, N);
    gatherRO<true, false><<<gGa, blk, 0, stream>>>(starts, csr, Y16, b11, b12, P, Wr1, w1,
                                                   u31, u32v, w3, z1, z2, outacc, N);

    // ---- layer 2: Q never materialized; readout2 + z-projection fused ----
    mmfma<128><<<gMM, blk, 0, stream>>>(P, W21, Y16, 0, N);
    mmfma<128><<<gMM, blk, 0, stream>>>(P, W22, Y16, 64, N);
    gatherRO<false, true><<<gGa, blk, 0, stream>>>(starts, csr, Y16, b21, b22, nullptr, Wr2, w2,
                                                   u31, u32v, w3, z1, z2, outacc, N);

    // ---- layer 3 (algebraic shortcut): out = outacc + gather(z) ----
    gather3<<<gG3, blk, 0, stream>>>(starts, csr, z1, z2, outacc, (float*)d_out, N);
}

// Round 12
// 461.159 us; speedup vs baseline: 1.0742x; 1.0742x over previous
//
#include <hip/hip_runtime.h>
#include <cstdint>
#include <cstddef>

typedef unsigned short u16;
typedef unsigned int u32;
typedef __attribute__((ext_vector_type(8))) short shortx8;
typedef __attribute__((ext_vector_type(4))) float floatx4;

__device__ __forceinline__ u16 f2b(float f) {
    u32 b = __float_as_uint(f);
    b += 0x7fffu + ((b >> 16) & 1u);   // RNE
    return (u16)(b >> 16);
}
__device__ __forceinline__ float b2f(u16 u) {
    return __uint_as_float(((u32)u) << 16);
}

// ================= u-precompute =================
// u31 = W31@Wr3[0:64], u32 = W32@Wr3[64:128], c3 = b3-terms
// c2v = {b21·Wr2lo + b22·Wr2hi, b21·u31lo + b22·u31hi, b21·u32lo + b22·u32hi}
__global__ void uprep(const float* __restrict__ W31, const float* __restrict__ W32,
                      const float* __restrict__ b31, const float* __restrict__ b32,
                      const float* __restrict__ Wr3, const float* __restrict__ br3,
                      const float* __restrict__ Wr2, const float* __restrict__ b21,
                      const float* __restrict__ b22,
                      float* __restrict__ u31, float* __restrict__ u32,
                      float* __restrict__ c3, float* __restrict__ c2v) {
    __shared__ float s[64];
    int t = threadIdx.x;
    if (t < 128) {
        float a = 0.f, b = 0.f;
        for (int c = 0; c < 64; ++c) {
            a = fmaf(W31[t * 64 + c], Wr3[c], a);
            b = fmaf(W32[t * 64 + c], Wr3[64 + c], b);
        }
        u31[t] = a;
        u32[t] = b;
    }
    if (t < 64) s[t] = b31[t] * Wr3[t] + b32[t] * Wr3[64 + t];
    __syncthreads();
    if (t < 32) s[t] += s[t + 32];
    __syncthreads();
    if (t == 0) {
        float acc = 0.f;
        for (int i = 0; i < 32; ++i) acc += s[i];
        c3[0] = acc + br3[0];
    }
    __syncthreads();           // u31/u32 visible to all threads of block
    if (t < 64) {
        float t0 = b21[t] * Wr2[t] + b22[t] * Wr2[64 + t];
        float t1 = b21[t] * u31[t] + b22[t] * u31[64 + t];
        float t2 = b21[t] * u32[t] + b22[t] * u32[64 + t];
#pragma unroll
        for (int off = 32; off > 0; off >>= 1) {
            t0 += __shfl_down(t0, off);
            t1 += __shfl_down(t1, off);
            t2 += __shfl_down(t2, off);
        }
        if (t == 0) { c2v[0] = t0; c2v[1] = t1; c2v[2] = t2; }
    }
}

// ================= CSR build — LDS atomics only =================
__global__ __launch_bounds__(256) void hist(const int* __restrict__ c1, const int* __restrict__ c2,
                                            u16* __restrict__ priv, int N, int E1, int E2) {
    __shared__ u32 h[12800];
    int b = blockIdx.x;
    int rid = b >> 7;          // 0..3
    int s = b & 127;
    int set2 = rid >> 1;
    int lo = (rid & 1) * 25600;
    const int* col = set2 ? c2 : c1;
    int E = set2 ? E2 : E1;
    int hi = lo + 25600; if (hi > N) hi = N;
    if (lo >= hi) return;
    int nw = (hi - lo + 1) >> 1;
    for (int i = threadIdx.x; i < nw; i += 256) h[i] = 0;
    __syncthreads();
    int esz = (E + 127) >> 7;
    int e0 = s * esz, e1 = min(e0 + esz, E);
    for (int e = e0 + threadIdx.x; e < e1; e += 256) {
        int c = col[e];
        if (c >= lo && c < hi) {
            int off = c - lo;
            atomicAdd(&h[off >> 1], 1u << ((off & 1) << 4));
        }
    }
    __syncthreads();
    int N2 = 2 * N;
    u32* pout = (u32*)(priv + (size_t)s * N2 + set2 * N + lo);
    for (int i = threadIdx.x; i < nw; i += 256) pout[i] = h[i];
}

__global__ void psum(u16* __restrict__ priv, int* __restrict__ degc,
                     float* __restrict__ d1, float* __restrict__ d2, int N) {
    int i = blockIdx.x * blockDim.x + threadIdx.x;
    int N2 = 2 * N;
    if (i >= N2) return;
    u32 run = 0;
    for (int s = 0; s < 128; ++s) {
        size_t idx = (size_t)s * N2 + i;
        u16 v = priv[idx];
        priv[idx] = (u16)run;
        run += v;
    }
    degc[i] = (int)run;
    float vv = run > 0 ? rsqrtf((float)run) : 0.f;
    if (i < N) d1[i] = vv;
    else d2[i - N] = vv;
}

__global__ void scan1(const int* __restrict__ deg, int* __restrict__ partial, int n) {
    __shared__ int s[256];
    int i = blockIdx.x * 256 + threadIdx.x;
    s[threadIdx.x] = (i < n) ? deg[i] : 0;
    __syncthreads();
    for (int off = 128; off > 0; off >>= 1) {
        if (threadIdx.x < off) s[threadIdx.x] += s[threadIdx.x + off];
        __syncthreads();
    }
    if (threadIdx.x == 0) partial[blockIdx.x] = s[0];
}

__global__ void scan2(int* __restrict__ partial, int nb, int* __restrict__ starts, int n) {
    __shared__ int s[256];
    __shared__ int carry;
    int t = threadIdx.x;
    if (t == 0) carry = 0;
    __syncthreads();
    for (int c0 = 0; c0 < nb; c0 += 256) {
        int i = c0 + t;
        int v = (i < nb) ? partial[i] : 0;
        s[t] = v;
        __syncthreads();
        for (int off = 1; off < 256; off <<= 1) {
            int u = (t >= off) ? s[t - off] : 0;
            __syncthreads();
            s[t] += u;
            __syncthreads();
        }
        if (i < nb) partial[i] = carry + s[t] - v;   // exclusive
        __syncthreads();
        if (t == 255) carry += s[255];
        __syncthreads();
    }
    if (t == 0) starts[n] = carry;
}

__global__ void scan3(const int* __restrict__ deg, const int* __restrict__ partial,
                      int* __restrict__ starts, int n) {
    __shared__ int s[256];
    int i = blockIdx.x * 256 + threadIdx.x;
    int v = (i < n) ? deg[i] : 0;
    s[threadIdx.x] = v;
    __syncthreads();
    for (int off = 1; off < 256; off <<= 1) {
        int u = (threadIdx.x >= off) ? s[threadIdx.x - off] : 0;
        __syncthreads();
        s[threadIdx.x] += u;
        __syncthreads();
    }
    if (i < n) starts[i] = partial[blockIdx.x] + s[threadIdx.x] - v;
}

__global__ __launch_bounds__(256) void fillr(const int* __restrict__ rows,
                                             const int* __restrict__ cols,
                                             const float* __restrict__ dinv,
                                             const int* __restrict__ starts,
                                             const u16* __restrict__ priv,
                                             int2* __restrict__ csr,
                                             int N2, int gbase, int lo, int nbins, int E) {
    __shared__ u32 cur[12544];
    int s = blockIdx.x;
    for (int i = threadIdx.x; i < nbins; i += 256)
        cur[i] = (u32)starts[gbase + i] + (u32)priv[(size_t)s * N2 + gbase + i];
    __syncthreads();
    int esz = (E + 127) >> 7;
    int e0 = s * esz, e1 = min(e0 + esz, E);
    int hi = lo + nbins;
    for (int e = e0 + threadIdx.x; e < e1; e += 256) {
        int c = cols[e];
        if (c >= lo && c < hi) {
            int r = rows[e];
            u32 pos = atomicAdd(&cur[c - lo], 1u);
            csr[pos] = make_int2(r, __float_as_int(dinv[r] * dinv[c]));
        }
    }
}

// ================= mm_in: R016 = bf16(relu(x@W_in + b_in)); fused readout0 + outacc init =========
__global__ __launch_bounds__(256) void mm_in(const float* __restrict__ A, const float* __restrict__ W,
                                             const float* __restrict__ bias, u16* __restrict__ C16,
                                             const float* __restrict__ Wr0, const float* __restrict__ br0,
                                             const float* __restrict__ br1, const float* __restrict__ br2,
                                             const float* __restrict__ w0, const float* __restrict__ w1,
                                             const float* __restrict__ w2, const float* __restrict__ w3,
                                             const float* __restrict__ c3, float* __restrict__ outacc,
                                             int n) {
    __shared__ float As[64][68];
    __shared__ float Ws[64][68];
    const int tid = threadIdx.x;
    const int r0 = blockIdx.x * 64;

    for (int idx = tid; idx < 64 * 16; idx += 256) {
        int k = idx >> 4, cq = (idx & 15) * 4;
        *(float4*)&Ws[k][cq] = *(const float4*)&W[k * 64 + cq];
    }

    const int tr = (tid >> 4) * 4;
    const int tc = (tid & 15) * 4;
    float4 acc0 = {0,0,0,0}, acc1 = {0,0,0,0}, acc2 = {0,0,0,0}, acc3 = {0,0,0,0};

    __syncthreads();
#pragma unroll
    for (int it = 0; it < 4; ++it) {
        int r = (tid >> 4) + it * 16;
        int cq = (tid & 15) * 4;
        int gr = r0 + r;
        float4 v = {0,0,0,0};
        if (gr < n) v = *(const float4*)&A[(size_t)gr * 64 + cq];
        *(float4*)&As[r][cq] = v;
    }
    __syncthreads();
#pragma unroll
    for (int k = 0; k < 64; k += 4) {
        float4 a0 = *(const float4*)&As[tr + 0][k];
        float4 a1 = *(const float4*)&As[tr + 1][k];
        float4 a2 = *(const float4*)&As[tr + 2][k];
        float4 a3 = *(const float4*)&As[tr + 3][k];
        float4 b0 = *(const float4*)&Ws[k + 0][tc];
        float4 b1 = *(const float4*)&Ws[k + 1][tc];
        float4 b2 = *(const float4*)&Ws[k + 2][tc];
        float4 b3 = *(const float4*)&Ws[k + 3][tc];
#define DK(comp, B)                                                                   \
        acc0.x = fmaf(a0.comp, B.x, acc0.x); acc0.y = fmaf(a0.comp, B.y, acc0.y);     \
        acc0.z = fmaf(a0.comp, B.z, acc0.z); acc0.w = fmaf(a0.comp, B.w, acc0.w);     \
        acc1.x = fmaf(a1.comp, B.x, acc1.x); acc1.y = fmaf(a1.comp, B.y, acc1.y);     \
        acc1.z = fmaf(a1.comp, B.z, acc1.z); acc1.w = fmaf(a1.comp, B.w, acc1.w);     \
        acc2.x = fmaf(a2.comp, B.x, acc2.x); acc2.y = fmaf(a2.comp, B.y, acc2.y);     \
        acc2.z = fmaf(a2.comp, B.z, acc2.z); acc2.w = fmaf(a2.comp, B.w, acc2.w);     \
        acc3.x = fmaf(a3.comp, B.x, acc3.x); acc3.y = fmaf(a3.comp, B.y, acc3.y);     \
        acc3.z = fmaf(a3.comp, B.z, acc3.z); acc3.w = fmaf(a3.comp, B.w, acc3.w);
        DK(x, b0) DK(y, b1) DK(z, b2) DK(w, b3)
#undef DK
    }

    float4 bv = *(const float4*)&bias[tc];
    float4 wr = *(const float4*)&Wr0[tc];
    float4 accs[4] = {acc0, acc1, acc2, acc3};
    float part[4];
#pragma unroll
    for (int i = 0; i < 4; ++i) {
        float4 v = accs[i];
        v.x = fmaxf(v.x + bv.x, 0.f); v.y = fmaxf(v.y + bv.y, 0.f);
        v.z = fmaxf(v.z + bv.z, 0.f); v.w = fmaxf(v.w + bv.w, 0.f);
        int gr = r0 + tr + i;
        if (gr < n) {
            ushort4 o = {f2b(v.x), f2b(v.y), f2b(v.z), f2b(v.w)};
            *(ushort4*)&C16[(size_t)gr * 64 + tc] = o;
        }
        part[i] = v.x * wr.x + v.y * wr.y + v.z * wr.z + v.w * wr.w;
    }
#pragma unroll
    for (int off = 8; off > 0; off >>= 1) {
#pragma unroll
        for (int i = 0; i < 4; ++i) part[i] += __shfl_down(part[i], off);
    }
    if ((tid & 15) == 0) {
        float W0 = w0[0];
        float CONST = W0 * br0[0] + w1[0] * br1[0] + w2[0] * br2[0] + w3[0] * c3[0];
#pragma unroll
        for (int i = 0; i < 4; ++i) {
            int gr = r0 + tr + i;
            if (gr < n) outacc[gr] = W0 * part[i] + CONST;
        }
    }
}

// ================= mmfma2: Y16[:,0:64] = A16@WA, Y16[:,64:128] = A16@WB (MFMA, paired) ============
// A16 is bf16 with row stride K. MFMA accumulators keep VGPR low (vs R5's FMA-pair spill).
template <int K>
__global__ __launch_bounds__(256) void mmfma2(const u16* __restrict__ A16,
                                              const float* __restrict__ WA,
                                              const float* __restrict__ WB,
                                              u16* __restrict__ Y16, int n) {
    constexpr int LDA = K + 8;
    __shared__ u16 As[64 * LDA];
    __shared__ u16 WtA[64 * LDA];
    __shared__ u16 WtB[64 * LDA];
    const int tid = threadIdx.x;
    const int r0 = blockIdx.x * 64;

    for (int idx = tid; idx < 64 * K / 8; idx += 256) {
        int r = idx / (K / 8), c8 = idx % (K / 8);
        int gr = r0 + r;
        uint4 v = {0, 0, 0, 0};
        if (gr < n) v = *(const uint4*)&A16[(size_t)gr * K + 8 * c8];
        *(uint4*)&As[r * LDA + 8 * c8] = v;
    }
    for (int idx = tid; idx < 16 * K; idx += 256) {
        int k = idx >> 4;
        int qc = idx & 15;
        float4 a = *(const float4*)&WA[k * 64 + 4 * qc];
        float4 b = *(const float4*)&WB[k * 64 + 4 * qc];
        WtA[(4*qc+0) * LDA + k] = f2b(a.x);
        WtA[(4*qc+1) * LDA + k] = f2b(a.y);
        WtA[(4*qc+2) * LDA + k] = f2b(a.z);
        WtA[(4*qc+3) * LDA + k] = f2b(a.w);
        WtB[(4*qc+0) * LDA + k] = f2b(b.x);
        WtB[(4*qc+1) * LDA + k] = f2b(b.y);
        WtB[(4*qc+2) * LDA + k] = f2b(b.z);
        WtB[(4*qc+3) * LDA + k] = f2b(b.w);
    }
    __syncthreads();

    const int wave = tid >> 6;
    const int lane = tid & 63;
    const int m = lane & 15;
    const int ko = (lane >> 4) * 8;
    floatx4 z4 = {0.f, 0.f, 0.f, 0.f};
    floatx4 accA[4] = {z4, z4, z4, z4};
    floatx4 accB[4] = {z4, z4, z4, z4};

#pragma unroll
    for (int kc = 0; kc < K; kc += 32) {
        shortx8 af = *(shortx8*)&As[(wave * 16 + m) * LDA + kc + ko];
#pragma unroll
        for (int nt = 0; nt < 4; ++nt) {
            shortx8 ba = *(shortx8*)&WtA[(nt * 16 + m) * LDA + kc + ko];
            accA[nt] = __builtin_amdgcn_mfma_f32_16x16x32_bf16(af, ba, accA[nt], 0, 0, 0);
            shortx8 bb = *(shortx8*)&WtB[(nt * 16 + m) * LDA + kc + ko];
            accB[nt] = __builtin_amdgcn_mfma_f32_16x16x32_bf16(af, bb, accB[nt], 0, 0, 0);
        }
    }

    const int rbase = r0 + wave * 16 + (lane >> 4) * 4;
#pragma unroll
    for (int nt = 0; nt < 4; ++nt) {
#pragma unroll
        for (int rg = 0; rg < 4; ++rg) {
            int gr = rbase + rg;
            if (gr < n) {
                Y16[(size_t)gr * 128 + nt * 16 + m] = f2b(accA[nt][rg]);
                Y16[(size_t)gr * 128 + 64 + nt * 16 + m] = f2b(accB[nt][rg]);
            }
        }
    }
}

// ================= layer-1 gather: P16 = bf16(R1); readout1 partials to pr1/pr2 (plain stores) ====
__global__ __launch_bounds__(256) void gatherRO(const int* __restrict__ starts,
                                                const int2* __restrict__ csr,
                                                const u16* __restrict__ Y16,
                                                const float* __restrict__ bA,
                                                const float* __restrict__ bB,
                                                u16* __restrict__ P16,
                                                const float* __restrict__ Wr,
                                                float* __restrict__ pr1,
                                                float* __restrict__ pr2, int N) {
    int wave = (blockIdx.x * blockDim.x + threadIdx.x) >> 6;
    int lane = threadIdx.x & 63;
    if (wave >= 2 * N) return;
    int set2 = wave >= N;
    int d = set2 ? wave - N : wave;
    int base = set2 ? N : 0;
    int yoff = set2 ? 64 : 0;
    int q = lane >> 4;
    int m = lane & 15;

    int s0 = __builtin_amdgcn_readfirstlane(starts[base + d]);
    int s1 = __builtin_amdgcn_readfirstlane(starts[base + d + 1]);

    float a0 = 0.f, a1 = 0.f, a2 = 0.f, a3 = 0.f;
    int j = s0;
    for (; j + 8 <= s1; j += 8) {
        int2 e0 = csr[j + q];
        int2 e1 = csr[j + 4 + q];
        uint2 ya = *(const uint2*)&Y16[(size_t)e0.x * 128 + yoff + 4 * m];
        uint2 yb = *(const uint2*)&Y16[(size_t)e1.x * 128 + yoff + 4 * m];
        float w0 = __int_as_float(e0.y), w1 = __int_as_float(e1.y);
        a0 = fmaf(w0, b2f((u16)ya.x), a0); a1 = fmaf(w0, b2f((u16)(ya.x >> 16)), a1);
        a2 = fmaf(w0, b2f((u16)ya.y), a2); a3 = fmaf(w0, b2f((u16)(ya.y >> 16)), a3);
        a0 = fmaf(w1, b2f((u16)yb.x), a0); a1 = fmaf(w1, b2f((u16)(yb.x >> 16)), a1);
        a2 = fmaf(w1, b2f((u16)yb.y), a2); a3 = fmaf(w1, b2f((u16)(yb.y >> 16)), a3);
    }
    if (j + 4 <= s1) {
        int2 e = csr[j + q];
        uint2 y = *(const uint2*)&Y16[(size_t)e.x * 128 + yoff + 4 * m];
        float w = __int_as_float(e.y);
        a0 = fmaf(w, b2f((u16)y.x), a0); a1 = fmaf(w, b2f((u16)(y.x >> 16)), a1);
        a2 = fmaf(w, b2f((u16)y.y), a2); a3 = fmaf(w, b2f((u16)(y.y >> 16)), a3);
        j += 4;
    }
    if (j + q < s1) {
        int2 e = csr[j + q];
        uint2 y = *(const uint2*)&Y16[(size_t)e.x * 128 + yoff + 4 * m];
        float w = __int_as_float(e.y);
        a0 = fmaf(w, b2f((u16)y.x), a0); a1 = fmaf(w, b2f((u16)(y.x >> 16)), a1);
        a2 = fmaf(w, b2f((u16)y.y), a2); a3 = fmaf(w, b2f((u16)(y.y >> 16)), a3);
    }
    a0 += __shfl_down(a0, 32); a1 += __shfl_down(a1, 32);
    a2 += __shfl_down(a2, 32); a3 += __shfl_down(a3, 32);
    a0 += __shfl_down(a0, 16); a1 += __shfl_down(a1, 16);
    a2 += __shfl_down(a2, 16); a3 += __shfl_down(a3, 16);

    if (q == 0) {
        float4 bv = *(const float4*)&(set2 ? bB : bA)[4 * m];
        float v0 = a0 + bv.x, v1 = a1 + bv.y, v2 = a2 + bv.z, v3 = a3 + bv.w;
        ushort4 o = {f2b(v0), f2b(v1), f2b(v2), f2b(v3)};
        *(ushort4*)&P16[(size_t)d * 128 + yoff + 4 * m] = o;
        float4 wr = *(const float4*)&Wr[yoff + 4 * m];
        float p = v0 * wr.x + v1 * wr.y + v2 * wr.z + v3 * wr.w;
#pragma unroll
        for (int off = 8; off > 0; off >>= 1) p += __shfl_down(p, off);
        if (m == 0) {
            if (set2) pr2[d] = p;
            else pr1[d] = p;
        }
    }
}

// ================= proj2: per-source scalar projections of Y2 =================
// sA[i] = {Y2[i,0:64]·Wr2lo, ·u31lo, ·u32lo}, sB[i] = same over cols 64:128 with hi halves.
__global__ __launch_bounds__(256) void proj2(const u16* __restrict__ Y16,
                                             const float* __restrict__ Wr2,
                                             const float* __restrict__ u31,
                                             const float* __restrict__ u32v,
                                             float4* __restrict__ sA, float4* __restrict__ sB, int N) {
    int i = (blockIdx.x * blockDim.x + threadIdx.x) >> 6;
    int lane = threadIdx.x & 63;
    if (i >= N) return;
    u32 y = *(const u32*)&Y16[(size_t)i * 128 + 2 * lane];
    float y0 = b2f((u16)y), y1 = b2f((u16)(y >> 16));
    int c0 = 2 * lane, c1 = 2 * lane + 1;
    float p  = y0 * Wr2[c0]  + y1 * Wr2[c1];
    float q1 = y0 * u31[c0]  + y1 * u31[c1];
    float q2 = y0 * u32v[c0] + y1 * u32v[c1];
#pragma unroll
    for (int off = 16; off > 0; off >>= 1) {   // xor network stays within 32-lane halves
        p  += __shfl_xor(p, off);
        q1 += __shfl_xor(q1, off);
        q2 += __shfl_xor(q2, off);
    }
    if (lane == 0)  sA[i] = make_float4(p, q1, q2, 0.f);
    if (lane == 32) sB[i] = make_float4(p, q1, q2, 0.f);
}

// ================= gatherS: scalar aggregation for readout2 + z; exclusive dest => no atomics =====
__global__ __launch_bounds__(256) void gatherS(const int* __restrict__ starts,
                                               const int2* __restrict__ csr,
                                               const float4* __restrict__ sA,
                                               const float4* __restrict__ sB,
                                               const float* __restrict__ pr1,
                                               const float* __restrict__ pr2,
                                               const float* __restrict__ w1,
                                               const float* __restrict__ w2,
                                               const float* __restrict__ w3,
                                               const float* __restrict__ c2v,
                                               float* __restrict__ outacc,
                                               float* __restrict__ z1, float* __restrict__ z2, int N) {
    int d = (blockIdx.x * blockDim.x + threadIdx.x) >> 6;
    int lane = threadIdx.x & 63;
    if (d >= N) return;
    int a0 = __builtin_amdgcn_readfirstlane(starts[d]);
    int a1 = __builtin_amdgcn_readfirstlane(starts[d + 1]);
    int b0 = __builtin_amdgcn_readfirstlane(starts[N + d]);
    int b1 = __builtin_amdgcn_readfirstlane(starts[N + d + 1]);
    float p = 0.f, q1 = 0.f, q2 = 0.f;
    for (int j = a0 + lane; j < a1; j += 64) {
        int2 e = csr[j];
        float4 s = sA[e.x];
        float w = __int_as_float(e.y);
        p = fmaf(w, s.x, p); q1 = fmaf(w, s.y, q1); q2 = fmaf(w, s.z, q2);
    }
    for (int j = b0 + lane; j < b1; j += 64) {
        int2 e = csr[j];
        float4 s = sB[e.x];
        float w = __int_as_float(e.y);
        p = fmaf(w, s.x, p); q1 = fmaf(w, s.y, q1); q2 = fmaf(w, s.z, q2);
    }
#pragma unroll
    for (int off = 32; off > 0; off >>= 1) {
        p += __shfl_down(p, off);
        q1 += __shfl_down(q1, off);
        q2 += __shfl_down(q2, off);
    }
    if (lane == 0) {
        float W3 = w3[0];
        outacc[d] += w1[0] * (pr1[d] + pr2[d]) + w2[0] * (p + c2v[0]);
        z1[d] = W3 * (q1 + c2v[1]);
        z2[d] = W3 * (q2 + c2v[2]);
    }
}

// ================= gather3: out[d] = outacc[d] + sum_e1 wt*z1[src] + sum_e2 wt*z2[src] ============
__global__ __launch_bounds__(256) void gather3(const int* __restrict__ starts,
                                               const int2* __restrict__ csr,
                                               const float* __restrict__ z1,
                                               const float* __restrict__ z2,
                                               const float* __restrict__ outacc,
                                               float* __restrict__ out, int N) {
    int d = (blockIdx.x * blockDim.x + threadIdx.x) >> 6;
    int lane = threadIdx.x & 63;
    if (d >= N) return;
    int a0 = __builtin_amdgcn_readfirstlane(starts[d]);
    int a1 = __builtin_amdgcn_readfirstlane(starts[d + 1]);
    int b0 = __builtin_amdgcn_readfirstlane(starts[N + d]);
    int b1 = __builtin_amdgcn_readfirstlane(starts[N + d + 1]);
    float acc = 0.f;
    for (int j = a0 + lane; j < a1; j += 64) {
        int2 e = csr[j];
        acc = fmaf(__int_as_float(e.y), z1[e.x], acc);
    }
    for (int j = b0 + lane; j < b1; j += 64) {
        int2 e = csr[j];
        acc = fmaf(__int_as_float(e.y), z2[e.x], acc);
    }
#pragma unroll
    for (int off = 32; off > 0; off >>= 1) acc += __shfl_down(acc, off);
    if (lane == 0) out[d] = outacc[d] + acc;
}

// ================= host =================
static inline char* carve(char*& p, size_t bytes) {
    char* r = p;
    p += (bytes + 255) & ~(size_t)255;
    return r;
}

extern "C" void kernel_launch(void* const* d_in, const int* in_sizes, int n_in,
                              void* d_out, int out_size, void* d_ws, size_t ws_size,
                              hipStream_t stream) {
    const float* x    = (const float*)d_in[0];
    const int*   ei1  = (const int*)d_in[1];
    const int*   ei2  = (const int*)d_in[2];
    const float* W_in = (const float*)d_in[3];  const float* b_in = (const float*)d_in[4];
    const float* W11  = (const float*)d_in[5];
    const float* b11  = (const float*)d_in[6];
    const float* W12  = (const float*)d_in[7];  const float* b12  = (const float*)d_in[8];
    const float* W21  = (const float*)d_in[9];  const float* b21  = (const float*)d_in[10];
    const float* W22  = (const float*)d_in[11]; const float* b22  = (const float*)d_in[12];
    const float* W31  = (const float*)d_in[13]; const float* b31  = (const float*)d_in[14];
    const float* W32  = (const float*)d_in[15]; const float* b32  = (const float*)d_in[16];
    const float* Wr0  = (const float*)d_in[17]; const float* br0  = (const float*)d_in[18];
    const float* Wr1  = (const float*)d_in[19]; const float* br1  = (const float*)d_in[20];
    const float* Wr2  = (const float*)d_in[21]; const float* br2  = (const float*)d_in[22];
    const float* Wr3  = (const float*)d_in[23]; const float* br3  = (const float*)d_in[24];
    const float* w0   = (const float*)d_in[25];
    const float* w1   = (const float*)d_in[26];
    const float* w2   = (const float*)d_in[27];
    const float* w3   = (const float*)d_in[28];

    const int N  = in_sizes[0] / 64;   // 50000
    const int E1 = in_sizes[1] / 2;    // 800000
    const int E2 = in_sizes[2] / 2;
    const int N2 = 2 * N;

    char* p = (char*)d_ws;
    float*  dinv1   = (float*)carve(p, (size_t)N * 4);
    float*  dinv2   = (float*)carve(p, (size_t)N * 4);
    u16*    priv    = (u16*)  carve(p, (size_t)128 * N2 * 2);
    int*    degc    = (int*)  carve(p, (size_t)N2 * 4);
    int*    starts  = (int*)  carve(p, ((size_t)N2 + 1) * 4);
    int*    partial = (int*)  carve(p, 2048 * 4);
    float*  uws     = (float*)carve(p, 264 * 4);             // u31[128], u32[128], c3[1], c2v[3]
    float*  z       = (float*)carve(p, (size_t)N2 * 4);      // z1 | z2
    float*  pr      = (float*)carve(p, (size_t)N2 * 4);      // pr1 | pr2
    float4* sA      = (float4*)carve(p, (size_t)N * 16);
    float4* sB      = (float4*)carve(p, (size_t)N * 16);
    int2*   csr     = (int2*) carve(p, (size_t)(E1 + E2) * 8);
    u16*    R016    = (u16*)  carve(p, (size_t)N * 64 * 2);
    u16*    P16     = (u16*)  carve(p, (size_t)N * 128 * 2);
    u16*    Y16     = (u16*)  carve(p, (size_t)N * 128 * 2);
    float*  outacc  = (float*)carve(p, (size_t)N * 4);
    float* u31 = uws, *u32v = uws + 128, *c3 = uws + 256, *c2v = uws + 257;
    float* z1 = z, *z2 = z + N;
    float* pr1 = pr, *pr2 = pr + N;
    (void)ws_size; (void)n_in; (void)out_size;

    const int B = 256;
    dim3 blk(B);
    int gN2  = (N2 + B - 1) / B;
    int gMM  = (N + 63) / 64;
    int gGa  = (int)(((long long)N2 * 64 + B - 1) / B);
    int gG3  = (int)(((long long)N * 64 + B - 1) / B);
    int nb   = (N2 + 255) / 256;

    // ---- CSR build (LDS-atomic counting sort) + u-precompute ----
    uprep<<<1, 128, 0, stream>>>(W31, W32, b31, b32, Wr3, br3, Wr2, b21, b22,
                                 u31, u32v, c3, c2v);
    hist<<<4 * 128, blk, 0, stream>>>(ei1 + E1, ei2 + E2, priv, N, E1, E2);
    psum<<<gN2, blk, 0, stream>>>(priv, degc, dinv1, dinv2, N);
    scan1<<<nb, blk, 0, stream>>>(degc, partial, N2);
    scan2<<<1, 256, 0, stream>>>(partial, nb, starts, N2);
    scan3<<<nb, blk, 0, stream>>>(degc, partial, starts, N2);
    int rb = (N + 3) / 4;
    for (int set = 0; set < 2; ++set) {
        const int* rows = set ? ei2 : ei1;
        const int* cols = set ? ei2 + E2 : ei1 + E1;
        const float* dv = set ? dinv2 : dinv1;
        int E = set ? E2 : E1;
        for (int rr = 0; rr < 4; ++rr) {
            int lo = rr * rb;
            int nbins = (lo + rb <= N) ? rb : (N - lo);
            if (nbins <= 0) continue;
            fillr<<<128, blk, 0, stream>>>(rows, cols, dv, starts, priv, csr,
                                           N2, set * N + lo, lo, nbins, E);
        }
    }

    // ---- R016 = bf16(relu(x @ W_in + b_in)); outacc = w0*readout0 + CONST ----
    mm_in<<<gMM, blk, 0, stream>>>(x, W_in, b_in, R016, Wr0, br0, br1, br2,
                                   w0, w1, w2, w3, c3, outacc, N);

    // ---- layer 1: Y = R0@[W11|W12]; gather -> P16 (bf16 R1) + readout1 partials ----
    mmfma2<64><<<gMM, blk, 0, stream>>>(R016, W11, W12, Y16, N);
    gatherRO<<<gGa, blk, 0, stream>>>(starts, csr, Y16, b11, b12, P16, Wr1, pr1, pr2, N);

    // ---- layer 2: Y = P@[W21|W22]; scalarize (R2 never materialized) ----
    mmfma2<128><<<gMM, blk, 0, stream>>>(P16, W21, W22, Y16, N);
    proj2<<<gG3, blk, 0, stream>>>(Y16, Wr2, u31, u32v, sA, sB, N);
    gatherS<<<gG3, blk, 0, stream>>>(starts, csr, sA, sB, pr1, pr2, w1, w2, w3, c2v,
                                     outacc, z1, z2, N);

    // ---- layer 3 (algebraic shortcut): out = outacc + gather(z) ----
    gather3<<<gG3, blk, 0, stream>>>(starts, csr, z1, z2, outacc, (float*)d_out, N);
}

// Round 13
// 457.138 us; speedup vs baseline: 1.0836x; 1.0088x over previous
//
#include <hip/hip_runtime.h>
#include <cstdint>
#include <cstddef>

typedef unsigned short u16;
typedef unsigned int u32;
typedef __attribute__((ext_vector_type(8))) short shortx8;
typedef __attribute__((ext_vector_type(4))) float floatx4;

__device__ __forceinline__ u16 f2b(float f) {
    u32 b = __float_as_uint(f);
    b += 0x7fffu + ((b >> 16) & 1u);   // RNE
    return (u16)(b >> 16);
}
__device__ __forceinline__ float b2f(u16 u) {
    return __uint_as_float(((u32)u) << 16);
}

// ================= u-precompute =================
__global__ void uprep(const float* __restrict__ W31, const float* __restrict__ W32,
                      const float* __restrict__ b31, const float* __restrict__ b32,
                      const float* __restrict__ Wr3, const float* __restrict__ br3,
                      const float* __restrict__ Wr2, const float* __restrict__ b21,
                      const float* __restrict__ b22,
                      float* __restrict__ u31, float* __restrict__ u32,
                      float* __restrict__ c3, float* __restrict__ c2v) {
    __shared__ float s[64];
    int t = threadIdx.x;
    if (t < 128) {
        float a = 0.f, b = 0.f;
        for (int c = 0; c < 64; ++c) {
            a = fmaf(W31[t * 64 + c], Wr3[c], a);
            b = fmaf(W32[t * 64 + c], Wr3[64 + c], b);
        }
        u31[t] = a;
        u32[t] = b;
    }
    if (t < 64) s[t] = b31[t] * Wr3[t] + b32[t] * Wr3[64 + t];
    __syncthreads();
    if (t < 32) s[t] += s[t + 32];
    __syncthreads();
    if (t == 0) {
        float acc = 0.f;
        for (int i = 0; i < 32; ++i) acc += s[i];
        c3[0] = acc + br3[0];
    }
    __syncthreads();
    if (t < 64) {
        float t0 = b21[t] * Wr2[t] + b22[t] * Wr2[64 + t];
        float t1 = b21[t] * u31[t] + b22[t] * u31[64 + t];
        float t2 = b21[t] * u32[t] + b22[t] * u32[64 + t];
#pragma unroll
        for (int off = 32; off > 0; off >>= 1) {
            t0 += __shfl_down(t0, off);
            t1 += __shfl_down(t1, off);
            t2 += __shfl_down(t2, off);
        }
        if (t == 0) { c2v[0] = t0; c2v[1] = t1; c2v[2] = t2; }
    }
}

// ================= CSR build — LDS atomics, 64 slices =================
// grid = 4 ranges x 64 slices. priv[s][bin] u16 per-(slice,bin) counts.
__global__ __launch_bounds__(256) void hist(const int* __restrict__ c1, const int* __restrict__ c2,
                                            u16* __restrict__ priv, int N, int E1, int E2) {
    __shared__ u32 h[12800];
    int b = blockIdx.x;
    int rid = b >> 6;          // 0..3
    int s = b & 63;
    int set2 = rid >> 1;
    int lo = (rid & 1) * 25600;
    const int* col = set2 ? c2 : c1;
    int E = set2 ? E2 : E1;
    int hi = lo + 25600; if (hi > N) hi = N;
    if (lo >= hi) return;
    int nw = (hi - lo + 1) >> 1;
    for (int i = threadIdx.x; i < nw; i += 256) h[i] = 0;
    __syncthreads();
    int esz = (E + 63) >> 6;
    int e0 = s * esz, e1 = min(e0 + esz, E);
    for (int e = e0 + threadIdx.x; e < e1; e += 256) {
        int c = col[e];
        if (c >= lo && c < hi) {
            int off = c - lo;
            atomicAdd(&h[off >> 1], 1u << ((off & 1) << 4));
        }
    }
    __syncthreads();
    int N2 = 2 * N;
    u32* pout = (u32*)(priv + (size_t)s * N2 + set2 * N + lo);
    for (int i = threadIdx.x; i < nw; i += 256) pout[i] = h[i];
}

__global__ void psum(u16* __restrict__ priv, int* __restrict__ degc,
                     float* __restrict__ d1, float* __restrict__ d2, int N) {
    int i = blockIdx.x * blockDim.x + threadIdx.x;
    int N2 = 2 * N;
    if (i >= N2) return;
    u32 run = 0;
    for (int s = 0; s < 64; ++s) {
        size_t idx = (size_t)s * N2 + i;
        u16 v = priv[idx];
        priv[idx] = (u16)run;
        run += v;
    }
    degc[i] = (int)run;
    float vv = run > 0 ? rsqrtf((float)run) : 0.f;
    if (i < N) d1[i] = vv;
    else d2[i - N] = vv;
}

__global__ void scan1(const int* __restrict__ deg, int* __restrict__ partial, int n) {
    __shared__ int s[256];
    int i = blockIdx.x * 256 + threadIdx.x;
    s[threadIdx.x] = (i < n) ? deg[i] : 0;
    __syncthreads();
    for (int off = 128; off > 0; off >>= 1) {
        if (threadIdx.x < off) s[threadIdx.x] += s[threadIdx.x + off];
        __syncthreads();
    }
    if (threadIdx.x == 0) partial[blockIdx.x] = s[0];
}

__global__ void scan2(int* __restrict__ partial, int nb, int* __restrict__ starts, int n) {
    __shared__ int s[256];
    __shared__ int carry;
    int t = threadIdx.x;
    if (t == 0) carry = 0;
    __syncthreads();
    for (int c0 = 0; c0 < nb; c0 += 256) {
        int i = c0 + t;
        int v = (i < nb) ? partial[i] : 0;
        s[t] = v;
        __syncthreads();
        for (int off = 1; off < 256; off <<= 1) {
            int u = (t >= off) ? s[t - off] : 0;
            __syncthreads();
            s[t] += u;
            __syncthreads();
        }
        if (i < nb) partial[i] = carry + s[t] - v;   // exclusive
        __syncthreads();
        if (t == 255) carry += s[255];
        __syncthreads();
    }
    if (t == 0) starts[n] = carry;
}

__global__ void scan3(const int* __restrict__ deg, const int* __restrict__ partial,
                      int* __restrict__ starts, int n) {
    __shared__ int s[256];
    int i = blockIdx.x * 256 + threadIdx.x;
    int v = (i < n) ? deg[i] : 0;
    s[threadIdx.x] = v;
    __syncthreads();
    for (int off = 1; off < 256; off <<= 1) {
        int u = (threadIdx.x >= off) ? s[threadIdx.x - off] : 0;
        __syncthreads();
        s[threadIdx.x] += u;
        __syncthreads();
    }
    if (i < n) starts[i] = partial[blockIdx.x] + s[threadIdx.x] - v;
}

// fillr: one dest-range, BOTH sets; grid = 2 sets x 64 slices. LDS cursors, zero global atomics.
__global__ __launch_bounds__(256) void fillr(const int* __restrict__ ei1, const int* __restrict__ ei2,
                                             const float* __restrict__ dinv1, const float* __restrict__ dinv2,
                                             const int* __restrict__ starts, const u16* __restrict__ priv,
                                             int2* __restrict__ csr, int N, int N2,
                                             int lo, int nbins, int E1, int E2) {
    __shared__ u32 cur[12544];
    int set = blockIdx.x >> 6;
    int s = blockIdx.x & 63;
    const int* rows = set ? ei2 : ei1;
    int E = set ? E2 : E1;
    const int* cols = rows + E;
    const float* dinv = set ? dinv2 : dinv1;
    int gbase = set * N + lo;
    for (int i = threadIdx.x; i < nbins; i += 256)
        cur[i] = (u32)starts[gbase + i] + (u32)priv[(size_t)s * N2 + gbase + i];
    __syncthreads();
    int esz = (E + 63) >> 6;
    int e0 = s * esz, e1 = min(e0 + esz, E);
    int hi = lo + nbins;
    for (int e = e0 + threadIdx.x; e < e1; e += 256) {
        int c = cols[e];
        if (c >= lo && c < hi) {
            int r = rows[e];
            u32 pos = atomicAdd(&cur[c - lo], 1u);
            csr[pos] = make_int2(r, __float_as_int(dinv[r] * dinv[c]));
        }
    }
}

// ================= mm_in: R016 = bf16(relu(x@W_in + b_in)); fused readout0 + outacc init =========
__global__ __launch_bounds__(256) void mm_in(const float* __restrict__ A, const float* __restrict__ W,
                                             const float* __restrict__ bias, u16* __restrict__ C16,
                                             const float* __restrict__ Wr0, const float* __restrict__ br0,
                                             const float* __restrict__ br1, const float* __restrict__ br2,
                                             const float* __restrict__ w0, const float* __restrict__ w1,
                                             const float* __restrict__ w2, const float* __restrict__ w3,
                                             const float* __restrict__ c3, float* __restrict__ outacc,
                                             int n) {
    __shared__ float As[64][68];
    __shared__ float Ws[64][68];
    const int tid = threadIdx.x;
    const int r0 = blockIdx.x * 64;

    for (int idx = tid; idx < 64 * 16; idx += 256) {
        int k = idx >> 4, cq = (idx & 15) * 4;
        *(float4*)&Ws[k][cq] = *(const float4*)&W[k * 64 + cq];
    }

    const int tr = (tid >> 4) * 4;
    const int tc = (tid & 15) * 4;
    float4 acc0 = {0,0,0,0}, acc1 = {0,0,0,0}, acc2 = {0,0,0,0}, acc3 = {0,0,0,0};

    __syncthreads();
#pragma unroll
    for (int it = 0; it < 4; ++it) {
        int r = (tid >> 4) + it * 16;
        int cq = (tid & 15) * 4;
        int gr = r0 + r;
        float4 v = {0,0,0,0};
        if (gr < n) v = *(const float4*)&A[(size_t)gr * 64 + cq];
        *(float4*)&As[r][cq] = v;
    }
    __syncthreads();
#pragma unroll
    for (int k = 0; k < 64; k += 4) {
        float4 a0 = *(const float4*)&As[tr + 0][k];
        float4 a1 = *(const float4*)&As[tr + 1][k];
        float4 a2 = *(const float4*)&As[tr + 2][k];
        float4 a3 = *(const float4*)&As[tr + 3][k];
        float4 b0 = *(const float4*)&Ws[k + 0][tc];
        float4 b1 = *(const float4*)&Ws[k + 1][tc];
        float4 b2 = *(const float4*)&Ws[k + 2][tc];
        float4 b3 = *(const float4*)&Ws[k + 3][tc];
#define DK(comp, B)                                                                   \
        acc0.x = fmaf(a0.comp, B.x, acc0.x); acc0.y = fmaf(a0.comp, B.y, acc0.y);     \
        acc0.z = fmaf(a0.comp, B.z, acc0.z); acc0.w = fmaf(a0.comp, B.w, acc0.w);     \
        acc1.x = fmaf(a1.comp, B.x, acc1.x); acc1.y = fmaf(a1.comp, B.y, acc1.y);     \
        acc1.z = fmaf(a1.comp, B.z, acc1.z); acc1.w = fmaf(a1.comp, B.w, acc1.w);     \
        acc2.x = fmaf(a2.comp, B.x, acc2.x); acc2.y = fmaf(a2.comp, B.y, acc2.y);     \
        acc2.z = fmaf(a2.comp, B.z, acc2.z); acc2.w = fmaf(a2.comp, B.w, acc2.w);     \
        acc3.x = fmaf(a3.comp, B.x, acc3.x); acc3.y = fmaf(a3.comp, B.y, acc3.y);     \
        acc3.z = fmaf(a3.comp, B.z, acc3.z); acc3.w = fmaf(a3.comp, B.w, acc3.w);
        DK(x, b0) DK(y, b1) DK(z, b2) DK(w, b3)
#undef DK
    }

    float4 bv = *(const float4*)&bias[tc];
    float4 wr = *(const float4*)&Wr0[tc];
    float4 accs[4] = {acc0, acc1, acc2, acc3};
    float part[4];
#pragma unroll
    for (int i = 0; i < 4; ++i) {
        float4 v = accs[i];
        v.x = fmaxf(v.x + bv.x, 0.f); v.y = fmaxf(v.y + bv.y, 0.f);
        v.z = fmaxf(v.z + bv.z, 0.f); v.w = fmaxf(v.w + bv.w, 0.f);
        int gr = r0 + tr + i;
        if (gr < n) {
            ushort4 o = {f2b(v.x), f2b(v.y), f2b(v.z), f2b(v.w)};
            *(ushort4*)&C16[(size_t)gr * 64 + tc] = o;
        }
        part[i] = v.x * wr.x + v.y * wr.y + v.z * wr.z + v.w * wr.w;
    }
#pragma unroll
    for (int off = 8; off > 0; off >>= 1) {
#pragma unroll
        for (int i = 0; i < 4; ++i) part[i] += __shfl_down(part[i], off);
    }
    if ((tid & 15) == 0) {
        float W0 = w0[0];
        float CONST = W0 * br0[0] + w1[0] * br1[0] + w2[0] * br2[0] + w3[0] * c3[0];
#pragma unroll
        for (int i = 0; i < 4; ++i) {
            int gr = r0 + tr + i;
            if (gr < n) outacc[gr] = W0 * part[i] + CONST;
        }
    }
}

// ================= mmfma2: Y16[:,0:64] = A16@WA, Y16[:,64:128] = A16@WB (MFMA, paired) ============
template <int K>
__global__ __launch_bounds__(256) void mmfma2(const u16* __restrict__ A16,
                                              const float* __restrict__ WA,
                                              const float* __restrict__ WB,
                                              u16* __restrict__ Y16, int n) {
    constexpr int LDA = K + 8;
    __shared__ u16 As[64 * LDA];
    __shared__ u16 WtA[64 * LDA];
    __shared__ u16 WtB[64 * LDA];
    const int tid = threadIdx.x;
    const int r0 = blockIdx.x * 64;

    for (int idx = tid; idx < 64 * K / 8; idx += 256) {
        int r = idx / (K / 8), c8 = idx % (K / 8);
        int gr = r0 + r;
        uint4 v = {0, 0, 0, 0};
        if (gr < n) v = *(const uint4*)&A16[(size_t)gr * K + 8 * c8];
        *(uint4*)&As[r * LDA + 8 * c8] = v;
    }
    for (int idx = tid; idx < 16 * K; idx += 256) {
        int k = idx >> 4;
        int qc = idx & 15;
        float4 a = *(const float4*)&WA[k * 64 + 4 * qc];
        float4 b = *(const float4*)&WB[k * 64 + 4 * qc];
        WtA[(4*qc+0) * LDA + k] = f2b(a.x);
        WtA[(4*qc+1) * LDA + k] = f2b(a.y);
        WtA[(4*qc+2) * LDA + k] = f2b(a.z);
        WtA[(4*qc+3) * LDA + k] = f2b(a.w);
        WtB[(4*qc+0) * LDA + k] = f2b(b.x);
        WtB[(4*qc+1) * LDA + k] = f2b(b.y);
        WtB[(4*qc+2) * LDA + k] = f2b(b.z);
        WtB[(4*qc+3) * LDA + k] = f2b(b.w);
    }
    __syncthreads();

    const int wave = tid >> 6;
    const int lane = tid & 63;
    const int m = lane & 15;
    const int ko = (lane >> 4) * 8;
    floatx4 z4 = {0.f, 0.f, 0.f, 0.f};
    floatx4 accA[4] = {z4, z4, z4, z4};
    floatx4 accB[4] = {z4, z4, z4, z4};

#pragma unroll
    for (int kc = 0; kc < K; kc += 32) {
        shortx8 af = *(shortx8*)&As[(wave * 16 + m) * LDA + kc + ko];
#pragma unroll
        for (int nt = 0; nt < 4; ++nt) {
            shortx8 ba = *(shortx8*)&WtA[(nt * 16 + m) * LDA + kc + ko];
            accA[nt] = __builtin_amdgcn_mfma_f32_16x16x32_bf16(af, ba, accA[nt], 0, 0, 0);
            shortx8 bb = *(shortx8*)&WtB[(nt * 16 + m) * LDA + kc + ko];
            accB[nt] = __builtin_amdgcn_mfma_f32_16x16x32_bf16(af, bb, accB[nt], 0, 0, 0);
        }
    }

    const int rbase = r0 + wave * 16 + (lane >> 4) * 4;
#pragma unroll
    for (int nt = 0; nt < 4; ++nt) {
#pragma unroll
        for (int rg = 0; rg < 4; ++rg) {
            int gr = rbase + rg;
            if (gr < n) {
                Y16[(size_t)gr * 128 + nt * 16 + m] = f2b(accA[nt][rg]);
                Y16[(size_t)gr * 128 + 64 + nt * 16 + m] = f2b(accB[nt][rg]);
            }
        }
    }
}

// ================= mmfma2p: layer-2 mm with fused projections — Y2 never materialized ============
// sA[r] = {Y2A[r]·Wr2lo, ·u31lo, ·u32lo}, sB[r] = {Y2B[r]·Wr2hi, ·u31hi, ·u32hi}
__global__ __launch_bounds__(256) void mmfma2p(const u16* __restrict__ A16,
                                               const float* __restrict__ WA,
                                               const float* __restrict__ WB,
                                               const float* __restrict__ Wr2,
                                               const float* __restrict__ u31,
                                               const float* __restrict__ u32v,
                                               float4* __restrict__ sA,
                                               float4* __restrict__ sB, int n) {
    constexpr int K = 128, LDA = K + 8;
    __shared__ u16 As[64 * LDA];
    __shared__ u16 WtA[64 * LDA];
    __shared__ u16 WtB[64 * LDA];
    const int tid = threadIdx.x;
    const int r0 = blockIdx.x * 64;

    for (int idx = tid; idx < 64 * K / 8; idx += 256) {
        int r = idx / (K / 8), c8 = idx % (K / 8);
        int gr = r0 + r;
        uint4 v = {0, 0, 0, 0};
        if (gr < n) v = *(const uint4*)&A16[(size_t)gr * K + 8 * c8];
        *(uint4*)&As[r * LDA + 8 * c8] = v;
    }
    for (int idx = tid; idx < 16 * K; idx += 256) {
        int k = idx >> 4;
        int qc = idx & 15;
        float4 a = *(const float4*)&WA[k * 64 + 4 * qc];
        float4 b = *(const float4*)&WB[k * 64 + 4 * qc];
        WtA[(4*qc+0) * LDA + k] = f2b(a.x);
        WtA[(4*qc+1) * LDA + k] = f2b(a.y);
        WtA[(4*qc+2) * LDA + k] = f2b(a.z);
        WtA[(4*qc+3) * LDA + k] = f2b(a.w);
        WtB[(4*qc+0) * LDA + k] = f2b(b.x);
        WtB[(4*qc+1) * LDA + k] = f2b(b.y);
        WtB[(4*qc+2) * LDA + k] = f2b(b.z);
        WtB[(4*qc+3) * LDA + k] = f2b(b.w);
    }
    __syncthreads();

    const int wave = tid >> 6;
    const int lane = tid & 63;
    const int m = lane & 15;
    const int ko = (lane >> 4) * 8;
    floatx4 z4 = {0.f, 0.f, 0.f, 0.f};
    floatx4 accA[4] = {z4, z4, z4, z4};
    floatx4 accB[4] = {z4, z4, z4, z4};

#pragma unroll
    for (int kc = 0; kc < K; kc += 32) {
        shortx8 af = *(shortx8*)&As[(wave * 16 + m) * LDA + kc + ko];
#pragma unroll
        for (int nt = 0; nt < 4; ++nt) {
            shortx8 ba = *(shortx8*)&WtA[(nt * 16 + m) * LDA + kc + ko];
            accA[nt] = __builtin_amdgcn_mfma_f32_16x16x32_bf16(af, ba, accA[nt], 0, 0, 0);
            shortx8 bb = *(shortx8*)&WtB[(nt * 16 + m) * LDA + kc + ko];
            accB[nt] = __builtin_amdgcn_mfma_f32_16x16x32_bf16(af, bb, accB[nt], 0, 0, 0);
        }
    }

    // per-lane projection weights for its 4 columns (nt*16+m)
    float wA[4], wB[4], uA[4], uB[4], vA[4], vB[4];
#pragma unroll
    for (int nt = 0; nt < 4; ++nt) {
        int c = nt * 16 + m;
        wA[nt] = Wr2[c];  wB[nt] = Wr2[64 + c];
        uA[nt] = u31[c];  uB[nt] = u31[64 + c];
        vA[nt] = u32v[c]; vB[nt] = u32v[64 + c];
    }
    const int rbase = r0 + wave * 16 + (lane >> 4) * 4;
#pragma unroll
    for (int rg = 0; rg < 4; ++rg) {
        float pA = 0.f, qA1 = 0.f, qA2 = 0.f, pB = 0.f, qB1 = 0.f, qB2 = 0.f;
#pragma unroll
        for (int nt = 0; nt < 4; ++nt) {
            float a = accA[nt][rg], b = accB[nt][rg];
            pA = fmaf(a, wA[nt], pA); qA1 = fmaf(a, uA[nt], qA1); qA2 = fmaf(a, vA[nt], qA2);
            pB = fmaf(b, wB[nt], pB); qB1 = fmaf(b, uB[nt], qB1); qB2 = fmaf(b, vB[nt], qB2);
        }
#pragma unroll
        for (int off = 8; off > 0; off >>= 1) {
            pA += __shfl_down(pA, off); qA1 += __shfl_down(qA1, off); qA2 += __shfl_down(qA2, off);
            pB += __shfl_down(pB, off); qB1 += __shfl_down(qB1, off); qB2 += __shfl_down(qB2, off);
        }
        int gr = rbase + rg;
        if (m == 0 && gr < n) {
            sA[gr] = make_float4(pA, qA1, qA2, 0.f);
            sB[gr] = make_float4(pB, qB1, qB2, 0.f);
        }
    }
}

// ================= layer-1 gather: P16 = bf16(R1); readout1 partials (plain stores) ===============
__global__ __launch_bounds__(256) void gatherRO(const int* __restrict__ starts,
                                                const int2* __restrict__ csr,
                                                const u16* __restrict__ Y16,
                                                const float* __restrict__ bA,
                                                const float* __restrict__ bB,
                                                u16* __restrict__ P16,
                                                const float* __restrict__ Wr,
                                                float* __restrict__ pr1,
                                                float* __restrict__ pr2, int N) {
    int wave = (blockIdx.x * blockDim.x + threadIdx.x) >> 6;
    int lane = threadIdx.x & 63;
    if (wave >= 2 * N) return;
    int set2 = wave >= N;
    int d = set2 ? wave - N : wave;
    int base = set2 ? N : 0;
    int yoff = set2 ? 64 : 0;
    int q = lane >> 4;
    int m = lane & 15;

    int s0 = __builtin_amdgcn_readfirstlane(starts[base + d]);
    int s1 = __builtin_amdgcn_readfirstlane(starts[base + d + 1]);

    float a0 = 0.f, a1 = 0.f, a2 = 0.f, a3 = 0.f;
    int j = s0;
#define GEDGE(EXPR)                                                                    \
    {                                                                                  \
        int2 e = (EXPR);                                                               \
        uint2 y = *(const uint2*)&Y16[(size_t)e.x * 128 + yoff + 4 * m];               \
        float w = __int_as_float(e.y);                                                 \
        a0 = fmaf(w, b2f((u16)y.x), a0); a1 = fmaf(w, b2f((u16)(y.x >> 16)), a1);      \
        a2 = fmaf(w, b2f((u16)y.y), a2); a3 = fmaf(w, b2f((u16)(y.y >> 16)), a3);      \
    }
    for (; j + 16 <= s1; j += 16) {
        int2 e0 = csr[j + q];
        int2 e1 = csr[j + 4 + q];
        int2 e2 = csr[j + 8 + q];
        int2 e3 = csr[j + 12 + q];
        uint2 ya = *(const uint2*)&Y16[(size_t)e0.x * 128 + yoff + 4 * m];
        uint2 yb = *(const uint2*)&Y16[(size_t)e1.x * 128 + yoff + 4 * m];
        uint2 yc = *(const uint2*)&Y16[(size_t)e2.x * 128 + yoff + 4 * m];
        uint2 yd = *(const uint2*)&Y16[(size_t)e3.x * 128 + yoff + 4 * m];
        float w0 = __int_as_float(e0.y), w1 = __int_as_float(e1.y);
        float w2 = __int_as_float(e2.y), w3 = __int_as_float(e3.y);
        a0 = fmaf(w0, b2f((u16)ya.x), a0); a1 = fmaf(w0, b2f((u16)(ya.x >> 16)), a1);
        a2 = fmaf(w0, b2f((u16)ya.y), a2); a3 = fmaf(w0, b2f((u16)(ya.y >> 16)), a3);
        a0 = fmaf(w1, b2f((u16)yb.x), a0); a1 = fmaf(w1, b2f((u16)(yb.x >> 16)), a1);
        a2 = fmaf(w1, b2f((u16)yb.y), a2); a3 = fmaf(w1, b2f((u16)(yb.y >> 16)), a3);
        a0 = fmaf(w2, b2f((u16)yc.x), a0); a1 = fmaf(w2, b2f((u16)(yc.x >> 16)), a1);
        a2 = fmaf(w2, b2f((u16)yc.y), a2); a3 = fmaf(w2, b2f((u16)(yc.y >> 16)), a3);
        a0 = fmaf(w3, b2f((u16)yd.x), a0); a1 = fmaf(w3, b2f((u16)(yd.x >> 16)), a1);
        a2 = fmaf(w3, b2f((u16)yd.y), a2); a3 = fmaf(w3, b2f((u16)(yd.y >> 16)), a3);
    }
    if (j + 8 <= s1) {
        GEDGE(csr[j + q]) GEDGE(csr[j + 4 + q])
        j += 8;
    }
    if (j + 4 <= s1) {
        GEDGE(csr[j + q])
        j += 4;
    }
    if (j + q < s1) GEDGE(csr[j + q])
#undef GEDGE
    a0 += __shfl_down(a0, 32); a1 += __shfl_down(a1, 32);
    a2 += __shfl_down(a2, 32); a3 += __shfl_down(a3, 32);
    a0 += __shfl_down(a0, 16); a1 += __shfl_down(a1, 16);
    a2 += __shfl_down(a2, 16); a3 += __shfl_down(a3, 16);

    if (q == 0) {
        float4 bv = *(const float4*)&(set2 ? bB : bA)[4 * m];
        float v0 = a0 + bv.x, v1 = a1 + bv.y, v2 = a2 + bv.z, v3 = a3 + bv.w;
        ushort4 o = {f2b(v0), f2b(v1), f2b(v2), f2b(v3)};
        *(ushort4*)&P16[(size_t)d * 128 + yoff + 4 * m] = o;
        float4 wr = *(const float4*)&Wr[yoff + 4 * m];
        float p = v0 * wr.x + v1 * wr.y + v2 * wr.z + v3 * wr.w;
#pragma unroll
        for (int off = 8; off > 0; off >>= 1) p += __shfl_down(p, off);
        if (m == 0) {
            if (set2) pr2[d] = p;
            else pr1[d] = p;
        }
    }
}

// ================= gatherS: scalar aggregation for readout2 + z; exclusive dest => no atomics =====
__global__ __launch_bounds__(256) void gatherS(const int* __restrict__ starts,
                                               const int2* __restrict__ csr,
                                               const float4* __restrict__ sA,
                                               const float4* __restrict__ sB,
                                               const float* __restrict__ pr1,
                                               const float* __restrict__ pr2,
                                               const float* __restrict__ w1,
                                               const float* __restrict__ w2,
                                               const float* __restrict__ w3,
                                               const float* __restrict__ c2v,
                                               float* __restrict__ outacc,
                                               float* __restrict__ z1, float* __restrict__ z2, int N) {
    int d = (blockIdx.x * blockDim.x + threadIdx.x) >> 6;
    int lane = threadIdx.x & 63;
    if (d >= N) return;
    int a0 = __builtin_amdgcn_readfirstlane(starts[d]);
    int a1 = __builtin_amdgcn_readfirstlane(starts[d + 1]);
    int b0 = __builtin_amdgcn_readfirstlane(starts[N + d]);
    int b1 = __builtin_amdgcn_readfirstlane(starts[N + d + 1]);
    float p = 0.f, q1 = 0.f, q2 = 0.f;
    for (int j = a0 + lane; j < a1; j += 64) {
        int2 e = csr[j];
        float4 s = sA[e.x];
        float w = __int_as_float(e.y);
        p = fmaf(w, s.x, p); q1 = fmaf(w, s.y, q1); q2 = fmaf(w, s.z, q2);
    }
    for (int j = b0 + lane; j < b1; j += 64) {
        int2 e = csr[j];
        float4 s = sB[e.x];
        float w = __int_as_float(e.y);
        p = fmaf(w, s.x, p); q1 = fmaf(w, s.y, q1); q2 = fmaf(w, s.z, q2);
    }
#pragma unroll
    for (int off = 32; off > 0; off >>= 1) {
        p += __shfl_down(p, off);
        q1 += __shfl_down(q1, off);
        q2 += __shfl_down(q2, off);
    }
    if (lane == 0) {
        float W3 = w3[0];
        outacc[d] += w1[0] * (pr1[d] + pr2[d]) + w2[0] * (p + c2v[0]);
        z1[d] = W3 * (q1 + c2v[1]);
        z2[d] = W3 * (q2 + c2v[2]);
    }
}

// ================= gather3: out[d] = outacc[d] + sum_e1 wt*z1[src] + sum_e2 wt*z2[src] ============
__global__ __launch_bounds__(256) void gather3(const int* __restrict__ starts,
                                               const int2* __restrict__ csr,
                                               const float* __restrict__ z1,
                                               const float* __restrict__ z2,
                                               const float* __restrict__ outacc,
                                               float* __restrict__ out, int N) {
    int d = (blockIdx.x * blockDim.x + threadIdx.x) >> 6;
    int lane = threadIdx.x & 63;
    if (d >= N) return;
    int a0 = __builtin_amdgcn_readfirstlane(starts[d]);
    int a1 = __builtin_amdgcn_readfirstlane(starts[d + 1]);
    int b0 = __builtin_amdgcn_readfirstlane(starts[N + d]);
    int b1 = __builtin_amdgcn_readfirstlane(starts[N + d + 1]);
    float acc = 0.f;
    for (int j = a0 + lane; j < a1; j += 64) {
        int2 e = csr[j];
        acc = fmaf(__int_as_float(e.y), z1[e.x], acc);
    }
    for (int j = b0 + lane; j < b1; j += 64) {
        int2 e = csr[j];
        acc = fmaf(__int_as_float(e.y), z2[e.x], acc);
    }
#pragma unroll
    for (int off = 32; off > 0; off >>= 1) acc += __shfl_down(acc, off);
    if (lane == 0) out[d] = outacc[d] + acc;
}

// ================= host =================
static inline char* carve(char*& p, size_t bytes) {
    char* r = p;
    p += (bytes + 255) & ~(size_t)255;
    return r;
}

extern "C" void kernel_launch(void* const* d_in, const int* in_sizes, int n_in,
                              void* d_out, int out_size, void* d_ws, size_t ws_size,
                              hipStream_t stream) {
    const float* x    = (const float*)d_in[0];
    const int*   ei1  = (const int*)d_in[1];
    const int*   ei2  = (const int*)d_in[2];
    const float* W_in = (const float*)d_in[3];  const float* b_in = (const float*)d_in[4];
    const float* W11  = (const float*)d_in[5];
    const float* b11  = (const float*)d_in[6];
    const float* W12  = (const float*)d_in[7];  const float* b12  = (const float*)d_in[8];
    const float* W21  = (const float*)d_in[9];  const float* b21  = (const float*)d_in[10];
    const float* W22  = (const float*)d_in[11]; const float* b22  = (const float*)d_in[12];
    const float* W31  = (const float*)d_in[13]; const float* b31  = (const float*)d_in[14];
    const float* W32  = (const float*)d_in[15]; const float* b32  = (const float*)d_in[16];
    const float* Wr0  = (const float*)d_in[17]; const float* br0  = (const float*)d_in[18];
    const float* Wr1  = (const float*)d_in[19]; const float* br1  = (const float*)d_in[20];
    const float* Wr2  = (const float*)d_in[21]; const float* br2  = (const float*)d_in[22];
    const float* Wr3  = (const float*)d_in[23]; const float* br3  = (const float*)d_in[24];
    const float* w0   = (const float*)d_in[25];
    const float* w1   = (const float*)d_in[26];
    const float* w2   = (const float*)d_in[27];
    const float* w3   = (const float*)d_in[28];

    const int N  = in_sizes[0] / 64;   // 50000
    const int E1 = in_sizes[1] / 2;    // 800000
    const int E2 = in_sizes[2] / 2;
    const int N2 = 2 * N;

    char* p = (char*)d_ws;
    float*  dinv1   = (float*)carve(p, (size_t)N * 4);
    float*  dinv2   = (float*)carve(p, (size_t)N * 4);
    u16*    priv    = (u16*)  carve(p, (size_t)64 * N2 * 2);
    int*    degc    = (int*)  carve(p, (size_t)N2 * 4);
    int*    starts  = (int*)  carve(p, ((size_t)N2 + 1) * 4);
    int*    partial = (int*)  carve(p, 2048 * 4);
    float*  uws     = (float*)carve(p, 264 * 4);             // u31[128], u32[128], c3[1], c2v[3]
    float*  z       = (float*)carve(p, (size_t)N2 * 4);      // z1 | z2
    float*  pr      = (float*)carve(p, (size_t)N2 * 4);      // pr1 | pr2
    float4* sA      = (float4*)carve(p, (size_t)N * 16);
    float4* sB      = (float4*)carve(p, (size_t)N * 16);
    int2*   csr     = (int2*) carve(p, (size_t)(E1 + E2) * 8);
    u16*    R016    = (u16*)  carve(p, (size_t)N * 64 * 2);
    u16*    P16     = (u16*)  carve(p, (size_t)N * 128 * 2);
    u16*    Y16     = (u16*)  carve(p, (size_t)N * 128 * 2);
    float*  outacc  = (float*)carve(p, (size_t)N * 4);
    float* u31 = uws, *u32v = uws + 128, *c3 = uws + 256, *c2v = uws + 257;
    float* z1 = z, *z2 = z + N;
    float* pr1 = pr, *pr2 = pr + N;
    (void)ws_size; (void)n_in; (void)out_size;

    const int B = 256;
    dim3 blk(B);
    int gN2  = (N2 + B - 1) / B;
    int gMM  = (N + 63) / 64;
    int gGa  = (int)(((long long)N2 * 64 + B - 1) / B);
    int gG3  = (int)(((long long)N * 64 + B - 1) / B);
    int nb   = (N2 + 255) / 256;

    // ---- CSR build (LDS-atomic counting sort, 64 slices) + u-precompute ----
    uprep<<<1, 128, 0, stream>>>(W31, W32, b31, b32, Wr3, br3, Wr2, b21, b22,
                                 u31, u32v, c3, c2v);
    hist<<<4 * 64, blk, 0, stream>>>(ei1 + E1, ei2 + E2, priv, N, E1, E2);
    psum<<<gN2, blk, 0, stream>>>(priv, degc, dinv1, dinv2, N);
    scan1<<<nb, blk, 0, stream>>>(degc, partial, N2);
    scan2<<<1, 256, 0, stream>>>(partial, nb, starts, N2);
    scan3<<<nb, blk, 0, stream>>>(degc, partial, starts, N2);
    int rb = (N + 3) / 4;
    for (int rr = 0; rr < 4; ++rr) {
        int lo = rr * rb;
        int nbins = (lo + rb <= N) ? rb : (N - lo);
        if (nbins <= 0) continue;
        fillr<<<2 * 64, blk, 0, stream>>>(ei1, ei2, dinv1, dinv2, starts, priv, csr,
                                          N, N2, lo, nbins, E1, E2);
    }

    // ---- R016 = bf16(relu(x @ W_in + b_in)); outacc = w0*readout0 + CONST ----
    mm_in<<<gMM, blk, 0, stream>>>(x, W_in, b_in, R016, Wr0, br0, br1, br2,
                                   w0, w1, w2, w3, c3, outacc, N);

    // ---- layer 1: Y = R0@[W11|W12]; gather -> P16 (bf16 R1) + readout1 partials ----
    mmfma2<64><<<gMM, blk, 0, stream>>>(R016, W11, W12, Y16, N);
    gatherRO<<<gGa, blk, 0, stream>>>(starts, csr, Y16, b11, b12, P16, Wr1, pr1, pr2, N);

    // ---- layer 2: fused mm + projections (Y2 never materialized) ----
    mmfma2p<<<gMM, blk, 0, stream>>>(P16, W21, W22, Wr2, u31, u32v, sA, sB, N);
    gatherS<<<gG3, blk, 0, stream>>>(starts, csr, sA, sB, pr1, pr2, w1, w2, w3, c2v,
                                     outacc, z1, z2, N);

    // ---- layer 3 (algebraic shortcut): out = outacc + gather(z) ----
    gather3<<<gG3, blk, 0, stream>>>(starts, csr, z1, z2, outacc, (float*)d_out, N);
}

// Round 14
// 347.873 us; speedup vs baseline: 1.4240x; 1.3141x over previous
//
#include <hip/hip_runtime.h>
#include <cstdint>
#include <cstddef>

typedef unsigned short u16;
typedef unsigned int u32;
typedef __attribute__((ext_vector_type(8))) short shortx8;
typedef __attribute__((ext_vector_type(4))) float floatx4;

__device__ __forceinline__ u16 f2b(float f) {
    u32 b = __float_as_uint(f);
    b += 0x7fffu + ((b >> 16) & 1u);   // RNE
    return (u16)(b >> 16);
}
__device__ __forceinline__ float b2f(u16 u) {
    return __uint_as_float(((u32)u) << 16);
}

// ================= u-precompute =================
__global__ void uprep(const float* __restrict__ W31, const float* __restrict__ W32,
                      const float* __restrict__ b31, const float* __restrict__ b32,
                      const float* __restrict__ Wr3, const float* __restrict__ br3,
                      const float* __restrict__ Wr2, const float* __restrict__ b21,
                      const float* __restrict__ b22,
                      float* __restrict__ u31, float* __restrict__ u32,
                      float* __restrict__ c3, float* __restrict__ c2v) {
    __shared__ float s[64];
    int t = threadIdx.x;
    if (t < 128) {
        float a = 0.f, b = 0.f;
        for (int c = 0; c < 64; ++c) {
            a = fmaf(W31[t * 64 + c], Wr3[c], a);
            b = fmaf(W32[t * 64 + c], Wr3[64 + c], b);
        }
        u31[t] = a;
        u32[t] = b;
    }
    if (t < 64) s[t] = b31[t] * Wr3[t] + b32[t] * Wr3[64 + t];
    __syncthreads();
    if (t < 32) s[t] += s[t + 32];
    __syncthreads();
    if (t == 0) {
        float acc = 0.f;
        for (int i = 0; i < 32; ++i) acc += s[i];
        c3[0] = acc + br3[0];
    }
    __syncthreads();
    if (t < 64) {
        float t0 = b21[t] * Wr2[t] + b22[t] * Wr2[64 + t];
        float t1 = b21[t] * u31[t] + b22[t] * u31[64 + t];
        float t2 = b21[t] * u32[t] + b22[t] * u32[64 + t];
#pragma unroll
        for (int off = 32; off > 0; off >>= 1) {
            t0 += __shfl_down(t0, off);
            t1 += __shfl_down(t1, off);
            t2 += __shfl_down(t2, off);
        }
        if (t == 0) { c2v[0] = t0; c2v[1] = t1; c2v[2] = t2; }
    }
}

// ================= CSR build — LDS atomics, 64 slices =================
__global__ __launch_bounds__(256) void hist(const int* __restrict__ c1, const int* __restrict__ c2,
                                            u16* __restrict__ priv, int N, int E1, int E2) {
    __shared__ u32 h[12800];
    int b = blockIdx.x;
    int rid = b >> 6;          // 0..3
    int s = b & 63;
    int set2 = rid >> 1;
    int lo = (rid & 1) * 25600;
    const int* col = set2 ? c2 : c1;
    int E = set2 ? E2 : E1;
    int hi = lo + 25600; if (hi > N) hi = N;
    if (lo >= hi) return;
    int nw = (hi - lo + 1) >> 1;
    for (int i = threadIdx.x; i < nw; i += 256) h[i] = 0;
    __syncthreads();
    int esz = (E + 63) >> 6;
    int e0 = s * esz, e1 = min(e0 + esz, E);
    for (int e = e0 + threadIdx.x; e < e1; e += 256) {
        int c = col[e];
        if (c >= lo && c < hi) {
            int off = c - lo;
            atomicAdd(&h[off >> 1], 1u << ((off & 1) << 4));
        }
    }
    __syncthreads();
    int N2 = 2 * N;
    u32* pout = (u32*)(priv + (size_t)s * N2 + set2 * N + lo);
    for (int i = threadIdx.x; i < nw; i += 256) pout[i] = h[i];
}

__global__ void psum(u16* __restrict__ priv, int* __restrict__ degc,
                     float* __restrict__ d1, float* __restrict__ d2, int N) {
    int i = blockIdx.x * blockDim.x + threadIdx.x;
    int N2 = 2 * N;
    if (i >= N2) return;
    u32 run = 0;
    for (int s = 0; s < 64; ++s) {
        size_t idx = (size_t)s * N2 + i;
        u16 v = priv[idx];
        priv[idx] = (u16)run;
        run += v;
    }
    degc[i] = (int)run;
    float vv = run > 0 ? rsqrtf((float)run) : 0.f;
    if (i < N) d1[i] = vv;
    else d2[i - N] = vv;
}

__global__ void scan1(const int* __restrict__ deg, int* __restrict__ partial, int n) {
    __shared__ int s[256];
    int i = blockIdx.x * 256 + threadIdx.x;
    s[threadIdx.x] = (i < n) ? deg[i] : 0;
    __syncthreads();
    for (int off = 128; off > 0; off >>= 1) {
        if (threadIdx.x < off) s[threadIdx.x] += s[threadIdx.x + off];
        __syncthreads();
    }
    if (threadIdx.x == 0) partial[blockIdx.x] = s[0];
}

__global__ void scan2(int* __restrict__ partial, int nb, int* __restrict__ starts, int n) {
    __shared__ int s[256];
    __shared__ int carry;
    int t = threadIdx.x;
    if (t == 0) carry = 0;
    __syncthreads();
    for (int c0 = 0; c0 < nb; c0 += 256) {
        int i = c0 + t;
        int v = (i < nb) ? partial[i] : 0;
        s[t] = v;
        __syncthreads();
        for (int off = 1; off < 256; off <<= 1) {
            int u = (t >= off) ? s[t - off] : 0;
            __syncthreads();
            s[t] += u;
            __syncthreads();
        }
        if (i < nb) partial[i] = carry + s[t] - v;   // exclusive
        __syncthreads();
        if (t == 255) carry += s[255];
        __syncthreads();
    }
    if (t == 0) starts[n] = carry;
}

__global__ void scan3(const int* __restrict__ deg, const int* __restrict__ partial,
                      int* __restrict__ starts, int n) {
    __shared__ int s[256];
    int i = blockIdx.x * 256 + threadIdx.x;
    int v = (i < n) ? deg[i] : 0;
    s[threadIdx.x] = v;
    __syncthreads();
    for (int off = 1; off < 256; off <<= 1) {
        int u = (threadIdx.x >= off) ? s[threadIdx.x - off] : 0;
        __syncthreads();
        s[threadIdx.x] += u;
        __syncthreads();
    }
    if (i < n) starts[i] = partial[blockIdx.x] + s[threadIdx.x] - v;
}

// fillr: ONE launch, grid = 4 ranges x 2 sets x 64 slices = 512 blocks.
// Each (set,range,slice) is an exclusive cursor domain -> LDS atomics only, zero global atomics.
__global__ __launch_bounds__(256) void fillr(const int* __restrict__ ei1, const int* __restrict__ ei2,
                                             const float* __restrict__ dinv1, const float* __restrict__ dinv2,
                                             const int* __restrict__ starts, const u16* __restrict__ priv,
                                             int2* __restrict__ csr, int N, int N2, int rb,
                                             int E1, int E2) {
    __shared__ u32 cur[12544];
    int rr = blockIdx.x >> 7;            // 0..3
    int set = (blockIdx.x >> 6) & 1;
    int s = blockIdx.x & 63;
    int lo = rr * rb;
    int nbins = (lo + rb <= N) ? rb : (N - lo);
    if (nbins <= 0) return;              // uniform per block
    const int* rows = set ? ei2 : ei1;
    int E = set ? E2 : E1;
    const int* cols = rows + E;
    const float* dinv = set ? dinv2 : dinv1;
    int gbase = set * N + lo;
    for (int i = threadIdx.x; i < nbins; i += 256)
        cur[i] = (u32)starts[gbase + i] + (u32)priv[(size_t)s * N2 + gbase + i];
    __syncthreads();
    int esz = (E + 63) >> 6;
    int e0 = s * esz, e1 = min(e0 + esz, E);
    int hi = lo + nbins;
    for (int e = e0 + threadIdx.x; e < e1; e += 256) {
        int c = cols[e];
        if (c >= lo && c < hi) {
            int r = rows[e];
            u32 pos = atomicAdd(&cur[c - lo], 1u);
            csr[pos] = make_int2(r, __float_as_int(dinv[r] * dinv[c]));
        }
    }
}

// ================= mm_in: R016 = bf16(relu(x@W_in + b_in)); fused readout0 + outacc init =========
__global__ __launch_bounds__(256) void mm_in(const float* __restrict__ A, const float* __restrict__ W,
                                             const float* __restrict__ bias, u16* __restrict__ C16,
                                             const float* __restrict__ Wr0, const float* __restrict__ br0,
                                             const float* __restrict__ br1, const float* __restrict__ br2,
                                             const float* __restrict__ w0, const float* __restrict__ w1,
                                             const float* __restrict__ w2, const float* __restrict__ w3,
                                             const float* __restrict__ c3, float* __restrict__ outacc,
                                             int n) {
    __shared__ float As[64][68];
    __shared__ float Ws[64][68];
    const int tid = threadIdx.x;
    const int r0 = blockIdx.x * 64;

    for (int idx = tid; idx < 64 * 16; idx += 256) {
        int k = idx >> 4, cq = (idx & 15) * 4;
        *(float4*)&Ws[k][cq] = *(const float4*)&W[k * 64 + cq];
    }

    const int tr = (tid >> 4) * 4;
    const int tc = (tid & 15) * 4;
    float4 acc0 = {0,0,0,0}, acc1 = {0,0,0,0}, acc2 = {0,0,0,0}, acc3 = {0,0,0,0};

    __syncthreads();
#pragma unroll
    for (int it = 0; it < 4; ++it) {
        int r = (tid >> 4) + it * 16;
        int cq = (tid & 15) * 4;
        int gr = r0 + r;
        float4 v = {0,0,0,0};
        if (gr < n) v = *(const float4*)&A[(size_t)gr * 64 + cq];
        *(float4*)&As[r][cq] = v;
    }
    __syncthreads();
#pragma unroll
    for (int k = 0; k < 64; k += 4) {
        float4 a0 = *(const float4*)&As[tr + 0][k];
        float4 a1 = *(const float4*)&As[tr + 1][k];
        float4 a2 = *(const float4*)&As[tr + 2][k];
        float4 a3 = *(const float4*)&As[tr + 3][k];
        float4 b0 = *(const float4*)&Ws[k + 0][tc];
        float4 b1 = *(const float4*)&Ws[k + 1][tc];
        float4 b2 = *(const float4*)&Ws[k + 2][tc];
        float4 b3 = *(const float4*)&Ws[k + 3][tc];
#define DK(comp, B)                                                                   \
        acc0.x = fmaf(a0.comp, B.x, acc0.x); acc0.y = fmaf(a0.comp, B.y, acc0.y);     \
        acc0.z = fmaf(a0.comp, B.z, acc0.z); acc0.w = fmaf(a0.comp, B.w, acc0.w);     \
        acc1.x = fmaf(a1.comp, B.x, acc1.x); acc1.y = fmaf(a1.comp, B.y, acc1.y);     \
        acc1.z = fmaf(a1.comp, B.z, acc1.z); acc1.w = fmaf(a1.comp, B.w, acc1.w);     \
        acc2.x = fmaf(a2.comp, B.x, acc2.x); acc2.y = fmaf(a2.comp, B.y, acc2.y);     \
        acc2.z = fmaf(a2.comp, B.z, acc2.z); acc2.w = fmaf(a2.comp, B.w, acc2.w);     \
        acc3.x = fmaf(a3.comp, B.x, acc3.x); acc3.y = fmaf(a3.comp, B.y, acc3.y);     \
        acc3.z = fmaf(a3.comp, B.z, acc3.z); acc3.w = fmaf(a3.comp, B.w, acc3.w);
        DK(x, b0) DK(y, b1) DK(z, b2) DK(w, b3)
#undef DK
    }

    float4 bv = *(const float4*)&bias[tc];
    float4 wr = *(const float4*)&Wr0[tc];
    float4 accs[4] = {acc0, acc1, acc2, acc3};
    float part[4];
#pragma unroll
    for (int i = 0; i < 4; ++i) {
        float4 v = accs[i];
        v.x = fmaxf(v.x + bv.x, 0.f); v.y = fmaxf(v.y + bv.y, 0.f);
        v.z = fmaxf(v.z + bv.z, 0.f); v.w = fmaxf(v.w + bv.w, 0.f);
        int gr = r0 + tr + i;
        if (gr < n) {
            ushort4 o = {f2b(v.x), f2b(v.y), f2b(v.z), f2b(v.w)};
            *(ushort4*)&C16[(size_t)gr * 64 + tc] = o;
        }
        part[i] = v.x * wr.x + v.y * wr.y + v.z * wr.z + v.w * wr.w;
    }
#pragma unroll
    for (int off = 8; off > 0; off >>= 1) {
#pragma unroll
        for (int i = 0; i < 4; ++i) part[i] += __shfl_down(part[i], off);
    }
    if ((tid & 15) == 0) {
        float W0 = w0[0];
        float CONST = W0 * br0[0] + w1[0] * br1[0] + w2[0] * br2[0] + w3[0] * c3[0];
#pragma unroll
        for (int i = 0; i < 4; ++i) {
            int gr = r0 + tr + i;
            if (gr < n) outacc[gr] = W0 * part[i] + CONST;
        }
    }
}

// ================= mmfma2: Y16[:,0:64] = A16@WA, Y16[:,64:128] = A16@WB (MFMA, paired) ============
template <int K>
__global__ __launch_bounds__(256) void mmfma2(const u16* __restrict__ A16,
                                              const float* __restrict__ WA,
                                              const float* __restrict__ WB,
                                              u16* __restrict__ Y16, int n) {
    constexpr int LDA = K + 8;
    __shared__ u16 As[64 * LDA];
    __shared__ u16 WtA[64 * LDA];
    __shared__ u16 WtB[64 * LDA];
    const int tid = threadIdx.x;
    const int r0 = blockIdx.x * 64;

    for (int idx = tid; idx < 64 * K / 8; idx += 256) {
        int r = idx / (K / 8), c8 = idx % (K / 8);
        int gr = r0 + r;
        uint4 v = {0, 0, 0, 0};
        if (gr < n) v = *(const uint4*)&A16[(size_t)gr * K + 8 * c8];
        *(uint4*)&As[r * LDA + 8 * c8] = v;
    }
    for (int idx = tid; idx < 16 * K; idx += 256) {
        int k = idx >> 4;
        int qc = idx & 15;
        float4 a = *(const float4*)&WA[k * 64 + 4 * qc];
        float4 b = *(const float4*)&WB[k * 64 + 4 * qc];
        WtA[(4*qc+0) * LDA + k] = f2b(a.x);
        WtA[(4*qc+1) * LDA + k] = f2b(a.y);
        WtA[(4*qc+2) * LDA + k] = f2b(a.z);
        WtA[(4*qc+3) * LDA + k] = f2b(a.w);
        WtB[(4*qc+0) * LDA + k] = f2b(b.x);
        WtB[(4*qc+1) * LDA + k] = f2b(b.y);
        WtB[(4*qc+2) * LDA + k] = f2b(b.z);
        WtB[(4*qc+3) * LDA + k] = f2b(b.w);
    }
    __syncthreads();

    const int wave = tid >> 6;
    const int lane = tid & 63;
    const int m = lane & 15;
    const int ko = (lane >> 4) * 8;
    floatx4 z4 = {0.f, 0.f, 0.f, 0.f};
    floatx4 accA[4] = {z4, z4, z4, z4};
    floatx4 accB[4] = {z4, z4, z4, z4};

#pragma unroll
    for (int kc = 0; kc < K; kc += 32) {
        shortx8 af = *(shortx8*)&As[(wave * 16 + m) * LDA + kc + ko];
#pragma unroll
        for (int nt = 0; nt < 4; ++nt) {
            shortx8 ba = *(shortx8*)&WtA[(nt * 16 + m) * LDA + kc + ko];
            accA[nt] = __builtin_amdgcn_mfma_f32_16x16x32_bf16(af, ba, accA[nt], 0, 0, 0);
            shortx8 bb = *(shortx8*)&WtB[(nt * 16 + m) * LDA + kc + ko];
            accB[nt] = __builtin_amdgcn_mfma_f32_16x16x32_bf16(af, bb, accB[nt], 0, 0, 0);
        }
    }

    const int rbase = r0 + wave * 16 + (lane >> 4) * 4;
#pragma unroll
    for (int nt = 0; nt < 4; ++nt) {
#pragma unroll
        for (int rg = 0; rg < 4; ++rg) {
            int gr = rbase + rg;
            if (gr < n) {
                Y16[(size_t)gr * 128 + nt * 16 + m] = f2b(accA[nt][rg]);
                Y16[(size_t)gr * 128 + 64 + nt * 16 + m] = f2b(accB[nt][rg]);
            }
        }
    }
}

// ================= mmfma2p: layer-2 mm with fused projections — Y2 never materialized ============
__global__ __launch_bounds__(256) void mmfma2p(const u16* __restrict__ A16,
                                               const float* __restrict__ WA,
                                               const float* __restrict__ WB,
                                               const float* __restrict__ Wr2,
                                               const float* __restrict__ u31,
                                               const float* __restrict__ u32v,
                                               float4* __restrict__ sA,
                                               float4* __restrict__ sB, int n) {
    constexpr int K = 128, LDA = K + 8;
    __shared__ u16 As[64 * LDA];
    __shared__ u16 WtA[64 * LDA];
    __shared__ u16 WtB[64 * LDA];
    const int tid = threadIdx.x;
    const int r0 = blockIdx.x * 64;

    for (int idx = tid; idx < 64 * K / 8; idx += 256) {
        int r = idx / (K / 8), c8 = idx % (K / 8);
        int gr = r0 + r;
        uint4 v = {0, 0, 0, 0};
        if (gr < n) v = *(const uint4*)&A16[(size_t)gr * K + 8 * c8];
        *(uint4*)&As[r * LDA + 8 * c8] = v;
    }
    for (int idx = tid; idx < 16 * K; idx += 256) {
        int k = idx >> 4;
        int qc = idx & 15;
        float4 a = *(const float4*)&WA[k * 64 + 4 * qc];
        float4 b = *(const float4*)&WB[k * 64 + 4 * qc];
        WtA[(4*qc+0) * LDA + k] = f2b(a.x);
        WtA[(4*qc+1) * LDA + k] = f2b(a.y);
        WtA[(4*qc+2) * LDA + k] = f2b(a.z);
        WtA[(4*qc+3) * LDA + k] = f2b(a.w);
        WtB[(4*qc+0) * LDA + k] = f2b(b.x);
        WtB[(4*qc+1) * LDA + k] = f2b(b.y);
        WtB[(4*qc+2) * LDA + k] = f2b(b.z);
        WtB[(4*qc+3) * LDA + k] = f2b(b.w);
    }
    __syncthreads();

    const int wave = tid >> 6;
    const int lane = tid & 63;
    const int m = lane & 15;
    const int ko = (lane >> 4) * 8;
    floatx4 z4 = {0.f, 0.f, 0.f, 0.f};
    floatx4 accA[4] = {z4, z4, z4, z4};
    floatx4 accB[4] = {z4, z4, z4, z4};

#pragma unroll
    for (int kc = 0; kc < K; kc += 32) {
        shortx8 af = *(shortx8*)&As[(wave * 16 + m) * LDA + kc + ko];
#pragma unroll
        for (int nt = 0; nt < 4; ++nt) {
            shortx8 ba = *(shortx8*)&WtA[(nt * 16 + m) * LDA + kc + ko];
            accA[nt] = __builtin_amdgcn_mfma_f32_16x16x32_bf16(af, ba, accA[nt], 0, 0, 0);
            shortx8 bb = *(shortx8*)&WtB[(nt * 16 + m) * LDA + kc + ko];
            accB[nt] = __builtin_amdgcn_mfma_f32_16x16x32_bf16(af, bb, accB[nt], 0, 0, 0);
        }
    }

    float wA[4], wB[4], uA[4], uB[4], vA[4], vB[4];
#pragma unroll
    for (int nt = 0; nt < 4; ++nt) {
        int c = nt * 16 + m;
        wA[nt] = Wr2[c];  wB[nt] = Wr2[64 + c];
        uA[nt] = u31[c];  uB[nt] = u31[64 + c];
        vA[nt] = u32v[c]; vB[nt] = u32v[64 + c];
    }
    const int rbase = r0 + wave * 16 + (lane >> 4) * 4;
#pragma unroll
    for (int rg = 0; rg < 4; ++rg) {
        float pA = 0.f, qA1 = 0.f, qA2 = 0.f, pB = 0.f, qB1 = 0.f, qB2 = 0.f;
#pragma unroll
        for (int nt = 0; nt < 4; ++nt) {
            float a = accA[nt][rg], b = accB[nt][rg];
            pA = fmaf(a, wA[nt], pA); qA1 = fmaf(a, uA[nt], qA1); qA2 = fmaf(a, vA[nt], qA2);
            pB = fmaf(b, wB[nt], pB); qB1 = fmaf(b, uB[nt], qB1); qB2 = fmaf(b, vB[nt], qB2);
        }
#pragma unroll
        for (int off = 8; off > 0; off >>= 1) {
            pA += __shfl_down(pA, off); qA1 += __shfl_down(qA1, off); qA2 += __shfl_down(qA2, off);
            pB += __shfl_down(pB, off); qB1 += __shfl_down(qB1, off); qB2 += __shfl_down(qB2, off);
        }
        int gr = rbase + rg;
        if (m == 0 && gr < n) {
            sA[gr] = make_float4(pA, qA1, qA2, 0.f);
            sB[gr] = make_float4(pB, qB1, qB2, 0.f);
        }
    }
}

// ================= layer-1 gather: P16 = bf16(R1); readout1 partials (plain stores) ===============
__global__ __launch_bounds__(256) void gatherRO(const int* __restrict__ starts,
                                                const int2* __restrict__ csr,
                                                const u16* __restrict__ Y16,
                                                const float* __restrict__ bA,
                                                const float* __restrict__ bB,
                                                u16* __restrict__ P16,
                                                const float* __restrict__ Wr,
                                                float* __restrict__ pr1,
                                                float* __restrict__ pr2, int N) {
    int wave = (blockIdx.x * blockDim.x + threadIdx.x) >> 6;
    int lane = threadIdx.x & 63;
    if (wave >= 2 * N) return;
    int set2 = wave >= N;
    int d = set2 ? wave - N : wave;
    int base = set2 ? N : 0;
    int yoff = set2 ? 64 : 0;
    int q = lane >> 4;
    int m = lane & 15;

    int s0 = __builtin_amdgcn_readfirstlane(starts[base + d]);
    int s1 = __builtin_amdgcn_readfirstlane(starts[base + d + 1]);

    float a0 = 0.f, a1 = 0.f, a2 = 0.f, a3 = 0.f;
    int j = s0;
#define GEDGE(EXPR)                                                                    \
    {                                                                                  \
        int2 e = (EXPR);                                                               \
        uint2 y = *(const uint2*)&Y16[(size_t)e.x * 128 + yoff + 4 * m];               \
        float w = __int_as_float(e.y);                                                 \
        a0 = fmaf(w, b2f((u16)y.x), a0); a1 = fmaf(w, b2f((u16)(y.x >> 16)), a1);      \
        a2 = fmaf(w, b2f((u16)y.y), a2); a3 = fmaf(w, b2f((u16)(y.y >> 16)), a3);      \
    }
    for (; j + 16 <= s1; j += 16) {
        int2 e0 = csr[j + q];
        int2 e1 = csr[j + 4 + q];
        int2 e2 = csr[j + 8 + q];
        int2 e3 = csr[j + 12 + q];
        uint2 ya = *(const uint2*)&Y16[(size_t)e0.x * 128 + yoff + 4 * m];
        uint2 yb = *(const uint2*)&Y16[(size_t)e1.x * 128 + yoff + 4 * m];
        uint2 yc = *(const uint2*)&Y16[(size_t)e2.x * 128 + yoff + 4 * m];
        uint2 yd = *(const uint2*)&Y16[(size_t)e3.x * 128 + yoff + 4 * m];
        float w0 = __int_as_float(e0.y), w1 = __int_as_float(e1.y);
        float w2 = __int_as_float(e2.y), w3 = __int_as_float(e3.y);
        a0 = fmaf(w0, b2f((u16)ya.x), a0); a1 = fmaf(w0, b2f((u16)(ya.x >> 16)), a1);
        a2 = fmaf(w0, b2f((u16)ya.y), a2); a3 = fmaf(w0, b2f((u16)(ya.y >> 16)), a3);
        a0 = fmaf(w1, b2f((u16)yb.x), a0); a1 = fmaf(w1, b2f((u16)(yb.x >> 16)), a1);
        a2 = fmaf(w1, b2f((u16)yb.y), a2); a3 = fmaf(w1, b2f((u16)(yb.y >> 16)), a3);
        a0 = fmaf(w2, b2f((u16)yc.x), a0); a1 = fmaf(w2, b2f((u16)(yc.x >> 16)), a1);
        a2 = fmaf(w2, b2f((u16)yc.y), a2); a3 = fmaf(w2, b2f((u16)(yc.y >> 16)), a3);
        a0 = fmaf(w3, b2f((u16)yd.x), a0); a1 = fmaf(w3, b2f((u16)(yd.x >> 16)), a1);
        a2 = fmaf(w3, b2f((u16)yd.y), a2); a3 = fmaf(w3, b2f((u16)(yd.y >> 16)), a3);
    }
    if (j + 8 <= s1) {
        GEDGE(csr[j + q]) GEDGE(csr[j + 4 + q])
        j += 8;
    }
    if (j + 4 <= s1) {
        GEDGE(csr[j + q])
        j += 4;
    }
    if (j + q < s1) GEDGE(csr[j + q])
#undef GEDGE
    a0 += __shfl_down(a0, 32); a1 += __shfl_down(a1, 32);
    a2 += __shfl_down(a2, 32); a3 += __shfl_down(a3, 32);
    a0 += __shfl_down(a0, 16); a1 += __shfl_down(a1, 16);
    a2 += __shfl_down(a2, 16); a3 += __shfl_down(a3, 16);

    if (q == 0) {
        float4 bv = *(const float4*)&(set2 ? bB : bA)[4 * m];
        float v0 = a0 + bv.x, v1 = a1 + bv.y, v2 = a2 + bv.z, v3 = a3 + bv.w;
        ushort4 o = {f2b(v0), f2b(v1), f2b(v2), f2b(v3)};
        *(ushort4*)&P16[(size_t)d * 128 + yoff + 4 * m] = o;
        float4 wr = *(const float4*)&Wr[yoff + 4 * m];
        float p = v0 * wr.x + v1 * wr.y + v2 * wr.z + v3 * wr.w;
#pragma unroll
        for (int off = 8; off > 0; off >>= 1) p += __shfl_down(p, off);
        if (m == 0) {
            if (set2) pr2[d] = p;
            else pr1[d] = p;
        }
    }
}

// ================= gatherS: scalar aggregation for readout2 + z; exclusive dest => no atomics =====
__global__ __launch_bounds__(256) void gatherS(const int* __restrict__ starts,
                                               const int2* __restrict__ csr,
                                               const float4* __restrict__ sA,
                                               const float4* __restrict__ sB,
                                               const float* __restrict__ pr1,
                                               const float* __restrict__ pr2,
                                               const float* __restrict__ w1,
                                               const float* __restrict__ w2,
                                               const float* __restrict__ w3,
                                               const float* __restrict__ c2v,
                                               float* __restrict__ outacc,
                                               float* __restrict__ z1, float* __restrict__ z2, int N) {
    int d = (blockIdx.x * blockDim.x + threadIdx.x) >> 6;
    int lane = threadIdx.x & 63;
    if (d >= N) return;
    int a0 = __builtin_amdgcn_readfirstlane(starts[d]);
    int a1 = __builtin_amdgcn_readfirstlane(starts[d + 1]);
    int b0 = __builtin_amdgcn_readfirstlane(starts[N + d]);
    int b1 = __builtin_amdgcn_readfirstlane(starts[N + d + 1]);
    float p = 0.f, q1 = 0.f, q2 = 0.f;
    for (int j = a0 + lane; j < a1; j += 64) {
        int2 e = csr[j];
        float4 s = sA[e.x];
        float w = __int_as_float(e.y);
        p = fmaf(w, s.x, p); q1 = fmaf(w, s.y, q1); q2 = fmaf(w, s.z, q2);
    }
    for (int j = b0 + lane; j < b1; j += 64) {
        int2 e = csr[j];
        float4 s = sB[e.x];
        float w = __int_as_float(e.y);
        p = fmaf(w, s.x, p); q1 = fmaf(w, s.y, q1); q2 = fmaf(w, s.z, q2);
    }
#pragma unroll
    for (int off = 32; off > 0; off >>= 1) {
        p += __shfl_down(p, off);
        q1 += __shfl_down(q1, off);
        q2 += __shfl_down(q2, off);
    }
    if (lane == 0) {
        float W3 = w3[0];
        outacc[d] += w1[0] * (pr1[d] + pr2[d]) + w2[0] * (p + c2v[0]);
        z1[d] = W3 * (q1 + c2v[1]);
        z2[d] = W3 * (q2 + c2v[2]);
    }
}

// ================= gather3: out[d] = outacc[d] + sum_e1 wt*z1[src] + sum_e2 wt*z2[src] ============
__global__ __launch_bounds__(256) void gather3(const int* __restrict__ starts,
                                               const int2* __restrict__ csr,
                                               const float* __restrict__ z1,
                                               const float* __restrict__ z2,
                                               const float* __restrict__ outacc,
                                               float* __restrict__ out, int N) {
    int d = (blockIdx.x * blockDim.x + threadIdx.x) >> 6;
    int lane = threadIdx.x & 63;
    if (d >= N) return;
    int a0 = __builtin_amdgcn_readfirstlane(starts[d]);
    int a1 = __builtin_amdgcn_readfirstlane(starts[d + 1]);
    int b0 = __builtin_amdgcn_readfirstlane(starts[N + d]);
    int b1 = __builtin_amdgcn_readfirstlane(starts[N + d + 1]);
    float acc = 0.f;
    for (int j = a0 + lane; j < a1; j += 64) {
        int2 e = csr[j];
        acc = fmaf(__int_as_float(e.y), z1[e.x], acc);
    }
    for (int j = b0 + lane; j < b1; j += 64) {
        int2 e = csr[j];
        acc = fmaf(__int_as_float(e.y), z2[e.x], acc);
    }
#pragma unroll
    for (int off = 32; off > 0; off >>= 1) acc += __shfl_down(acc, off);
    if (lane == 0) out[d] = outacc[d] + acc;
}

// ================= host =================
static inline char* carve(char*& p, size_t bytes) {
    char* r = p;
    p += (bytes + 255) & ~(size_t)255;
    return r;
}

extern "C" void kernel_launch(void* const* d_in, const int* in_sizes, int n_in,
                              void* d_out, int out_size, void* d_ws, size_t ws_size,
                              hipStream_t stream) {
    const float* x    = (const float*)d_in[0];
    const int*   ei1  = (const int*)d_in[1];
    const int*   ei2  = (const int*)d_in[2];
    const float* W_in = (const float*)d_in[3];  const float* b_in = (const float*)d_in[4];
    const float* W11  = (const float*)d_in[5];
    const float* b11  = (const float*)d_in[6];
    const float* W12  = (const float*)d_in[7];  const float* b12  = (const float*)d_in[8];
    const float* W21  = (const float*)d_in[9];  const float* b21  = (const float*)d_in[10];
    const float* W22  = (const float*)d_in[11]; const float* b22  = (const float*)d_in[12];
    const float* W31  = (const float*)d_in[13]; const float* b31  = (const float*)d_in[14];
    const float* W32  = (const float*)d_in[15]; const float* b32  = (const float*)d_in[16];
    const float* Wr0  = (const float*)d_in[17]; const float* br0  = (const float*)d_in[18];
    const float* Wr1  = (const float*)d_in[19]; const float* br1  = (const float*)d_in[20];
    const float* Wr2  = (const float*)d_in[21]; const float* br2  = (const float*)d_in[22];
    const float* Wr3  = (const float*)d_in[23]; const float* br3  = (const float*)d_in[24];
    const float* w0   = (const float*)d_in[25];
    const float* w1   = (const float*)d_in[26];
    const float* w2   = (const float*)d_in[27];
    const float* w3   = (const float*)d_in[28];

    const int N  = in_sizes[0] / 64;   // 50000
    const int E1 = in_sizes[1] / 2;    // 800000
    const int E2 = in_sizes[2] / 2;
    const int N2 = 2 * N;

    char* p = (char*)d_ws;
    float*  dinv1   = (float*)carve(p, (size_t)N * 4);
    float*  dinv2   = (float*)carve(p, (size_t)N * 4);
    u16*    priv    = (u16*)  carve(p, (size_t)64 * N2 * 2);
    int*    degc    = (int*)  carve(p, (size_t)N2 * 4);
    int*    starts  = (int*)  carve(p, ((size_t)N2 + 1) * 4);
    int*    partial = (int*)  carve(p, 2048 * 4);
    float*  uws     = (float*)carve(p, 264 * 4);             // u31[128], u32[128], c3[1], c2v[3]
    float*  z       = (float*)carve(p, (size_t)N2 * 4);      // z1 | z2
    float*  pr      = (float*)carve(p, (size_t)N2 * 4);      // pr1 | pr2
    float4* sA      = (float4*)carve(p, (size_t)N * 16);
    float4* sB      = (float4*)carve(p, (size_t)N * 16);
    int2*   csr     = (int2*) carve(p, (size_t)(E1 + E2) * 8);
    u16*    R016    = (u16*)  carve(p, (size_t)N * 64 * 2);
    u16*    P16     = (u16*)  carve(p, (size_t)N * 128 * 2);
    u16*    Y16     = (u16*)  carve(p, (size_t)N * 128 * 2);
    float*  outacc  = (float*)carve(p, (size_t)N * 4);
    float* u31 = uws, *u32v = uws + 128, *c3 = uws + 256, *c2v = uws + 257;
    float* z1 = z, *z2 = z + N;
    float* pr1 = pr, *pr2 = pr + N;
    (void)ws_size; (void)n_in; (void)out_size;

    const int B = 256;
    dim3 blk(B);
    int gN2  = (N2 + B - 1) / B;
    int gMM  = (N + 63) / 64;
    int gGa  = (int)(((long long)N2 * 64 + B - 1) / B);
    int gG3  = (int)(((long long)N * 64 + B - 1) / B);
    int nb   = (N2 + 255) / 256;

    // ---- CSR build (LDS-atomic counting sort, 64 slices) + u-precompute ----
    uprep<<<1, 128, 0, stream>>>(W31, W32, b31, b32, Wr3, br3, Wr2, b21, b22,
                                 u31, u32v, c3, c2v);
    hist<<<4 * 64, blk, 0, stream>>>(ei1 + E1, ei2 + E2, priv, N, E1, E2);
    psum<<<gN2, blk, 0, stream>>>(priv, degc, dinv1, dinv2, N);
    scan1<<<nb, blk, 0, stream>>>(degc, partial, N2);
    scan2<<<1, 256, 0, stream>>>(partial, nb, starts, N2);
    scan3<<<nb, blk, 0, stream>>>(degc, partial, starts, N2);
    int rb = (N + 3) / 4;
    fillr<<<4 * 2 * 64, blk, 0, stream>>>(ei1, ei2, dinv1, dinv2, starts, priv, csr,
                                          N, N2, rb, E1, E2);

    // ---- R016 = bf16(relu(x @ W_in + b_in)); outacc = w0*readout0 + CONST ----
    mm_in<<<gMM, blk, 0, stream>>>(x, W_in, b_in, R016, Wr0, br0, br1, br2,
                                   w0, w1, w2, w3, c3, outacc, N);

    // ---- layer 1: Y = R0@[W11|W12]; gather -> P16 (bf16 R1) + readout1 partials ----
    mmfma2<64><<<gMM, blk, 0, stream>>>(R016, W11, W12, Y16, N);
    gatherRO<<<gGa, blk, 0, stream>>>(starts, csr, Y16, b11, b12, P16, Wr1, pr1, pr2, N);

    // ---- layer 2: fused mm + projections (Y2 never materialized) ----
    mmfma2p<<<gMM, blk, 0, stream>>>(P16, W21, W22, Wr2, u31, u32v, sA, sB, N);
    gatherS<<<gG3, blk, 0, stream>>>(starts, csr, sA, sB, pr1, pr2, w1, w2, w3, c2v,
                                     outacc, z1, z2, N);

    // ---- layer 3 (algebraic shortcut): out = outacc + gather(z) ----
    gather3<<<gG3, blk, 0, stream>>>(starts, csr, z1, z2, outacc, (float*)d_out, N);
}

// Round 15
// 342.023 us; speedup vs baseline: 1.4483x; 1.0171x over previous
//
#include <hip/hip_runtime.h>
#include <cstdint>
#include <cstddef>

typedef unsigned short u16;
typedef unsigned int u32;
typedef __attribute__((ext_vector_type(8))) short shortx8;
typedef __attribute__((ext_vector_type(4))) float floatx4;

__device__ __forceinline__ u16 f2b(float f) {
    u32 b = __float_as_uint(f);
    b += 0x7fffu + ((b >> 16) & 1u);   // RNE
    return (u16)(b >> 16);
}
__device__ __forceinline__ float b2f(u16 u) {
    return __uint_as_float(((u32)u) << 16);
}

// ================= u-precompute =================
__global__ void uprep(const float* __restrict__ W31, const float* __restrict__ W32,
                      const float* __restrict__ b31, const float* __restrict__ b32,
                      const float* __restrict__ Wr3, const float* __restrict__ br3,
                      const float* __restrict__ Wr2, const float* __restrict__ b21,
                      const float* __restrict__ b22,
                      float* __restrict__ u31, float* __restrict__ u32,
                      float* __restrict__ c3, float* __restrict__ c2v) {
    __shared__ float s[64];
    int t = threadIdx.x;
    if (t < 128) {
        float a = 0.f, b = 0.f;
        for (int c = 0; c < 64; ++c) {
            a = fmaf(W31[t * 64 + c], Wr3[c], a);
            b = fmaf(W32[t * 64 + c], Wr3[64 + c], b);
        }
        u31[t] = a;
        u32[t] = b;
    }
    if (t < 64) s[t] = b31[t] * Wr3[t] + b32[t] * Wr3[64 + t];
    __syncthreads();
    if (t < 32) s[t] += s[t + 32];
    __syncthreads();
    if (t == 0) {
        float acc = 0.f;
        for (int i = 0; i < 32; ++i) acc += s[i];
        c3[0] = acc + br3[0];
    }
    __syncthreads();
    if (t < 64) {
        float t0 = b21[t] * Wr2[t] + b22[t] * Wr2[64 + t];
        float t1 = b21[t] * u31[t] + b22[t] * u31[64 + t];
        float t2 = b21[t] * u32[t] + b22[t] * u32[64 + t];
#pragma unroll
        for (int off = 32; off > 0; off >>= 1) {
            t0 += __shfl_down(t0, off);
            t1 += __shfl_down(t1, off);
            t2 += __shfl_down(t2, off);
        }
        if (t == 0) { c2v[0] = t0; c2v[1] = t1; c2v[2] = t2; }
    }
}

// ================= CSR build — radix 2-phase counting sort (no global atomics) =================
// Buckets: bucket(c) = c >> 8, NB buckets/set (256 bins each). 64 edge-slices per set.

// hist256: grid = 2 sets x 64 slices. Per-(slice,bucket) counts -> pcnt[(set*NB+b)*64 + s].
__global__ __launch_bounds__(256) void hist256(const int* __restrict__ ei1, const int* __restrict__ ei2,
                                               int* __restrict__ pcnt, int NB, int E1, int E2) {
    __shared__ u32 h[256];
    int set = blockIdx.x >> 6;
    int s = blockIdx.x & 63;
    const int* col = set ? ei2 + E2 : ei1 + E1;
    int E = set ? E2 : E1;
    for (int i = threadIdx.x; i < 256; i += 256) h[i] = 0;
    __syncthreads();
    int esz = (E + 63) >> 6;
    int e0 = s * esz, e1 = min(e0 + esz, E);
    for (int e = e0 + threadIdx.x; e < e1; e += 256)
        atomicAdd(&h[col[e] >> 8], 1u);
    __syncthreads();
    for (int b = threadIdx.x; b < NB; b += 256)
        pcnt[(size_t)(set * NB + b) * 64 + s] = (int)h[b];
}

// part: grid = 2 sets x 64 slices. Scatter edges into bucket-ordered eord[] as (r,c) pairs.
// Per-(slice,bucket) positions are contiguous -> coalesced sector writes.
__global__ __launch_bounds__(256) void part(const int* __restrict__ ei1, const int* __restrict__ ei2,
                                            const int* __restrict__ poffs, int2* __restrict__ eord,
                                            int NB, int E1, int E2) {
    __shared__ u32 cur[256];
    int set = blockIdx.x >> 6;
    int s = blockIdx.x & 63;
    const int* rows = set ? ei2 : ei1;
    int E = set ? E2 : E1;
    const int* cols = rows + E;
    for (int b = threadIdx.x; b < NB; b += 256)
        cur[b] = (u32)poffs[(size_t)(set * NB + b) * 64 + s];
    __syncthreads();
    int esz = (E + 63) >> 6;
    int e0 = s * esz, e1 = min(e0 + esz, E);
    for (int e = e0 + threadIdx.x; e < e1; e += 256) {
        int c = cols[e];
        u32 pos = atomicAdd(&cur[c >> 8], 1u);
        eord[pos] = make_int2(rows[e], c);
    }
}

// cnt2: grid = 2 sets x NB buckets. Each block exclusively owns 256 bins: count degrees,
// write degc + dinv (single owner per bin -> plain stores).
__global__ __launch_bounds__(256) void cnt2(const int2* __restrict__ eord,
                                            const int* __restrict__ poffs,
                                            int* __restrict__ degc,
                                            float* __restrict__ d1, float* __restrict__ d2,
                                            int N, int NB) {
    __shared__ u32 cnt[256];
    int set = blockIdx.x >= NB;
    int bucket = set ? blockIdx.x - NB : blockIdx.x;
    cnt[threadIdx.x] = 0;
    __syncthreads();
    int s0 = poffs[(size_t)(set * NB + bucket) * 64];
    int s1 = poffs[(size_t)(set * NB + bucket + 1) * 64];
    for (int j = s0 + threadIdx.x; j < s1; j += 256)
        atomicAdd(&cnt[eord[j].y & 255], 1u);
    __syncthreads();
    int bin = bucket * 256 + threadIdx.x;
    if (bin < N) {
        u32 d = cnt[threadIdx.x];
        degc[set * N + bin] = (int)d;
        float v = d > 0 ? rsqrtf((float)d) : 0.f;
        if (set) d2[bin] = v;
        else d1[bin] = v;
    }
}

// fill2: grid = 2 sets x NB buckets. Exclusive bins -> each bin's entries are one block's
// consecutive stores (write amp ~1x). LDS cursors from starts.
__global__ __launch_bounds__(256) void fill2(const int2* __restrict__ eord,
                                             const int* __restrict__ poffs,
                                             const int* __restrict__ starts,
                                             const float* __restrict__ dinv1,
                                             const float* __restrict__ dinv2,
                                             int2* __restrict__ csr, int N, int NB) {
    __shared__ u32 cur[256];
    int set = blockIdx.x >= NB;
    int bucket = set ? blockIdx.x - NB : blockIdx.x;
    const float* dinv = set ? dinv2 : dinv1;
    int bin = bucket * 256 + threadIdx.x;
    cur[threadIdx.x] = (bin < N) ? (u32)starts[set * N + bin] : 0u;
    __syncthreads();
    int s0 = poffs[(size_t)(set * NB + bucket) * 64];
    int s1 = poffs[(size_t)(set * NB + bucket + 1) * 64];
    for (int j = s0 + threadIdx.x; j < s1; j += 256) {
        int2 e = eord[j];
        int r = e.x, c = e.y;
        u32 pos = atomicAdd(&cur[c & 255], 1u);
        csr[pos] = make_int2(r, __float_as_int(dinv[r] * dinv[c]));
    }
}

// ================= scans (shared by pcnt and degc) =================
__global__ void scan1(const int* __restrict__ deg, int* __restrict__ partial, int n) {
    __shared__ int s[256];
    int i = blockIdx.x * 256 + threadIdx.x;
    s[threadIdx.x] = (i < n) ? deg[i] : 0;
    __syncthreads();
    for (int off = 128; off > 0; off >>= 1) {
        if (threadIdx.x < off) s[threadIdx.x] += s[threadIdx.x + off];
        __syncthreads();
    }
    if (threadIdx.x == 0) partial[blockIdx.x] = s[0];
}

__global__ void scan2(int* __restrict__ partial, int nb, int* __restrict__ starts, int n) {
    __shared__ int s[256];
    __shared__ int carry;
    int t = threadIdx.x;
    if (t == 0) carry = 0;
    __syncthreads();
    for (int c0 = 0; c0 < nb; c0 += 256) {
        int i = c0 + t;
        int v = (i < nb) ? partial[i] : 0;
        s[t] = v;
        __syncthreads();
        for (int off = 1; off < 256; off <<= 1) {
            int u = (t >= off) ? s[t - off] : 0;
            __syncthreads();
            s[t] += u;
            __syncthreads();
        }
        if (i < nb) partial[i] = carry + s[t] - v;   // exclusive
        __syncthreads();
        if (t == 255) carry += s[255];
        __syncthreads();
    }
    if (t == 0) starts[n] = carry;
}

__global__ void scan3(const int* __restrict__ deg, const int* __restrict__ partial,
                      int* __restrict__ starts, int n) {
    __shared__ int s[256];
    int i = blockIdx.x * 256 + threadIdx.x;
    int v = (i < n) ? deg[i] : 0;
    s[threadIdx.x] = v;
    __syncthreads();
    for (int off = 1; off < 256; off <<= 1) {
        int u = (threadIdx.x >= off) ? s[threadIdx.x - off] : 0;
        __syncthreads();
        s[threadIdx.x] += u;
        __syncthreads();
    }
    if (i < n) starts[i] = partial[blockIdx.x] + s[threadIdx.x] - v;
}

// ================= mm_in: R016 = bf16(relu(x@W_in + b_in)); fused readout0 + outacc init =========
__global__ __launch_bounds__(256) void mm_in(const float* __restrict__ A, const float* __restrict__ W,
                                             const float* __restrict__ bias, u16* __restrict__ C16,
                                             const float* __restrict__ Wr0, const float* __restrict__ br0,
                                             const float* __restrict__ br1, const float* __restrict__ br2,
                                             const float* __restrict__ w0, const float* __restrict__ w1,
                                             const float* __restrict__ w2, const float* __restrict__ w3,
                                             const float* __restrict__ c3, float* __restrict__ outacc,
                                             int n) {
    __shared__ float As[64][68];
    __shared__ float Ws[64][68];
    const int tid = threadIdx.x;
    const int r0 = blockIdx.x * 64;

    for (int idx = tid; idx < 64 * 16; idx += 256) {
        int k = idx >> 4, cq = (idx & 15) * 4;
        *(float4*)&Ws[k][cq] = *(const float4*)&W[k * 64 + cq];
    }

    const int tr = (tid >> 4) * 4;
    const int tc = (tid & 15) * 4;
    float4 acc0 = {0,0,0,0}, acc1 = {0,0,0,0}, acc2 = {0,0,0,0}, acc3 = {0,0,0,0};

    __syncthreads();
#pragma unroll
    for (int it = 0; it < 4; ++it) {
        int r = (tid >> 4) + it * 16;
        int cq = (tid & 15) * 4;
        int gr = r0 + r;
        float4 v = {0,0,0,0};
        if (gr < n) v = *(const float4*)&A[(size_t)gr * 64 + cq];
        *(float4*)&As[r][cq] = v;
    }
    __syncthreads();
#pragma unroll
    for (int k = 0; k < 64; k += 4) {
        float4 a0 = *(const float4*)&As[tr + 0][k];
        float4 a1 = *(const float4*)&As[tr + 1][k];
        float4 a2 = *(const float4*)&As[tr + 2][k];
        float4 a3 = *(const float4*)&As[tr + 3][k];
        float4 b0 = *(const float4*)&Ws[k + 0][tc];
        float4 b1 = *(const float4*)&Ws[k + 1][tc];
        float4 b2 = *(const float4*)&Ws[k + 2][tc];
        float4 b3 = *(const float4*)&Ws[k + 3][tc];
#define DK(comp, B)                                                                   \
        acc0.x = fmaf(a0.comp, B.x, acc0.x); acc0.y = fmaf(a0.comp, B.y, acc0.y);     \
        acc0.z = fmaf(a0.comp, B.z, acc0.z); acc0.w = fmaf(a0.comp, B.w, acc0.w);     \
        acc1.x = fmaf(a1.comp, B.x, acc1.x); acc1.y = fmaf(a1.comp, B.y, acc1.y);     \
        acc1.z = fmaf(a1.comp, B.z, acc1.z); acc1.w = fmaf(a1.comp, B.w, acc1.w);     \
        acc2.x = fmaf(a2.comp, B.x, acc2.x); acc2.y = fmaf(a2.comp, B.y, acc2.y);     \
        acc2.z = fmaf(a2.comp, B.z, acc2.z); acc2.w = fmaf(a2.comp, B.w, acc2.w);     \
        acc3.x = fmaf(a3.comp, B.x, acc3.x); acc3.y = fmaf(a3.comp, B.y, acc3.y);     \
        acc3.z = fmaf(a3.comp, B.z, acc3.z); acc3.w = fmaf(a3.comp, B.w, acc3.w);
        DK(x, b0) DK(y, b1) DK(z, b2) DK(w, b3)
#undef DK
    }

    float4 bv = *(const float4*)&bias[tc];
    float4 wr = *(const float4*)&Wr0[tc];
    float4 accs[4] = {acc0, acc1, acc2, acc3};
    float part[4];
#pragma unroll
    for (int i = 0; i < 4; ++i) {
        float4 v = accs[i];
        v.x = fmaxf(v.x + bv.x, 0.f); v.y = fmaxf(v.y + bv.y, 0.f);
        v.z = fmaxf(v.z + bv.z, 0.f); v.w = fmaxf(v.w + bv.w, 0.f);
        int gr = r0 + tr + i;
        if (gr < n) {
            ushort4 o = {f2b(v.x), f2b(v.y), f2b(v.z), f2b(v.w)};
            *(ushort4*)&C16[(size_t)gr * 64 + tc] = o;
        }
        part[i] = v.x * wr.x + v.y * wr.y + v.z * wr.z + v.w * wr.w;
    }
#pragma unroll
    for (int off = 8; off > 0; off >>= 1) {
#pragma unroll
        for (int i = 0; i < 4; ++i) part[i] += __shfl_down(part[i], off);
    }
    if ((tid & 15) == 0) {
        float W0 = w0[0];
        float CONST = W0 * br0[0] + w1[0] * br1[0] + w2[0] * br2[0] + w3[0] * c3[0];
#pragma unroll
        for (int i = 0; i < 4; ++i) {
            int gr = r0 + tr + i;
            if (gr < n) outacc[gr] = W0 * part[i] + CONST;
        }
    }
}

// ================= mmfma2: Y16[:,0:64] = A16@WA, Y16[:,64:128] = A16@WB (MFMA, paired) ============
template <int K>
__global__ __launch_bounds__(256) void mmfma2(const u16* __restrict__ A16,
                                              const float* __restrict__ WA,
                                              const float* __restrict__ WB,
                                              u16* __restrict__ Y16, int n) {
    constexpr int LDA = K + 8;
    __shared__ u16 As[64 * LDA];
    __shared__ u16 WtA[64 * LDA];
    __shared__ u16 WtB[64 * LDA];
    const int tid = threadIdx.x;
    const int r0 = blockIdx.x * 64;

    for (int idx = tid; idx < 64 * K / 8; idx += 256) {
        int r = idx / (K / 8), c8 = idx % (K / 8);
        int gr = r0 + r;
        uint4 v = {0, 0, 0, 0};
        if (gr < n) v = *(const uint4*)&A16[(size_t)gr * K + 8 * c8];
        *(uint4*)&As[r * LDA + 8 * c8] = v;
    }
    for (int idx = tid; idx < 16 * K; idx += 256) {
        int k = idx >> 4;
        int qc = idx & 15;
        float4 a = *(const float4*)&WA[k * 64 + 4 * qc];
        float4 b = *(const float4*)&WB[k * 64 + 4 * qc];
        WtA[(4*qc+0) * LDA + k] = f2b(a.x);
        WtA[(4*qc+1) * LDA + k] = f2b(a.y);
        WtA[(4*qc+2) * LDA + k] = f2b(a.z);
        WtA[(4*qc+3) * LDA + k] = f2b(a.w);
        WtB[(4*qc+0) * LDA + k] = f2b(b.x);
        WtB[(4*qc+1) * LDA + k] = f2b(b.y);
        WtB[(4*qc+2) * LDA + k] = f2b(b.z);
        WtB[(4*qc+3) * LDA + k] = f2b(b.w);
    }
    __syncthreads();

    const int wave = tid >> 6;
    const int lane = tid & 63;
    const int m = lane & 15;
    const int ko = (lane >> 4) * 8;
    floatx4 z4 = {0.f, 0.f, 0.f, 0.f};
    floatx4 accA[4] = {z4, z4, z4, z4};
    floatx4 accB[4] = {z4, z4, z4, z4};

#pragma unroll
    for (int kc = 0; kc < K; kc += 32) {
        shortx8 af = *(shortx8*)&As[(wave * 16 + m) * LDA + kc + ko];
#pragma unroll
        for (int nt = 0; nt < 4; ++nt) {
            shortx8 ba = *(shortx8*)&WtA[(nt * 16 + m) * LDA + kc + ko];
            accA[nt] = __builtin_amdgcn_mfma_f32_16x16x32_bf16(af, ba, accA[nt], 0, 0, 0);
            shortx8 bb = *(shortx8*)&WtB[(nt * 16 + m) * LDA + kc + ko];
            accB[nt] = __builtin_amdgcn_mfma_f32_16x16x32_bf16(af, bb, accB[nt], 0, 0, 0);
        }
    }

    const int rbase = r0 + wave * 16 + (lane >> 4) * 4;
#pragma unroll
    for (int nt = 0; nt < 4; ++nt) {
#pragma unroll
        for (int rg = 0; rg < 4; ++rg) {
            int gr = rbase + rg;
            if (gr < n) {
                Y16[(size_t)gr * 128 + nt * 16 + m] = f2b(accA[nt][rg]);
                Y16[(size_t)gr * 128 + 64 + nt * 16 + m] = f2b(accB[nt][rg]);
            }
        }
    }
}

// ================= mmfma2p: layer-2 mm with fused projections — Y2 never materialized ============
__global__ __launch_bounds__(256) void mmfma2p(const u16* __restrict__ A16,
                                               const float* __restrict__ WA,
                                               const float* __restrict__ WB,
                                               const float* __restrict__ Wr2,
                                               const float* __restrict__ u31,
                                               const float* __restrict__ u32v,
                                               float4* __restrict__ sA,
                                               float4* __restrict__ sB, int n) {
    constexpr int K = 128, LDA = K + 8;
    __shared__ u16 As[64 * LDA];
    __shared__ u16 WtA[64 * LDA];
    __shared__ u16 WtB[64 * LDA];
    const int tid = threadIdx.x;
    const int r0 = blockIdx.x * 64;

    for (int idx = tid; idx < 64 * K / 8; idx += 256) {
        int r = idx / (K / 8), c8 = idx % (K / 8);
        int gr = r0 + r;
        uint4 v = {0, 0, 0, 0};
        if (gr < n) v = *(const uint4*)&A16[(size_t)gr * K + 8 * c8];
        *(uint4*)&As[r * LDA + 8 * c8] = v;
    }
    for (int idx = tid; idx < 16 * K; idx += 256) {
        int k = idx >> 4;
        int qc = idx & 15;
        float4 a = *(const float4*)&WA[k * 64 + 4 * qc];
        float4 b = *(const float4*)&WB[k * 64 + 4 * qc];
        WtA[(4*qc+0) * LDA + k] = f2b(a.x);
        WtA[(4*qc+1) * LDA + k] = f2b(a.y);
        WtA[(4*qc+2) * LDA + k] = f2b(a.z);
        WtA[(4*qc+3) * LDA + k] = f2b(a.w);
        WtB[(4*qc+0) * LDA + k] = f2b(b.x);
        WtB[(4*qc+1) * LDA + k] = f2b(b.y);
        WtB[(4*qc+2) * LDA + k] = f2b(b.z);
        WtB[(4*qc+3) * LDA + k] = f2b(b.w);
    }
    __syncthreads();

    const int wave = tid >> 6;
    const int lane = tid & 63;
    const int m = lane & 15;
    const int ko = (lane >> 4) * 8;
    floatx4 z4 = {0.f, 0.f, 0.f, 0.f};
    floatx4 accA[4] = {z4, z4, z4, z4};
    floatx4 accB[4] = {z4, z4, z4, z4};

#pragma unroll
    for (int kc = 0; kc < K; kc += 32) {
        shortx8 af = *(shortx8*)&As[(wave * 16 + m) * LDA + kc + ko];
#pragma unroll
        for (int nt = 0; nt < 4; ++nt) {
            shortx8 ba = *(shortx8*)&WtA[(nt * 16 + m) * LDA + kc + ko];
            accA[nt] = __builtin_amdgcn_mfma_f32_16x16x32_bf16(af, ba, accA[nt], 0, 0, 0);
            shortx8 bb = *(shortx8*)&WtB[(nt * 16 + m) * LDA + kc + ko];
            accB[nt] = __builtin_amdgcn_mfma_f32_16x16x32_bf16(af, bb, accB[nt], 0, 0, 0);
        }
    }

    float wA[4], wB[4], uA[4], uB[4], vA[4], vB[4];
#pragma unroll
    for (int nt = 0; nt < 4; ++nt) {
        int c = nt * 16 + m;
        wA[nt] = Wr2[c];  wB[nt] = Wr2[64 + c];
        uA[nt] = u31[c];  uB[nt] = u31[64 + c];
        vA[nt] = u32v[c]; vB[nt] = u32v[64 + c];
    }
    const int rbase = r0 + wave * 16 + (lane >> 4) * 4;
#pragma unroll
    for (int rg = 0; rg < 4; ++rg) {
        float pA = 0.f, qA1 = 0.f, qA2 = 0.f, pB = 0.f, qB1 = 0.f, qB2 = 0.f;
#pragma unroll
        for (int nt = 0; nt < 4; ++nt) {
            float a = accA[nt][rg], b = accB[nt][rg];
            pA = fmaf(a, wA[nt], pA); qA1 = fmaf(a, uA[nt], qA1); qA2 = fmaf(a, vA[nt], qA2);
            pB = fmaf(b, wB[nt], pB); qB1 = fmaf(b, uB[nt], qB1); qB2 = fmaf(b, vB[nt], qB2);
        }
#pragma unroll
        for (int off = 8; off > 0; off >>= 1) {
            pA += __shfl_down(pA, off); qA1 += __shfl_down(qA1, off); qA2 += __shfl_down(qA2, off);
            pB += __shfl_down(pB, off); qB1 += __shfl_down(qB1, off); qB2 += __shfl_down(qB2, off);
        }
        int gr = rbase + rg;
        if (m == 0 && gr < n) {
            sA[gr] = make_float4(pA, qA1, qA2, 0.f);
            sB[gr] = make_float4(pB, qB1, qB2, 0.f);
        }
    }
}

// ================= layer-1 gather: P16 = bf16(R1); readout1 partials (plain stores) ===============
__global__ __launch_bounds__(256) void gatherRO(const int* __restrict__ starts,
                                                const int2* __restrict__ csr,
                                                const u16* __restrict__ Y16,
                                                const float* __restrict__ bA,
                                                const float* __restrict__ bB,
                                                u16* __restrict__ P16,
                                                const float* __restrict__ Wr,
                                                float* __restrict__ pr1,
                                                float* __restrict__ pr2, int N) {
    int wave = (blockIdx.x * blockDim.x + threadIdx.x) >> 6;
    int lane = threadIdx.x & 63;
    if (wave >= 2 * N) return;
    int set2 = wave >= N;
    int d = set2 ? wave - N : wave;
    int base = set2 ? N : 0;
    int yoff = set2 ? 64 : 0;
    int q = lane >> 4;
    int m = lane & 15;

    int s0 = __builtin_amdgcn_readfirstlane(starts[base + d]);
    int s1 = __builtin_amdgcn_readfirstlane(starts[base + d + 1]);

    float a0 = 0.f, a1 = 0.f, a2 = 0.f, a3 = 0.f;
    int j = s0;
#define GEDGE(EXPR)                                                                    \
    {                                                                                  \
        int2 e = (EXPR);                                                               \
        uint2 y = *(const uint2*)&Y16[(size_t)e.x * 128 + yoff + 4 * m];               \
        float w = __int_as_float(e.y);                                                 \
        a0 = fmaf(w, b2f((u16)y.x), a0); a1 = fmaf(w, b2f((u16)(y.x >> 16)), a1);      \
        a2 = fmaf(w, b2f((u16)y.y), a2); a3 = fmaf(w, b2f((u16)(y.y >> 16)), a3);      \
    }
    for (; j + 16 <= s1; j += 16) {
        int2 e0 = csr[j + q];
        int2 e1 = csr[j + 4 + q];
        int2 e2 = csr[j + 8 + q];
        int2 e3 = csr[j + 12 + q];
        uint2 ya = *(const uint2*)&Y16[(size_t)e0.x * 128 + yoff + 4 * m];
        uint2 yb = *(const uint2*)&Y16[(size_t)e1.x * 128 + yoff + 4 * m];
        uint2 yc = *(const uint2*)&Y16[(size_t)e2.x * 128 + yoff + 4 * m];
        uint2 yd = *(const uint2*)&Y16[(size_t)e3.x * 128 + yoff + 4 * m];
        float w0 = __int_as_float(e0.y), w1 = __int_as_float(e1.y);
        float w2 = __int_as_float(e2.y), w3 = __int_as_float(e3.y);
        a0 = fmaf(w0, b2f((u16)ya.x), a0); a1 = fmaf(w0, b2f((u16)(ya.x >> 16)), a1);
        a2 = fmaf(w0, b2f((u16)ya.y), a2); a3 = fmaf(w0, b2f((u16)(ya.y >> 16)), a3);
        a0 = fmaf(w1, b2f((u16)yb.x), a0); a1 = fmaf(w1, b2f((u16)(yb.x >> 16)), a1);
        a2 = fmaf(w1, b2f((u16)yb.y), a2); a3 = fmaf(w1, b2f((u16)(yb.y >> 16)), a3);
        a0 = fmaf(w2, b2f((u16)yc.x), a0); a1 = fmaf(w2, b2f((u16)(yc.x >> 16)), a1);
        a2 = fmaf(w2, b2f((u16)yc.y), a2); a3 = fmaf(w2, b2f((u16)(yc.y >> 16)), a3);
        a0 = fmaf(w3, b2f((u16)yd.x), a0); a1 = fmaf(w3, b2f((u16)(yd.x >> 16)), a1);
        a2 = fmaf(w3, b2f((u16)yd.y), a2); a3 = fmaf(w3, b2f((u16)(yd.y >> 16)), a3);
    }
    if (j + 8 <= s1) {
        GEDGE(csr[j + q]) GEDGE(csr[j + 4 + q])
        j += 8;
    }
    if (j + 4 <= s1) {
        GEDGE(csr[j + q])
        j += 4;
    }
    if (j + q < s1) GEDGE(csr[j + q])
#undef GEDGE
    a0 += __shfl_down(a0, 32); a1 += __shfl_down(a1, 32);
    a2 += __shfl_down(a2, 32); a3 += __shfl_down(a3, 32);
    a0 += __shfl_down(a0, 16); a1 += __shfl_down(a1, 16);
    a2 += __shfl_down(a2, 16); a3 += __shfl_down(a3, 16);

    if (q == 0) {
        float4 bv = *(const float4*)&(set2 ? bB : bA)[4 * m];
        float v0 = a0 + bv.x, v1 = a1 + bv.y, v2 = a2 + bv.z, v3 = a3 + bv.w;
        ushort4 o = {f2b(v0), f2b(v1), f2b(v2), f2b(v3)};
        *(ushort4*)&P16[(size_t)d * 128 + yoff + 4 * m] = o;
        float4 wr = *(const float4*)&Wr[yoff + 4 * m];
        float p = v0 * wr.x + v1 * wr.y + v2 * wr.z + v3 * wr.w;
#pragma unroll
        for (int off = 8; off > 0; off >>= 1) p += __shfl_down(p, off);
        if (m == 0) {
            if (set2) pr2[d] = p;
            else pr1[d] = p;
        }
    }
}

// ================= gatherS: scalar aggregation for readout2 + z; exclusive dest => no atomics =====
__global__ __launch_bounds__(256) void gatherS(const int* __restrict__ starts,
                                               const int2* __restrict__ csr,
                                               const float4* __restrict__ sA,
                                               const float4* __restrict__ sB,
                                               const float* __restrict__ pr1,
                                               const float* __restrict__ pr2,
                                               const float* __restrict__ w1,
                                               const float* __restrict__ w2,
                                               const float* __restrict__ w3,
                                               const float* __restrict__ c2v,
                                               float* __restrict__ outacc,
                                               float* __restrict__ z1, float* __restrict__ z2, int N) {
    int d = (blockIdx.x * blockDim.x + threadIdx.x) >> 6;
    int lane = threadIdx.x & 63;
    if (d >= N) return;
    int a0 = __builtin_amdgcn_readfirstlane(starts[d]);
    int a1 = __builtin_amdgcn_readfirstlane(starts[d + 1]);
    int b0 = __builtin_amdgcn_readfirstlane(starts[N + d]);
    int b1 = __builtin_amdgcn_readfirstlane(starts[N + d + 1]);
    float p = 0.f, q1 = 0.f, q2 = 0.f;
    for (int j = a0 + lane; j < a1; j += 64) {
        int2 e = csr[j];
        float4 s = sA[e.x];
        float w = __int_as_float(e.y);
        p = fmaf(w, s.x, p); q1 = fmaf(w, s.y, q1); q2 = fmaf(w, s.z, q2);
    }
    for (int j = b0 + lane; j < b1; j += 64) {
        int2 e = csr[j];
        float4 s = sB[e.x];
        float w = __int_as_float(e.y);
        p = fmaf(w, s.x, p); q1 = fmaf(w, s.y, q1); q2 = fmaf(w, s.z, q2);
    }
#pragma unroll
    for (int off = 32; off > 0; off >>= 1) {
        p += __shfl_down(p, off);
        q1 += __shfl_down(q1, off);
        q2 += __shfl_down(q2, off);
    }
    if (lane == 0) {
        float W3 = w3[0];
        outacc[d] += w1[0] * (pr1[d] + pr2[d]) + w2[0] * (p + c2v[0]);
        z1[d] = W3 * (q1 + c2v[1]);
        z2[d] = W3 * (q2 + c2v[2]);
    }
}

// ================= gather3: out[d] = outacc[d] + sum_e1 wt*z1[src] + sum_e2 wt*z2[src] ============
__global__ __launch_bounds__(256) void gather3(const int* __restrict__ starts,
                                               const int2* __restrict__ csr,
                                               const float* __restrict__ z1,
                                               const float* __restrict__ z2,
                                               const float* __restrict__ outacc,
                                               float* __restrict__ out, int N) {
    int d = (blockIdx.x * blockDim.x + threadIdx.x) >> 6;
    int lane = threadIdx.x & 63;
    if (d >= N) return;
    int a0 = __builtin_amdgcn_readfirstlane(starts[d]);
    int a1 = __builtin_amdgcn_readfirstlane(starts[d + 1]);
    int b0 = __builtin_amdgcn_readfirstlane(starts[N + d]);
    int b1 = __builtin_amdgcn_readfirstlane(starts[N + d + 1]);
    float acc = 0.f;
    for (int j = a0 + lane; j < a1; j += 64) {
        int2 e = csr[j];
        acc = fmaf(__int_as_float(e.y), z1[e.x], acc);
    }
    for (int j = b0 + lane; j < b1; j += 64) {
        int2 e = csr[j];
        acc = fmaf(__int_as_float(e.y), z2[e.x], acc);
    }
#pragma unroll
    for (int off = 32; off > 0; off >>= 1) acc += __shfl_down(acc, off);
    if (lane == 0) out[d] = outacc[d] + acc;
}

// ================= host =================
static inline char* carve(char*& p, size_t bytes) {
    char* r = p;
    p += (bytes + 255) & ~(size_t)255;
    return r;
}

extern "C" void kernel_launch(void* const* d_in, const int* in_sizes, int n_in,
                              void* d_out, int out_size, void* d_ws, size_t ws_size,
                              hipStream_t stream) {
    const float* x    = (const float*)d_in[0];
    const int*   ei1  = (const int*)d_in[1];
    const int*   ei2  = (const int*)d_in[2];
    const float* W_in = (const float*)d_in[3];  const float* b_in = (const float*)d_in[4];
    const float* W11  = (const float*)d_in[5];
    const float* b11  = (const float*)d_in[6];
    const float* W12  = (const float*)d_in[7];  const float* b12  = (const float*)d_in[8];
    const float* W21  = (const float*)d_in[9];  const float* b21  = (const float*)d_in[10];
    const float* W22  = (const float*)d_in[11]; const float* b22  = (const float*)d_in[12];
    const float* W31  = (const float*)d_in[13]; const float* b31  = (const float*)d_in[14];
    const float* W32  = (const float*)d_in[15]; const float* b32  = (const float*)d_in[16];
    const float* Wr0  = (const float*)d_in[17]; const float* br0  = (const float*)d_in[18];
    const float* Wr1  = (const float*)d_in[19]; const float* br1  = (const float*)d_in[20];
    const float* Wr2  = (const float*)d_in[21]; const float* br2  = (const float*)d_in[22];
    const float* Wr3  = (const float*)d_in[23]; const float* br3  = (const float*)d_in[24];
    const float* w0   = (const float*)d_in[25];
    const float* w1   = (const float*)d_in[26];
    const float* w2   = (const float*)d_in[27];
    const float* w3   = (const float*)d_in[28];

    const int N  = in_sizes[0] / 64;   // 50000
    const int E1 = in_sizes[1] / 2;    // 800000
    const int E2 = in_sizes[2] / 2;
    const int N2 = 2 * N;
    const int NB = (N + 255) >> 8;     // dest buckets per set (256 bins each); 196 for N=50000
    const int NP = 2 * NB * 64;        // pcnt/poffs element count

    char* p = (char*)d_ws;
    float*  dinv1   = (float*)carve(p, (size_t)N * 4);
    float*  dinv2   = (float*)carve(p, (size_t)N * 4);
    int*    pcnt    = (int*)  carve(p, ((size_t)NP + 1) * 4);    // scanned in place -> poffs
    int2*   eord    = (int2*) carve(p, (size_t)(E1 + E2) * 8);   // bucket-partitioned edges
    int*    degc    = (int*)  carve(p, (size_t)N2 * 4);
    int*    starts  = (int*)  carve(p, ((size_t)N2 + 1) * 4);
    int*    partial = (int*)  carve(p, 2048 * 4);
    float*  uws     = (float*)carve(p, 264 * 4);             // u31[128], u32[128], c3[1], c2v[3]
    float*  z       = (float*)carve(p, (size_t)N2 * 4);      // z1 | z2
    float*  pr      = (float*)carve(p, (size_t)N2 * 4);      // pr1 | pr2
    float4* sA      = (float4*)carve(p, (size_t)N * 16);
    float4* sB      = (float4*)carve(p, (size_t)N * 16);
    int2*   csr     = (int2*) carve(p, (size_t)(E1 + E2) * 8);
    u16*    R016    = (u16*)  carve(p, (size_t)N * 64 * 2);
    u16*    P16     = (u16*)  carve(p, (size_t)N * 128 * 2);
    u16*    Y16     = (u16*)  carve(p, (size_t)N * 128 * 2);
    float*  outacc  = (float*)carve(p, (size_t)N * 4);
    float* u31 = uws, *u32v = uws + 128, *c3 = uws + 256, *c2v = uws + 257;
    float* z1 = z, *z2 = z + N;
    float* pr1 = pr, *pr2 = pr + N;
    (void)ws_size; (void)n_in; (void)out_size;

    const int B = 256;
    dim3 blk(B);
    int gMM  = (N + 63) / 64;
    int gGa  = (int)(((long long)N2 * 64 + B - 1) / B);
    int gG3  = (int)(((long long)N * 64 + B - 1) / B);
    int nbP  = (NP + 255) / 256;       // scan blocks for pcnt
    int nbD  = (N2 + 255) / 256;       // scan blocks for degc

    // ---- CSR build: radix 2-phase counting sort + u-precompute ----
    uprep<<<1, 128, 0, stream>>>(W31, W32, b31, b32, Wr3, br3, Wr2, b21, b22,
                                 u31, u32v, c3, c2v);
    hist256<<<2 * 64, blk, 0, stream>>>(ei1, ei2, pcnt, NB, E1, E2);
    scan1<<<nbP, blk, 0, stream>>>(pcnt, partial, NP);
    scan2<<<1, 256, 0, stream>>>(partial, nbP, pcnt, NP);
    scan3<<<nbP, blk, 0, stream>>>(pcnt, partial, pcnt, NP);   // in-place exclusive scan
    part<<<2 * 64, blk, 0, stream>>>(ei1, ei2, pcnt, eord, NB, E1, E2);
    cnt2<<<2 * NB, blk, 0, stream>>>(eord, pcnt, degc, dinv1, dinv2, N, NB);
    scan1<<<nbD, blk, 0, stream>>>(degc, partial, N2);
    scan2<<<1, 256, 0, stream>>>(partial, nbD, starts, N2);
    scan3<<<nbD, blk, 0, stream>>>(degc, partial, starts, N2);
    fill2<<<2 * NB, blk, 0, stream>>>(eord, pcnt, starts, dinv1, dinv2, csr, N, NB);

    // ---- R016 = bf16(relu(x @ W_in + b_in)); outacc = w0*readout0 + CONST ----
    mm_in<<<gMM, blk, 0, stream>>>(x, W_in, b_in, R016, Wr0, br0, br1, br2,
                                   w0, w1, w2, w3, c3, outacc, N);

    // ---- layer 1: Y = R0@[W11|W12]; gather -> P16 (bf16 R1) + readout1 partials ----
    mmfma2<64><<<gMM, blk, 0, stream>>>(R016, W11, W12, Y16, N);
    gatherRO<<<gGa, blk, 0, stream>>>(starts, csr, Y16, b11, b12, P16, Wr1, pr1, pr2, N);

    // ---- layer 2: fused mm + projections (Y2 never materialized) ----
    mmfma2p<<<gMM, blk, 0, stream>>>(P16, W21, W22, Wr2, u31, u32v, sA, sB, N);
    gatherS<<<gG3, blk, 0, stream>>>(starts, csr, sA, sB, pr1, pr2, w1, w2, w3, c2v,
                                     outacc, z1, z2, N);

    // ---- layer 3 (algebraic shortcut): out = outacc + gather(z) ----
    gather3<<<gG3, blk, 0, stream>>>(starts, csr, z1, z2, outacc, (float*)d_out, N);
}

// Round 16
// 291.623 us; speedup vs baseline: 1.6986x; 1.1728x over previous
//
#include <hip/hip_runtime.h>
#include <cstdint>
#include <cstddef>

typedef unsigned short u16;
typedef unsigned int u32;
typedef __attribute__((ext_vector_type(8))) short shortx8;
typedef __attribute__((ext_vector_type(4))) float floatx4;

__device__ __forceinline__ u16 f2b(float f) {
    u32 b = __float_as_uint(f);
    b += 0x7fffu + ((b >> 16) & 1u);   // RNE
    return (u16)(b >> 16);
}
__device__ __forceinline__ float b2f(u16 u) {
    return __uint_as_float(((u32)u) << 16);
}
__device__ __forceinline__ float b2f_lo(u32 y) { return __uint_as_float(y << 16); }
__device__ __forceinline__ float b2f_hi(u32 y) { return __uint_as_float(y & 0xffff0000u); }

// ================= u-precompute =================
__global__ void uprep(const float* __restrict__ W31, const float* __restrict__ W32,
                      const float* __restrict__ b31, const float* __restrict__ b32,
                      const float* __restrict__ Wr3, const float* __restrict__ br3,
                      const float* __restrict__ Wr2, const float* __restrict__ b21,
                      const float* __restrict__ b22,
                      float* __restrict__ u31, float* __restrict__ u32,
                      float* __restrict__ c3, float* __restrict__ c2v) {
    __shared__ float s[64];
    int t = threadIdx.x;
    if (t < 128) {
        float a = 0.f, b = 0.f;
        for (int c = 0; c < 64; ++c) {
            a = fmaf(W31[t * 64 + c], Wr3[c], a);
            b = fmaf(W32[t * 64 + c], Wr3[64 + c], b);
        }
        u31[t] = a;
        u32[t] = b;
    }
    if (t < 64) s[t] = b31[t] * Wr3[t] + b32[t] * Wr3[64 + t];
    __syncthreads();
    if (t < 32) s[t] += s[t + 32];
    __syncthreads();
    if (t == 0) {
        float acc = 0.f;
        for (int i = 0; i < 32; ++i) acc += s[i];
        c3[0] = acc + br3[0];
    }
    __syncthreads();
    if (t < 64) {
        float t0 = b21[t] * Wr2[t] + b22[t] * Wr2[64 + t];
        float t1 = b21[t] * u31[t] + b22[t] * u31[64 + t];
        float t2 = b21[t] * u32[t] + b22[t] * u32[64 + t];
#pragma unroll
        for (int off = 32; off > 0; off >>= 1) {
            t0 += __shfl_down(t0, off);
            t1 += __shfl_down(t1, off);
            t2 += __shfl_down(t2, off);
        }
        if (t == 0) { c2v[0] = t0; c2v[1] = t1; c2v[2] = t2; }
    }
}

// ================= CSR build — radix counting sort, 256 slices, 128-bin buckets =================
// histB: grid = 2 sets x 256 slices. Per-(slice,bucket) counts -> pcnt[(set*NB+b)*256 + s].
__global__ __launch_bounds__(256) void histB(const int* __restrict__ ei1, const int* __restrict__ ei2,
                                             int* __restrict__ pcnt, int NB, int E1, int E2) {
    __shared__ u32 h[512];
    int set = blockIdx.x >> 8;
    int s = blockIdx.x & 255;
    const int* col = set ? ei2 + E2 : ei1 + E1;
    int E = set ? E2 : E1;
    for (int i = threadIdx.x; i < NB; i += 256) h[i] = 0;
    __syncthreads();
    int esz = (E + 255) >> 8;
    int e0 = s * esz, e1 = min(e0 + esz, E);
    for (int e = e0 + threadIdx.x; e < e1; e += 256)
        atomicAdd(&h[col[e] >> 7], 1u);
    __syncthreads();
    for (int b = threadIdx.x; b < NB; b += 256)
        pcnt[(size_t)(set * NB + b) * 256 + s] = (int)h[b];
}

// part: grid = 2 sets x 256 slices. Scatter edges bucket-ordered into eord[] (coalesced runs).
__global__ __launch_bounds__(256) void part(const int* __restrict__ ei1, const int* __restrict__ ei2,
                                            const int* __restrict__ poffs, int2* __restrict__ eord,
                                            int NB, int E1, int E2) {
    __shared__ u32 cur[512];
    int set = blockIdx.x >> 8;
    int s = blockIdx.x & 255;
    const int* rows = set ? ei2 : ei1;
    int E = set ? E2 : E1;
    const int* cols = rows + E;
    for (int b = threadIdx.x; b < NB; b += 256)
        cur[b] = (u32)poffs[(size_t)(set * NB + b) * 256 + s];
    __syncthreads();
    int esz = (E + 255) >> 8;
    int e0 = s * esz, e1 = min(e0 + esz, E);
    for (int e = e0 + threadIdx.x; e < e1; e += 256) {
        int c = cols[e];
        u32 pos = atomicAdd(&cur[c >> 7], 1u);
        eord[pos] = make_int2(rows[e], c);
    }
}

// cnt2d: grid = 2 sets x NB buckets. Exclusive 128-bin ownership -> dinv via plain stores.
__global__ __launch_bounds__(256) void cnt2d(const int2* __restrict__ eord,
                                             const int* __restrict__ poffs,
                                             float* __restrict__ d1, float* __restrict__ d2,
                                             int N, int NB) {
    __shared__ u32 cnt[128];
    int set = blockIdx.x >= NB;
    int bucket = set ? blockIdx.x - NB : blockIdx.x;
    if (threadIdx.x < 128) cnt[threadIdx.x] = 0;
    __syncthreads();
    int s0 = poffs[(size_t)(set * NB + bucket) * 256];
    int s1 = poffs[(size_t)(set * NB + bucket + 1) * 256];
    for (int j = s0 + threadIdx.x; j < s1; j += 256)
        atomicAdd(&cnt[eord[j].y & 127], 1u);
    __syncthreads();
    if (threadIdx.x < 128) {
        int bin = bucket * 128 + threadIdx.x;
        if (bin < N) {
            u32 d = cnt[threadIdx.x];
            float v = d > 0 ? rsqrtf((float)d) : 0.f;
            if (set) d2[bin] = v;
            else d1[bin] = v;
        }
    }
}

// fill3: grid = 2 sets x NB. Derives starts from s0 + LDS prefix (csr region == eord region),
// writes starts + places csr entries with weights. Zero global atomics; ~1x write amp.
__global__ __launch_bounds__(256) void fill3(const int2* __restrict__ eord,
                                             const int* __restrict__ poffs,
                                             const float* __restrict__ dinv1,
                                             const float* __restrict__ dinv2,
                                             int* __restrict__ starts,
                                             int2* __restrict__ csr, int N, int NB) {
    __shared__ u32 cnt[128];
    __shared__ int sc[128];
    __shared__ u32 cur[128];
    int set = blockIdx.x >= NB;
    int bucket = set ? blockIdx.x - NB : blockIdx.x;
    const float* dinv = set ? dinv2 : dinv1;
    if (threadIdx.x < 128) cnt[threadIdx.x] = 0;
    __syncthreads();
    int s0 = poffs[(size_t)(set * NB + bucket) * 256];
    int s1 = poffs[(size_t)(set * NB + bucket + 1) * 256];
    for (int j = s0 + threadIdx.x; j < s1; j += 256)
        atomicAdd(&cnt[eord[j].y & 127], 1u);
    __syncthreads();
    if (threadIdx.x < 128) sc[threadIdx.x] = (int)cnt[threadIdx.x];
    __syncthreads();
    for (int off = 1; off < 128; off <<= 1) {
        int u = (threadIdx.x < 128 && threadIdx.x >= off) ? sc[threadIdx.x - off] : 0;
        __syncthreads();
        if (threadIdx.x < 128) sc[threadIdx.x] += u;
        __syncthreads();
    }
    if (threadIdx.x < 128) {
        u32 st = (u32)s0 + (u32)(sc[threadIdx.x] - (int)cnt[threadIdx.x]);  // exclusive
        cur[threadIdx.x] = st;
        int bin = bucket * 128 + threadIdx.x;
        if (bin < N) starts[set * N + bin] = (int)st;
    }
    if (blockIdx.x == 2 * NB - 1 && threadIdx.x == 0) starts[2 * N] = s1;
    __syncthreads();
    for (int j = s0 + threadIdx.x; j < s1; j += 256) {
        int2 e = eord[j];
        int r = e.x, c = e.y;
        u32 pos = atomicAdd(&cur[c & 127], 1u);
        csr[pos] = make_int2(r, __float_as_int(dinv[r] * dinv[c]));
    }
}

// ================= scans (pcnt only) =================
__global__ void scan1(const int* __restrict__ deg, int* __restrict__ partial, int n) {
    __shared__ int s[256];
    int i = blockIdx.x * 256 + threadIdx.x;
    s[threadIdx.x] = (i < n) ? deg[i] : 0;
    __syncthreads();
    for (int off = 128; off > 0; off >>= 1) {
        if (threadIdx.x < off) s[threadIdx.x] += s[threadIdx.x + off];
        __syncthreads();
    }
    if (threadIdx.x == 0) partial[blockIdx.x] = s[0];
}

__global__ void scan2(int* __restrict__ partial, int nb, int* __restrict__ starts, int n) {
    __shared__ int s[256];
    __shared__ int carry;
    int t = threadIdx.x;
    if (t == 0) carry = 0;
    __syncthreads();
    for (int c0 = 0; c0 < nb; c0 += 256) {
        int i = c0 + t;
        int v = (i < nb) ? partial[i] : 0;
        s[t] = v;
        __syncthreads();
        for (int off = 1; off < 256; off <<= 1) {
            int u = (t >= off) ? s[t - off] : 0;
            __syncthreads();
            s[t] += u;
            __syncthreads();
        }
        if (i < nb) partial[i] = carry + s[t] - v;   // exclusive
        __syncthreads();
        if (t == 255) carry += s[255];
        __syncthreads();
    }
    if (t == 0) starts[n] = carry;
}

__global__ void scan3(const int* __restrict__ deg, const int* __restrict__ partial,
                      int* __restrict__ starts, int n) {
    __shared__ int s[256];
    int i = blockIdx.x * 256 + threadIdx.x;
    int v = (i < n) ? deg[i] : 0;
    s[threadIdx.x] = v;
    __syncthreads();
    for (int off = 1; off < 256; off <<= 1) {
        int u = (threadIdx.x >= off) ? s[threadIdx.x - off] : 0;
        __syncthreads();
        s[threadIdx.x] += u;
        __syncthreads();
    }
    if (i < n) starts[i] = partial[blockIdx.x] + s[threadIdx.x] - v;
}

// ================= mmfirst: fused input + layer-1 matmuls =================
// R0 = relu(bf16(x)@W_in + b_in) computed via MFMA, held in LDS (never hits global);
// Y16 = R0@[W11|W12]; readout0 + outacc init fused.
__global__ __launch_bounds__(256) void mmfirst(const float* __restrict__ x,
                                               const float* __restrict__ W_in,
                                               const float* __restrict__ b_in,
                                               const float* __restrict__ W11,
                                               const float* __restrict__ W12,
                                               u16* __restrict__ Y16,
                                               const float* __restrict__ Wr0,
                                               const float* __restrict__ br0,
                                               const float* __restrict__ br1,
                                               const float* __restrict__ br2,
                                               const float* __restrict__ w0,
                                               const float* __restrict__ w1,
                                               const float* __restrict__ w2,
                                               const float* __restrict__ w3,
                                               const float* __restrict__ c3,
                                               float* __restrict__ outacc, int n) {
    constexpr int LDA = 72;
    __shared__ u16 As[64 * LDA];    // x (bf16), later overwritten in-place by R0 (wave-private rows)
    __shared__ u16 W0s[64 * LDA];   // W_in^T
    __shared__ u16 W1s[64 * LDA];   // W11^T
    __shared__ u16 W2s[64 * LDA];   // W12^T
    const int tid = threadIdx.x;
    const int r0 = blockIdx.x * 64;

    for (int idx = tid; idx < 64 * 16; idx += 256) {
        int r = idx >> 4, q4 = (idx & 15) * 4;
        int gr = r0 + r;
        float4 v = {0, 0, 0, 0};
        if (gr < n) v = *(const float4*)&x[(size_t)gr * 64 + q4];
        ushort4 o = {f2b(v.x), f2b(v.y), f2b(v.z), f2b(v.w)};
        *(ushort4*)&As[r * LDA + q4] = o;
    }
    for (int idx = tid; idx < 16 * 64; idx += 256) {
        int k = idx >> 4, qc = idx & 15;
        float4 a = *(const float4*)&W_in[k * 64 + 4 * qc];
        float4 b = *(const float4*)&W11[k * 64 + 4 * qc];
        float4 c = *(const float4*)&W12[k * 64 + 4 * qc];
        W0s[(4*qc+0) * LDA + k] = f2b(a.x); W0s[(4*qc+1) * LDA + k] = f2b(a.y);
        W0s[(4*qc+2) * LDA + k] = f2b(a.z); W0s[(4*qc+3) * LDA + k] = f2b(a.w);
        W1s[(4*qc+0) * LDA + k] = f2b(b.x); W1s[(4*qc+1) * LDA + k] = f2b(b.y);
        W1s[(4*qc+2) * LDA + k] = f2b(b.z); W1s[(4*qc+3) * LDA + k] = f2b(b.w);
        W2s[(4*qc+0) * LDA + k] = f2b(c.x); W2s[(4*qc+1) * LDA + k] = f2b(c.y);
        W2s[(4*qc+2) * LDA + k] = f2b(c.z); W2s[(4*qc+3) * LDA + k] = f2b(c.w);
    }
    __syncthreads();

    const int wave = tid >> 6;
    const int lane = tid & 63;
    const int m = lane & 15;
    const int ko = (lane >> 4) * 8;
    floatx4 z4 = {0.f, 0.f, 0.f, 0.f};
    floatx4 accR[4] = {z4, z4, z4, z4};

#pragma unroll
    for (int kc = 0; kc < 64; kc += 32) {
        shortx8 af = *(shortx8*)&As[(wave * 16 + m) * LDA + kc + ko];
#pragma unroll
        for (int nt = 0; nt < 4; ++nt) {
            shortx8 bf = *(shortx8*)&W0s[(nt * 16 + m) * LDA + kc + ko];
            accR[nt] = __builtin_amdgcn_mfma_f32_16x16x32_bf16(af, bf, accR[nt], 0, 0, 0);
        }
    }

    // bias + relu + readout0, then write R0 (bf16) back into As (wave-private rows).
    float bv[4], wr0[4];
#pragma unroll
    for (int nt = 0; nt < 4; ++nt) {
        bv[nt] = b_in[nt * 16 + m];
        wr0[nt] = Wr0[nt * 16 + m];
    }
    const int lrow = wave * 16 + (lane >> 4) * 4;     // local row base
    float W0c = w0[0];
    float CONST = W0c * br0[0] + w1[0] * br1[0] + w2[0] * br2[0] + w3[0] * c3[0];
#pragma unroll
    for (int rg = 0; rg < 4; ++rg) {
        float p = 0.f;
#pragma unroll
        for (int nt = 0; nt < 4; ++nt) {
            float v = fmaxf(accR[nt][rg] + bv[nt], 0.f);
            As[(lrow + rg) * LDA + nt * 16 + m] = f2b(v);
            p = fmaf(v, wr0[nt], p);
        }
#pragma unroll
        for (int off = 8; off > 0; off >>= 1) p += __shfl_down(p, off);
        int gr = r0 + lrow + rg;
        if (m == 0 && gr < n) outacc[gr] = W0c * p + CONST;
    }
    // No barrier needed: each wave reads only its own 16 rows of As below.

    floatx4 accA[4] = {z4, z4, z4, z4};
    floatx4 accB[4] = {z4, z4, z4, z4};
#pragma unroll
    for (int kc = 0; kc < 64; kc += 32) {
        shortx8 af = *(shortx8*)&As[(wave * 16 + m) * LDA + kc + ko];
#pragma unroll
        for (int nt = 0; nt < 4; ++nt) {
            shortx8 ba = *(shortx8*)&W1s[(nt * 16 + m) * LDA + kc + ko];
            accA[nt] = __builtin_amdgcn_mfma_f32_16x16x32_bf16(af, ba, accA[nt], 0, 0, 0);
            shortx8 bb = *(shortx8*)&W2s[(nt * 16 + m) * LDA + kc + ko];
            accB[nt] = __builtin_amdgcn_mfma_f32_16x16x32_bf16(af, bb, accB[nt], 0, 0, 0);
        }
    }

    const int rbase = r0 + lrow;
#pragma unroll
    for (int nt = 0; nt < 4; ++nt) {
#pragma unroll
        for (int rg = 0; rg < 4; ++rg) {
            int gr = rbase + rg;
            if (gr < n) {
                Y16[(size_t)gr * 128 + nt * 16 + m] = f2b(accA[nt][rg]);
                Y16[(size_t)gr * 128 + 64 + nt * 16 + m] = f2b(accB[nt][rg]);
            }
        }
    }
}

// ================= mmfma2p: layer-2 mm with fused projections — Y2 never materialized ============
__global__ __launch_bounds__(256) void mmfma2p(const u16* __restrict__ A16,
                                               const float* __restrict__ WA,
                                               const float* __restrict__ WB,
                                               const float* __restrict__ Wr2,
                                               const float* __restrict__ u31,
                                               const float* __restrict__ u32v,
                                               float4* __restrict__ sA,
                                               float4* __restrict__ sB, int n) {
    constexpr int K = 128, LDA = K + 8;
    __shared__ u16 As[64 * LDA];
    __shared__ u16 WtA[64 * LDA];
    __shared__ u16 WtB[64 * LDA];
    const int tid = threadIdx.x;
    const int r0 = blockIdx.x * 64;

    for (int idx = tid; idx < 64 * K / 8; idx += 256) {
        int r = idx / (K / 8), c8 = idx % (K / 8);
        int gr = r0 + r;
        uint4 v = {0, 0, 0, 0};
        if (gr < n) v = *(const uint4*)&A16[(size_t)gr * K + 8 * c8];
        *(uint4*)&As[r * LDA + 8 * c8] = v;
    }
    for (int idx = tid; idx < 16 * K; idx += 256) {
        int k = idx >> 4;
        int qc = idx & 15;
        float4 a = *(const float4*)&WA[k * 64 + 4 * qc];
        float4 b = *(const float4*)&WB[k * 64 + 4 * qc];
        WtA[(4*qc+0) * LDA + k] = f2b(a.x);
        WtA[(4*qc+1) * LDA + k] = f2b(a.y);
        WtA[(4*qc+2) * LDA + k] = f2b(a.z);
        WtA[(4*qc+3) * LDA + k] = f2b(a.w);
        WtB[(4*qc+0) * LDA + k] = f2b(b.x);
        WtB[(4*qc+1) * LDA + k] = f2b(b.y);
        WtB[(4*qc+2) * LDA + k] = f2b(b.z);
        WtB[(4*qc+3) * LDA + k] = f2b(b.w);
    }
    __syncthreads();

    const int wave = tid >> 6;
    const int lane = tid & 63;
    const int m = lane & 15;
    const int ko = (lane >> 4) * 8;
    floatx4 z4 = {0.f, 0.f, 0.f, 0.f};
    floatx4 accA[4] = {z4, z4, z4, z4};
    floatx4 accB[4] = {z4, z4, z4, z4};

#pragma unroll
    for (int kc = 0; kc < K; kc += 32) {
        shortx8 af = *(shortx8*)&As[(wave * 16 + m) * LDA + kc + ko];
#pragma unroll
        for (int nt = 0; nt < 4; ++nt) {
            shortx8 ba = *(shortx8*)&WtA[(nt * 16 + m) * LDA + kc + ko];
            accA[nt] = __builtin_amdgcn_mfma_f32_16x16x32_bf16(af, ba, accA[nt], 0, 0, 0);
            shortx8 bb = *(shortx8*)&WtB[(nt * 16 + m) * LDA + kc + ko];
            accB[nt] = __builtin_amdgcn_mfma_f32_16x16x32_bf16(af, bb, accB[nt], 0, 0, 0);
        }
    }

    float wA[4], wB[4], uA[4], uB[4], vA[4], vB[4];
#pragma unroll
    for (int nt = 0; nt < 4; ++nt) {
        int c = nt * 16 + m;
        wA[nt] = Wr2[c];  wB[nt] = Wr2[64 + c];
        uA[nt] = u31[c];  uB[nt] = u31[64 + c];
        vA[nt] = u32v[c]; vB[nt] = u32v[64 + c];
    }
    const int rbase = r0 + wave * 16 + (lane >> 4) * 4;
#pragma unroll
    for (int rg = 0; rg < 4; ++rg) {
        float pA = 0.f, qA1 = 0.f, qA2 = 0.f, pB = 0.f, qB1 = 0.f, qB2 = 0.f;
#pragma unroll
        for (int nt = 0; nt < 4; ++nt) {
            float a = accA[nt][rg], b = accB[nt][rg];
            pA = fmaf(a, wA[nt], pA); qA1 = fmaf(a, uA[nt], qA1); qA2 = fmaf(a, vA[nt], qA2);
            pB = fmaf(b, wB[nt], pB); qB1 = fmaf(b, uB[nt], qB1); qB2 = fmaf(b, vB[nt], qB2);
        }
#pragma unroll
        for (int off = 8; off > 0; off >>= 1) {
            pA += __shfl_down(pA, off); qA1 += __shfl_down(qA1, off); qA2 += __shfl_down(qA2, off);
            pB += __shfl_down(pB, off); qB1 += __shfl_down(qB1, off); qB2 += __shfl_down(qB2, off);
        }
        int gr = rbase + rg;
        if (m == 0 && gr < n) {
            sA[gr] = make_float4(pA, qA1, qA2, 0.f);
            sB[gr] = make_float4(pB, qB1, qB2, 0.f);
        }
    }
}

// ================= layer-1 gather: P16 = bf16(R1); readout1 partials (plain stores) ===============
__global__ __launch_bounds__(256) void gatherRO(const int* __restrict__ starts,
                                                const int2* __restrict__ csr,
                                                const u16* __restrict__ Y16,
                                                const float* __restrict__ bA,
                                                const float* __restrict__ bB,
                                                u16* __restrict__ P16,
                                                const float* __restrict__ Wr,
                                                float* __restrict__ pr1,
                                                float* __restrict__ pr2, int N) {
    int wave = (blockIdx.x * blockDim.x + threadIdx.x) >> 6;
    int lane = threadIdx.x & 63;
    if (wave >= 2 * N) return;
    int set2 = wave >= N;
    int d = set2 ? wave - N : wave;
    int base = set2 ? N : 0;
    int yoff = set2 ? 64 : 0;
    int q = lane >> 4;
    int m = lane & 15;

    int s0 = __builtin_amdgcn_readfirstlane(starts[base + d]);
    int s1 = __builtin_amdgcn_readfirstlane(starts[base + d + 1]);

    float a0 = 0.f, a1 = 0.f, a2 = 0.f, a3 = 0.f;
    int j = s0;
#define GEDGE(EXPR)                                                                    \
    {                                                                                  \
        int2 e = (EXPR);                                                               \
        uint2 y = *(const uint2*)&Y16[(size_t)e.x * 128 + yoff + 4 * m];               \
        float w = __int_as_float(e.y);                                                 \
        a0 = fmaf(w, b2f_lo(y.x), a0); a1 = fmaf(w, b2f_hi(y.x), a1);                  \
        a2 = fmaf(w, b2f_lo(y.y), a2); a3 = fmaf(w, b2f_hi(y.y), a3);                  \
    }
    for (; j + 16 <= s1; j += 16) {
        int2 e0 = csr[j + q];
        int2 e1 = csr[j + 4 + q];
        int2 e2 = csr[j + 8 + q];
        int2 e3 = csr[j + 12 + q];
        uint2 ya = *(const uint2*)&Y16[(size_t)e0.x * 128 + yoff + 4 * m];
        uint2 yb = *(const uint2*)&Y16[(size_t)e1.x * 128 + yoff + 4 * m];
        uint2 yc = *(const uint2*)&Y16[(size_t)e2.x * 128 + yoff + 4 * m];
        uint2 yd = *(const uint2*)&Y16[(size_t)e3.x * 128 + yoff + 4 * m];
        float w0 = __int_as_float(e0.y), w1 = __int_as_float(e1.y);
        float w2 = __int_as_float(e2.y), w3 = __int_as_float(e3.y);
        a0 = fmaf(w0, b2f_lo(ya.x), a0); a1 = fmaf(w0, b2f_hi(ya.x), a1);
        a2 = fmaf(w0, b2f_lo(ya.y), a2); a3 = fmaf(w0, b2f_hi(ya.y), a3);
        a0 = fmaf(w1, b2f_lo(yb.x), a0); a1 = fmaf(w1, b2f_hi(yb.x), a1);
        a2 = fmaf(w1, b2f_lo(yb.y), a2); a3 = fmaf(w1, b2f_hi(yb.y), a3);
        a0 = fmaf(w2, b2f_lo(yc.x), a0); a1 = fmaf(w2, b2f_hi(yc.x), a1);
        a2 = fmaf(w2, b2f_lo(yc.y), a2); a3 = fmaf(w2, b2f_hi(yc.y), a3);
        a0 = fmaf(w3, b2f_lo(yd.x), a0); a1 = fmaf(w3, b2f_hi(yd.x), a1);
        a2 = fmaf(w3, b2f_lo(yd.y), a2); a3 = fmaf(w3, b2f_hi(yd.y), a3);
    }
    if (j + 8 <= s1) {
        GEDGE(csr[j + q]) GEDGE(csr[j + 4 + q])
        j += 8;
    }
    if (j + 4 <= s1) {
        GEDGE(csr[j + q])
        j += 4;
    }
    if (j + q < s1) GEDGE(csr[j + q])
#undef GEDGE
    a0 += __shfl_down(a0, 32); a1 += __shfl_down(a1, 32);
    a2 += __shfl_down(a2, 32); a3 += __shfl_down(a3, 32);
    a0 += __shfl_down(a0, 16); a1 += __shfl_down(a1, 16);
    a2 += __shfl_down(a2, 16); a3 += __shfl_down(a3, 16);

    if (q == 0) {
        float4 bv = *(const float4*)&(set2 ? bB : bA)[4 * m];
        float v0 = a0 + bv.x, v1 = a1 + bv.y, v2 = a2 + bv.z, v3 = a3 + bv.w;
        ushort4 o = {f2b(v0), f2b(v1), f2b(v2), f2b(v3)};
        *(ushort4*)&P16[(size_t)d * 128 + yoff + 4 * m] = o;
        float4 wr = *(const float4*)&Wr[yoff + 4 * m];
        float p = v0 * wr.x + v1 * wr.y + v2 * wr.z + v3 * wr.w;
#pragma unroll
        for (int off = 8; off > 0; off >>= 1) p += __shfl_down(p, off);
        if (m == 0) {
            if (set2) pr2[d] = p;
            else pr1[d] = p;
        }
    }
}

// ================= gatherS: scalar aggregation for readout2 + z; exclusive dest => no atomics =====
__global__ __launch_bounds__(256) void gatherS(const int* __restrict__ starts,
                                               const int2* __restrict__ csr,
                                               const float4* __restrict__ sA,
                                               const float4* __restrict__ sB,
                                               const float* __restrict__ pr1,
                                               const float* __restrict__ pr2,
                                               const float* __restrict__ w1,
                                               const float* __restrict__ w2,
                                               const float* __restrict__ w3,
                                               const float* __restrict__ c2v,
                                               float* __restrict__ outacc,
                                               float* __restrict__ z1, float* __restrict__ z2, int N) {
    int d = (blockIdx.x * blockDim.x + threadIdx.x) >> 6;
    int lane = threadIdx.x & 63;
    if (d >= N) return;
    int a0 = __builtin_amdgcn_readfirstlane(starts[d]);
    int a1 = __builtin_amdgcn_readfirstlane(starts[d + 1]);
    int b0 = __builtin_amdgcn_readfirstlane(starts[N + d]);
    int b1 = __builtin_amdgcn_readfirstlane(starts[N + d + 1]);
    float p = 0.f, q1 = 0.f, q2 = 0.f;
    for (int j = a0 + lane; j < a1; j += 64) {
        int2 e = csr[j];
        float4 s = sA[e.x];
        float w = __int_as_float(e.y);
        p = fmaf(w, s.x, p); q1 = fmaf(w, s.y, q1); q2 = fmaf(w, s.z, q2);
    }
    for (int j = b0 + lane; j < b1; j += 64) {
        int2 e = csr[j];
        float4 s = sB[e.x];
        float w = __int_as_float(e.y);
        p = fmaf(w, s.x, p); q1 = fmaf(w, s.y, q1); q2 = fmaf(w, s.z, q2);
    }
#pragma unroll
    for (int off = 32; off > 0; off >>= 1) {
        p += __shfl_down(p, off);
        q1 += __shfl_down(q1, off);
        q2 += __shfl_down(q2, off);
    }
    if (lane == 0) {
        float W3 = w3[0];
        outacc[d] += w1[0] * (pr1[d] + pr2[d]) + w2[0] * (p + c2v[0]);
        z1[d] = W3 * (q1 + c2v[1]);
        z2[d] = W3 * (q2 + c2v[2]);
    }
}

// ================= gather3: out[d] = outacc[d] + sum_e1 wt*z1[src] + sum_e2 wt*z2[src] ============
__global__ __launch_bounds__(256) void gather3(const int* __restrict__ starts,
                                               const int2* __restrict__ csr,
                                               const float* __restrict__ z1,
                                               const float* __restrict__ z2,
                                               const float* __restrict__ outacc,
                                               float* __restrict__ out, int N) {
    int d = (blockIdx.x * blockDim.x + threadIdx.x) >> 6;
    int lane = threadIdx.x & 63;
    if (d >= N) return;
    int a0 = __builtin_amdgcn_readfirstlane(starts[d]);
    int a1 = __builtin_amdgcn_readfirstlane(starts[d + 1]);
    int b0 = __builtin_amdgcn_readfirstlane(starts[N + d]);
    int b1 = __builtin_amdgcn_readfirstlane(starts[N + d + 1]);
    float acc = 0.f;
    for (int j = a0 + lane; j < a1; j += 64) {
        int2 e = csr[j];
        acc = fmaf(__int_as_float(e.y), z1[e.x], acc);
    }
    for (int j = b0 + lane; j < b1; j += 64) {
        int2 e = csr[j];
        acc = fmaf(__int_as_float(e.y), z2[e.x], acc);
    }
#pragma unroll
    for (int off = 32; off > 0; off >>= 1) acc += __shfl_down(acc, off);
    if (lane == 0) out[d] = outacc[d] + acc;
}

// ================= host =================
static inline char* carve(char*& p, size_t bytes) {
    char* r = p;
    p += (bytes + 255) & ~(size_t)255;
    return r;
}

extern "C" void kernel_launch(void* const* d_in, const int* in_sizes, int n_in,
                              void* d_out, int out_size, void* d_ws, size_t ws_size,
                              hipStream_t stream) {
    const float* x    = (const float*)d_in[0];
    const int*   ei1  = (const int*)d_in[1];
    const int*   ei2  = (const int*)d_in[2];
    const float* W_in = (const float*)d_in[3];  const float* b_in = (const float*)d_in[4];
    const float* W11  = (const float*)d_in[5];
    const float* b11  = (const float*)d_in[6];
    const float* W12  = (const float*)d_in[7];  const float* b12  = (const float*)d_in[8];
    const float* W21  = (const float*)d_in[9];  const float* b21  = (const float*)d_in[10];
    const float* W22  = (const float*)d_in[11]; const float* b22  = (const float*)d_in[12];
    const float* W31  = (const float*)d_in[13]; const float* b31  = (const float*)d_in[14];
    const float* W32  = (const float*)d_in[15]; const float* b32  = (const float*)d_in[16];
    const float* Wr0  = (const float*)d_in[17]; const float* br0  = (const float*)d_in[18];
    const float* Wr1  = (const float*)d_in[19]; const float* br1  = (const float*)d_in[20];
    const float* Wr2  = (const float*)d_in[21]; const float* br2  = (const float*)d_in[22];
    const float* Wr3  = (const float*)d_in[23]; const float* br3  = (const float*)d_in[24];
    const float* w0   = (const float*)d_in[25];
    const float* w1   = (const float*)d_in[26];
    const float* w2   = (const float*)d_in[27];
    const float* w3   = (const float*)d_in[28];

    const int N  = in_sizes[0] / 64;   // 50000
    const int E1 = in_sizes[1] / 2;    // 800000
    const int E2 = in_sizes[2] / 2;
    const int N2 = 2 * N;
    const int NB = (N + 127) >> 7;     // 128-bin buckets per set (391 for N=50000)
    const int NP = 2 * NB * 256;       // pcnt element count (slices = 256)

    char* p = (char*)d_ws;
    float*  dinv1   = (float*)carve(p, (size_t)N * 4);
    float*  dinv2   = (float*)carve(p, (size_t)N * 4);
    int*    pcnt    = (int*)  carve(p, ((size_t)NP + 1) * 4);    // scanned in place -> poffs
    int2*   eord    = (int2*) carve(p, (size_t)(E1 + E2) * 8);   // bucket-partitioned edges
    int*    starts  = (int*)  carve(p, ((size_t)N2 + 1) * 4);
    int*    partial = (int*)  carve(p, 2048 * 4);
    float*  uws     = (float*)carve(p, 264 * 4);             // u31[128], u32[128], c3[1], c2v[3]
    float*  z       = (float*)carve(p, (size_t)N2 * 4);      // z1 | z2
    float*  pr      = (float*)carve(p, (size_t)N2 * 4);      // pr1 | pr2
    float4* sA      = (float4*)carve(p, (size_t)N * 16);
    float4* sB      = (float4*)carve(p, (size_t)N * 16);
    int2*   csr     = (int2*) carve(p, (size_t)(E1 + E2) * 8);
    u16*    P16     = (u16*)  carve(p, (size_t)N * 128 * 2);
    u16*    Y16     = (u16*)  carve(p, (size_t)N * 128 * 2);
    float*  outacc  = (float*)carve(p, (size_t)N * 4);
    float* u31 = uws, *u32v = uws + 128, *c3 = uws + 256, *c2v = uws + 257;
    float* z1 = z, *z2 = z + N;
    float* pr1 = pr, *pr2 = pr + N;
    (void)ws_size; (void)n_in; (void)out_size;

    const int B = 256;
    dim3 blk(B);
    int gMM  = (N + 63) / 64;
    int gGa  = (int)(((long long)N2 * 64 + B - 1) / B);
    int gG3  = (int)(((long long)N * 64 + B - 1) / B);
    int nbP  = (NP + 255) / 256;

    // ---- CSR build: radix counting sort (LDS atomics only) + u-precompute ----
    uprep<<<1, 128, 0, stream>>>(W31, W32, b31, b32, Wr3, br3, Wr2, b21, b22,
                                 u31, u32v, c3, c2v);
    histB<<<2 * 256, blk, 0, stream>>>(ei1, ei2, pcnt, NB, E1, E2);
    scan1<<<nbP, blk, 0, stream>>>(pcnt, partial, NP);
    scan2<<<1, 256, 0, stream>>>(partial, nbP, pcnt, NP);
    scan3<<<nbP, blk, 0, stream>>>(pcnt, partial, pcnt, NP);   // in-place exclusive scan
    part<<<2 * 256, blk, 0, stream>>>(ei1, ei2, pcnt, eord, NB, E1, E2);
    cnt2d<<<2 * NB, blk, 0, stream>>>(eord, pcnt, dinv1, dinv2, N, NB);
    fill3<<<2 * NB, blk, 0, stream>>>(eord, pcnt, dinv1, dinv2, starts, csr, N, NB);

    // ---- fused input+layer-1 mms: R0 never leaves LDS; Y16 + readout0 + outacc ----
    mmfirst<<<gMM, blk, 0, stream>>>(x, W_in, b_in, W11, W12, Y16, Wr0, br0, br1, br2,
                                     w0, w1, w2, w3, c3, outacc, N);
    gatherRO<<<gGa, blk, 0, stream>>>(starts, csr, Y16, b11, b12, P16, Wr1, pr1, pr2, N);

    // ---- layer 2: fused mm + projections (Y2 never materialized) ----
    mmfma2p<<<gMM, blk, 0, stream>>>(P16, W21, W22, Wr2, u31, u32v, sA, sB, N);
    gatherS<<<gG3, blk, 0, stream>>>(starts, csr, sA, sB, pr1, pr2, w1, w2, w3, c2v,
                                     outacc, z1, z2, N);

    // ---- layer 3 (algebraic shortcut): out = outacc + gather(z) ----
    gather3<<<gG3, blk, 0, stream>>>(starts, csr, z1, z2, outacc, (float*)d_out, N);
}

// Round 17
// 288.223 us; speedup vs baseline: 1.7187x; 1.0118x over previous
//
#include <hip/hip_runtime.h>
#include <cstdint>
#include <cstddef>

typedef unsigned short u16;
typedef unsigned int u32;
typedef __attribute__((ext_vector_type(8))) short shortx8;
typedef __attribute__((ext_vector_type(4))) float floatx4;

__device__ __forceinline__ u16 f2b(float f) {
    u32 b = __float_as_uint(f);
    b += 0x7fffu + ((b >> 16) & 1u);   // RNE
    return (u16)(b >> 16);
}
__device__ __forceinline__ float b2f(u16 u) {
    return __uint_as_float(((u32)u) << 16);
}
__device__ __forceinline__ float b2f_lo(u32 y) { return __uint_as_float(y << 16); }
__device__ __forceinline__ float b2f_hi(u32 y) { return __uint_as_float(y & 0xffff0000u); }

// ================= u-precompute =================
__global__ void uprep(const float* __restrict__ W31, const float* __restrict__ W32,
                      const float* __restrict__ b31, const float* __restrict__ b32,
                      const float* __restrict__ Wr3, const float* __restrict__ br3,
                      const float* __restrict__ Wr2, const float* __restrict__ b21,
                      const float* __restrict__ b22,
                      float* __restrict__ u31, float* __restrict__ u32,
                      float* __restrict__ c3, float* __restrict__ c2v) {
    __shared__ float s[64];
    int t = threadIdx.x;
    if (t < 128) {
        float a = 0.f, b = 0.f;
        for (int c = 0; c < 64; ++c) {
            a = fmaf(W31[t * 64 + c], Wr3[c], a);
            b = fmaf(W32[t * 64 + c], Wr3[64 + c], b);
        }
        u31[t] = a;
        u32[t] = b;
    }
    if (t < 64) s[t] = b31[t] * Wr3[t] + b32[t] * Wr3[64 + t];
    __syncthreads();
    if (t < 32) s[t] += s[t + 32];
    __syncthreads();
    if (t == 0) {
        float acc = 0.f;
        for (int i = 0; i < 32; ++i) acc += s[i];
        c3[0] = acc + br3[0];
    }
    __syncthreads();
    if (t < 64) {
        float t0 = b21[t] * Wr2[t] + b22[t] * Wr2[64 + t];
        float t1 = b21[t] * u31[t] + b22[t] * u31[64 + t];
        float t2 = b21[t] * u32[t] + b22[t] * u32[64 + t];
#pragma unroll
        for (int off = 32; off > 0; off >>= 1) {
            t0 += __shfl_down(t0, off);
            t1 += __shfl_down(t1, off);
            t2 += __shfl_down(t2, off);
        }
        if (t == 0) { c2v[0] = t0; c2v[1] = t1; c2v[2] = t2; }
    }
}

// ================= CSR build — radix counting sort, 256 slices, 128-bin buckets =================
// dinv[r] folded into source payloads; csr = u32 src index only; eord = packed (r<<7 | c&127).
__global__ __launch_bounds__(256) void histB(const int* __restrict__ ei1, const int* __restrict__ ei2,
                                             int* __restrict__ pcnt, int NB, int E1, int E2) {
    __shared__ u32 h[512];
    int set = blockIdx.x >> 8;
    int s = blockIdx.x & 255;
    const int* col = set ? ei2 + E2 : ei1 + E1;
    int E = set ? E2 : E1;
    for (int i = threadIdx.x; i < NB; i += 256) h[i] = 0;
    __syncthreads();
    int esz = (E + 255) >> 8;
    int e0 = s * esz, e1 = min(e0 + esz, E);
    for (int e = e0 + threadIdx.x; e < e1; e += 256)
        atomicAdd(&h[col[e] >> 7], 1u);
    __syncthreads();
    for (int b = threadIdx.x; b < NB; b += 256)
        pcnt[(size_t)(set * NB + b) * 256 + s] = (int)h[b];
}

__global__ __launch_bounds__(256) void part(const int* __restrict__ ei1, const int* __restrict__ ei2,
                                            const int* __restrict__ poffs, u32* __restrict__ eord,
                                            int NB, int E1, int E2) {
    __shared__ u32 cur[512];
    int set = blockIdx.x >> 8;
    int s = blockIdx.x & 255;
    const int* rows = set ? ei2 : ei1;
    int E = set ? E2 : E1;
    const int* cols = rows + E;
    for (int b = threadIdx.x; b < NB; b += 256)
        cur[b] = (u32)poffs[(size_t)(set * NB + b) * 256 + s];
    __syncthreads();
    int esz = (E + 255) >> 8;
    int e0 = s * esz, e1 = min(e0 + esz, E);
    for (int e = e0 + threadIdx.x; e < e1; e += 256) {
        int c = cols[e];
        u32 pos = atomicAdd(&cur[c >> 7], 1u);
        eord[pos] = ((u32)rows[e] << 7) | (u32)(c & 127);
    }
}

// fill3: grid = 2 sets x NB. Counts bins (also emits dinv = rsqrt(deg)), derives starts from
// s0 + LDS prefix, places csr src indices. Zero global atomics; ~1x write amp.
__global__ __launch_bounds__(256) void fill3(const u32* __restrict__ eord,
                                             const int* __restrict__ poffs,
                                             int* __restrict__ starts,
                                             u32* __restrict__ csr,
                                             float* __restrict__ d1, float* __restrict__ d2,
                                             int N, int NB) {
    __shared__ u32 cnt[128];
    __shared__ int sc[128];
    __shared__ u32 cur[128];
    int set = blockIdx.x >= NB;
    int bucket = set ? blockIdx.x - NB : blockIdx.x;
    if (threadIdx.x < 128) cnt[threadIdx.x] = 0;
    __syncthreads();
    int s0 = poffs[(size_t)(set * NB + bucket) * 256];
    int s1 = poffs[(size_t)(set * NB + bucket + 1) * 256];
    for (int j = s0 + threadIdx.x; j < s1; j += 256)
        atomicAdd(&cnt[eord[j] & 127], 1u);
    __syncthreads();
    if (threadIdx.x < 128) sc[threadIdx.x] = (int)cnt[threadIdx.x];
    __syncthreads();
    for (int off = 1; off < 128; off <<= 1) {
        int u = (threadIdx.x < 128 && threadIdx.x >= off) ? sc[threadIdx.x - off] : 0;
        __syncthreads();
        if (threadIdx.x < 128) sc[threadIdx.x] += u;
        __syncthreads();
    }
    if (threadIdx.x < 128) {
        u32 st = (u32)s0 + (u32)(sc[threadIdx.x] - (int)cnt[threadIdx.x]);  // exclusive
        cur[threadIdx.x] = st;
        int bin = bucket * 128 + threadIdx.x;
        if (bin < N) {
            starts[set * N + bin] = (int)st;
            u32 d = cnt[threadIdx.x];
            float v = d > 0 ? rsqrtf((float)d) : 0.f;
            if (set) d2[bin] = v;
            else d1[bin] = v;
        }
    }
    if (blockIdx.x == 2 * NB - 1 && threadIdx.x == 0) starts[2 * N] = s1;
    __syncthreads();
    for (int j = s0 + threadIdx.x; j < s1; j += 256) {
        u32 e = eord[j];
        u32 pos = atomicAdd(&cur[e & 127], 1u);
        csr[pos] = e >> 7;
    }
}

// ================= scans (pcnt only) =================
__global__ void scan1(const int* __restrict__ deg, int* __restrict__ partial, int n) {
    __shared__ int s[256];
    int i = blockIdx.x * 256 + threadIdx.x;
    s[threadIdx.x] = (i < n) ? deg[i] : 0;
    __syncthreads();
    for (int off = 128; off > 0; off >>= 1) {
        if (threadIdx.x < off) s[threadIdx.x] += s[threadIdx.x + off];
        __syncthreads();
    }
    if (threadIdx.x == 0) partial[blockIdx.x] = s[0];
}

__global__ void scan2(int* __restrict__ partial, int nb, int* __restrict__ starts, int n) {
    __shared__ int s[256];
    __shared__ int carry;
    int t = threadIdx.x;
    if (t == 0) carry = 0;
    __syncthreads();
    for (int c0 = 0; c0 < nb; c0 += 256) {
        int i = c0 + t;
        int v = (i < nb) ? partial[i] : 0;
        s[t] = v;
        __syncthreads();
        for (int off = 1; off < 256; off <<= 1) {
            int u = (t >= off) ? s[t - off] : 0;
            __syncthreads();
            s[t] += u;
            __syncthreads();
        }
        if (i < nb) partial[i] = carry + s[t] - v;   // exclusive
        __syncthreads();
        if (t == 255) carry += s[255];
        __syncthreads();
    }
    if (t == 0) starts[n] = carry;
}

__global__ void scan3(const int* __restrict__ deg, const int* __restrict__ partial,
                      int* __restrict__ starts, int n) {
    __shared__ int s[256];
    int i = blockIdx.x * 256 + threadIdx.x;
    int v = (i < n) ? deg[i] : 0;
    s[threadIdx.x] = v;
    __syncthreads();
    for (int off = 1; off < 256; off <<= 1) {
        int u = (threadIdx.x >= off) ? s[threadIdx.x - off] : 0;
        __syncthreads();
        s[threadIdx.x] += u;
        __syncthreads();
    }
    if (i < n) starts[i] = partial[blockIdx.x] + s[threadIdx.x] - v;
}

// ================= mmfirst: fused input + layer-1 matmuls; Y16 pre-scaled by dinv[r] =============
__global__ __launch_bounds__(256) void mmfirst(const float* __restrict__ x,
                                               const float* __restrict__ W_in,
                                               const float* __restrict__ b_in,
                                               const float* __restrict__ W11,
                                               const float* __restrict__ W12,
                                               u16* __restrict__ Y16,
                                               const float* __restrict__ dinv1,
                                               const float* __restrict__ dinv2,
                                               const float* __restrict__ Wr0,
                                               const float* __restrict__ br0,
                                               const float* __restrict__ br1,
                                               const float* __restrict__ br2,
                                               const float* __restrict__ w0,
                                               const float* __restrict__ w1,
                                               const float* __restrict__ w2,
                                               const float* __restrict__ w3,
                                               const float* __restrict__ c3,
                                               float* __restrict__ outacc, int n) {
    constexpr int LDA = 72;
    __shared__ u16 As[64 * LDA];    // x (bf16), later overwritten by R0 (wave-private rows)
    __shared__ u16 W0s[64 * LDA];
    __shared__ u16 W1s[64 * LDA];
    __shared__ u16 W2s[64 * LDA];
    const int tid = threadIdx.x;
    const int r0 = blockIdx.x * 64;

    for (int idx = tid; idx < 64 * 16; idx += 256) {
        int r = idx >> 4, q4 = (idx & 15) * 4;
        int gr = r0 + r;
        float4 v = {0, 0, 0, 0};
        if (gr < n) v = *(const float4*)&x[(size_t)gr * 64 + q4];
        ushort4 o = {f2b(v.x), f2b(v.y), f2b(v.z), f2b(v.w)};
        *(ushort4*)&As[r * LDA + q4] = o;
    }
    for (int idx = tid; idx < 16 * 64; idx += 256) {
        int k = idx >> 4, qc = idx & 15;
        float4 a = *(const float4*)&W_in[k * 64 + 4 * qc];
        float4 b = *(const float4*)&W11[k * 64 + 4 * qc];
        float4 c = *(const float4*)&W12[k * 64 + 4 * qc];
        W0s[(4*qc+0) * LDA + k] = f2b(a.x); W0s[(4*qc+1) * LDA + k] = f2b(a.y);
        W0s[(4*qc+2) * LDA + k] = f2b(a.z); W0s[(4*qc+3) * LDA + k] = f2b(a.w);
        W1s[(4*qc+0) * LDA + k] = f2b(b.x); W1s[(4*qc+1) * LDA + k] = f2b(b.y);
        W1s[(4*qc+2) * LDA + k] = f2b(b.z); W1s[(4*qc+3) * LDA + k] = f2b(b.w);
        W2s[(4*qc+0) * LDA + k] = f2b(c.x); W2s[(4*qc+1) * LDA + k] = f2b(c.y);
        W2s[(4*qc+2) * LDA + k] = f2b(c.z); W2s[(4*qc+3) * LDA + k] = f2b(c.w);
    }
    __syncthreads();

    const int wave = tid >> 6;
    const int lane = tid & 63;
    const int m = lane & 15;
    const int ko = (lane >> 4) * 8;
    floatx4 z4 = {0.f, 0.f, 0.f, 0.f};
    floatx4 accR[4] = {z4, z4, z4, z4};

#pragma unroll
    for (int kc = 0; kc < 64; kc += 32) {
        shortx8 af = *(shortx8*)&As[(wave * 16 + m) * LDA + kc + ko];
#pragma unroll
        for (int nt = 0; nt < 4; ++nt) {
            shortx8 bf = *(shortx8*)&W0s[(nt * 16 + m) * LDA + kc + ko];
            accR[nt] = __builtin_amdgcn_mfma_f32_16x16x32_bf16(af, bf, accR[nt], 0, 0, 0);
        }
    }

    float bv[4], wr0[4];
#pragma unroll
    for (int nt = 0; nt < 4; ++nt) {
        bv[nt] = b_in[nt * 16 + m];
        wr0[nt] = Wr0[nt * 16 + m];
    }
    const int lrow = wave * 16 + (lane >> 4) * 4;
    float W0c = w0[0];
    float CONST = W0c * br0[0] + w1[0] * br1[0] + w2[0] * br2[0] + w3[0] * c3[0];
#pragma unroll
    for (int rg = 0; rg < 4; ++rg) {
        float p = 0.f;
#pragma unroll
        for (int nt = 0; nt < 4; ++nt) {
            float v = fmaxf(accR[nt][rg] + bv[nt], 0.f);
            As[(lrow + rg) * LDA + nt * 16 + m] = f2b(v);
            p = fmaf(v, wr0[nt], p);
        }
#pragma unroll
        for (int off = 8; off > 0; off >>= 1) p += __shfl_down(p, off);
        int gr = r0 + lrow + rg;
        if (m == 0 && gr < n) outacc[gr] = W0c * p + CONST;
    }
    // No barrier needed: each wave reads only its own 16 rows of As below.

    floatx4 accA[4] = {z4, z4, z4, z4};
    floatx4 accB[4] = {z4, z4, z4, z4};
#pragma unroll
    for (int kc = 0; kc < 64; kc += 32) {
        shortx8 af = *(shortx8*)&As[(wave * 16 + m) * LDA + kc + ko];
#pragma unroll
        for (int nt = 0; nt < 4; ++nt) {
            shortx8 ba = *(shortx8*)&W1s[(nt * 16 + m) * LDA + kc + ko];
            accA[nt] = __builtin_amdgcn_mfma_f32_16x16x32_bf16(af, ba, accA[nt], 0, 0, 0);
            shortx8 bb = *(shortx8*)&W2s[(nt * 16 + m) * LDA + kc + ko];
            accB[nt] = __builtin_amdgcn_mfma_f32_16x16x32_bf16(af, bb, accB[nt], 0, 0, 0);
        }
    }

    const int rbase = r0 + lrow;
#pragma unroll
    for (int rg = 0; rg < 4; ++rg) {
        int gr = rbase + rg;
        if (gr < n) {
            float da = dinv1[gr], db = dinv2[gr];
#pragma unroll
            for (int nt = 0; nt < 4; ++nt) {
                Y16[(size_t)gr * 128 + nt * 16 + m] = f2b(da * accA[nt][rg]);
                Y16[(size_t)gr * 128 + 64 + nt * 16 + m] = f2b(db * accB[nt][rg]);
            }
        }
    }
}

// ================= mmfma2p: layer-2 mm with fused projections; sA/sB pre-scaled by dinv[r] =======
__global__ __launch_bounds__(256) void mmfma2p(const u16* __restrict__ A16,
                                               const float* __restrict__ WA,
                                               const float* __restrict__ WB,
                                               const float* __restrict__ Wr2,
                                               const float* __restrict__ u31,
                                               const float* __restrict__ u32v,
                                               const float* __restrict__ dinv1,
                                               const float* __restrict__ dinv2,
                                               float4* __restrict__ sA,
                                               float4* __restrict__ sB, int n) {
    constexpr int K = 128, LDA = K + 8;
    __shared__ u16 As[64 * LDA];
    __shared__ u16 WtA[64 * LDA];
    __shared__ u16 WtB[64 * LDA];
    const int tid = threadIdx.x;
    const int r0 = blockIdx.x * 64;

    for (int idx = tid; idx < 64 * K / 8; idx += 256) {
        int r = idx / (K / 8), c8 = idx % (K / 8);
        int gr = r0 + r;
        uint4 v = {0, 0, 0, 0};
        if (gr < n) v = *(const uint4*)&A16[(size_t)gr * K + 8 * c8];
        *(uint4*)&As[r * LDA + 8 * c8] = v;
    }
    for (int idx = tid; idx < 16 * K; idx += 256) {
        int k = idx >> 4;
        int qc = idx & 15;
        float4 a = *(const float4*)&WA[k * 64 + 4 * qc];
        float4 b = *(const float4*)&WB[k * 64 + 4 * qc];
        WtA[(4*qc+0) * LDA + k] = f2b(a.x);
        WtA[(4*qc+1) * LDA + k] = f2b(a.y);
        WtA[(4*qc+2) * LDA + k] = f2b(a.z);
        WtA[(4*qc+3) * LDA + k] = f2b(a.w);
        WtB[(4*qc+0) * LDA + k] = f2b(b.x);
        WtB[(4*qc+1) * LDA + k] = f2b(b.y);
        WtB[(4*qc+2) * LDA + k] = f2b(b.z);
        WtB[(4*qc+3) * LDA + k] = f2b(b.w);
    }
    __syncthreads();

    const int wave = tid >> 6;
    const int lane = tid & 63;
    const int m = lane & 15;
    const int ko = (lane >> 4) * 8;
    floatx4 z4 = {0.f, 0.f, 0.f, 0.f};
    floatx4 accA[4] = {z4, z4, z4, z4};
    floatx4 accB[4] = {z4, z4, z4, z4};

#pragma unroll
    for (int kc = 0; kc < K; kc += 32) {
        shortx8 af = *(shortx8*)&As[(wave * 16 + m) * LDA + kc + ko];
#pragma unroll
        for (int nt = 0; nt < 4; ++nt) {
            shortx8 ba = *(shortx8*)&WtA[(nt * 16 + m) * LDA + kc + ko];
            accA[nt] = __builtin_amdgcn_mfma_f32_16x16x32_bf16(af, ba, accA[nt], 0, 0, 0);
            shortx8 bb = *(shortx8*)&WtB[(nt * 16 + m) * LDA + kc + ko];
            accB[nt] = __builtin_amdgcn_mfma_f32_16x16x32_bf16(af, bb, accB[nt], 0, 0, 0);
        }
    }

    float wA[4], wB[4], uA[4], uB[4], vA[4], vB[4];
#pragma unroll
    for (int nt = 0; nt < 4; ++nt) {
        int c = nt * 16 + m;
        wA[nt] = Wr2[c];  wB[nt] = Wr2[64 + c];
        uA[nt] = u31[c];  uB[nt] = u31[64 + c];
        vA[nt] = u32v[c]; vB[nt] = u32v[64 + c];
    }
    const int rbase = r0 + wave * 16 + (lane >> 4) * 4;
#pragma unroll
    for (int rg = 0; rg < 4; ++rg) {
        float pA = 0.f, qA1 = 0.f, qA2 = 0.f, pB = 0.f, qB1 = 0.f, qB2 = 0.f;
#pragma unroll
        for (int nt = 0; nt < 4; ++nt) {
            float a = accA[nt][rg], b = accB[nt][rg];
            pA = fmaf(a, wA[nt], pA); qA1 = fmaf(a, uA[nt], qA1); qA2 = fmaf(a, vA[nt], qA2);
            pB = fmaf(b, wB[nt], pB); qB1 = fmaf(b, uB[nt], qB1); qB2 = fmaf(b, vB[nt], qB2);
        }
#pragma unroll
        for (int off = 8; off > 0; off >>= 1) {
            pA += __shfl_down(pA, off); qA1 += __shfl_down(qA1, off); qA2 += __shfl_down(qA2, off);
            pB += __shfl_down(pB, off); qB1 += __shfl_down(qB1, off); qB2 += __shfl_down(qB2, off);
        }
        int gr = rbase + rg;
        if (m == 0 && gr < n) {
            float da = dinv1[gr], db = dinv2[gr];
            sA[gr] = make_float4(da * pA, da * qA1, da * qA2, 0.f);
            sB[gr] = make_float4(db * pB, db * qB1, db * qB2, 0.f);
        }
    }
}

// ================= layer-1 gather: unweighted sums; dinv[d] applied at epilogue ===================
__global__ __launch_bounds__(256) void gatherRO(const int* __restrict__ starts,
                                                const u32* __restrict__ csr,
                                                const u16* __restrict__ Y16,
                                                const float* __restrict__ bA,
                                                const float* __restrict__ bB,
                                                const float* __restrict__ dinv1,
                                                const float* __restrict__ dinv2,
                                                u16* __restrict__ P16,
                                                const float* __restrict__ Wr,
                                                float* __restrict__ pr1,
                                                float* __restrict__ pr2, int N) {
    int wave = (blockIdx.x * blockDim.x + threadIdx.x) >> 6;
    int lane = threadIdx.x & 63;
    if (wave >= 2 * N) return;
    int set2 = wave >= N;
    int d = set2 ? wave - N : wave;
    int base = set2 ? N : 0;
    int yoff = set2 ? 64 : 0;
    int q = lane >> 4;
    int m = lane & 15;

    int s0 = __builtin_amdgcn_readfirstlane(starts[base + d]);
    int s1 = __builtin_amdgcn_readfirstlane(starts[base + d + 1]);

    float a0 = 0.f, a1 = 0.f, a2 = 0.f, a3 = 0.f;
    int j = s0;
#define GEDGE(EXPR)                                                                    \
    {                                                                                  \
        u32 e = (EXPR);                                                                \
        uint2 y = *(const uint2*)&Y16[(size_t)e * 128 + yoff + 4 * m];                 \
        a0 += b2f_lo(y.x); a1 += b2f_hi(y.x);                                          \
        a2 += b2f_lo(y.y); a3 += b2f_hi(y.y);                                          \
    }
    for (; j + 16 <= s1; j += 16) {
        u32 e0 = csr[j + q];
        u32 e1 = csr[j + 4 + q];
        u32 e2 = csr[j + 8 + q];
        u32 e3 = csr[j + 12 + q];
        uint2 ya = *(const uint2*)&Y16[(size_t)e0 * 128 + yoff + 4 * m];
        uint2 yb = *(const uint2*)&Y16[(size_t)e1 * 128 + yoff + 4 * m];
        uint2 yc = *(const uint2*)&Y16[(size_t)e2 * 128 + yoff + 4 * m];
        uint2 yd = *(const uint2*)&Y16[(size_t)e3 * 128 + yoff + 4 * m];
        a0 += b2f_lo(ya.x); a1 += b2f_hi(ya.x); a2 += b2f_lo(ya.y); a3 += b2f_hi(ya.y);
        a0 += b2f_lo(yb.x); a1 += b2f_hi(yb.x); a2 += b2f_lo(yb.y); a3 += b2f_hi(yb.y);
        a0 += b2f_lo(yc.x); a1 += b2f_hi(yc.x); a2 += b2f_lo(yc.y); a3 += b2f_hi(yc.y);
        a0 += b2f_lo(yd.x); a1 += b2f_hi(yd.x); a2 += b2f_lo(yd.y); a3 += b2f_hi(yd.y);
    }
    if (j + 8 <= s1) {
        GEDGE(csr[j + q]) GEDGE(csr[j + 4 + q])
        j += 8;
    }
    if (j + 4 <= s1) {
        GEDGE(csr[j + q])
        j += 4;
    }
    if (j + q < s1) GEDGE(csr[j + q])
#undef GEDGE
    a0 += __shfl_down(a0, 32); a1 += __shfl_down(a1, 32);
    a2 += __shfl_down(a2, 32); a3 += __shfl_down(a3, 32);
    a0 += __shfl_down(a0, 16); a1 += __shfl_down(a1, 16);
    a2 += __shfl_down(a2, 16); a3 += __shfl_down(a3, 16);

    if (q == 0) {
        float dd = set2 ? dinv2[d] : dinv1[d];
        float4 bv = *(const float4*)&(set2 ? bB : bA)[4 * m];
        float v0 = fmaf(dd, a0, bv.x), v1 = fmaf(dd, a1, bv.y);
        float v2 = fmaf(dd, a2, bv.z), v3 = fmaf(dd, a3, bv.w);
        ushort4 o = {f2b(v0), f2b(v1), f2b(v2), f2b(v3)};
        *(ushort4*)&P16[(size_t)d * 128 + yoff + 4 * m] = o;
        float4 wr = *(const float4*)&Wr[yoff + 4 * m];
        float p = v0 * wr.x + v1 * wr.y + v2 * wr.z + v3 * wr.w;
#pragma unroll
        for (int off = 8; off > 0; off >>= 1) p += __shfl_down(p, off);
        if (m == 0) {
            if (set2) pr2[d] = p;
            else pr1[d] = p;
        }
    }
}

// ================= gatherS: unweighted scalar sums; dinv[d] at epilogue; z pre-scaled for next ====
__global__ __launch_bounds__(256) void gatherS(const int* __restrict__ starts,
                                               const u32* __restrict__ csr,
                                               const float4* __restrict__ sA,
                                               const float4* __restrict__ sB,
                                               const float* __restrict__ pr1,
                                               const float* __restrict__ pr2,
                                               const float* __restrict__ dinv1,
                                               const float* __restrict__ dinv2,
                                               const float* __restrict__ w1,
                                               const float* __restrict__ w2,
                                               const float* __restrict__ w3,
                                               const float* __restrict__ c2v,
                                               float* __restrict__ outacc,
                                               float* __restrict__ z1, float* __restrict__ z2, int N) {
    int d = (blockIdx.x * blockDim.x + threadIdx.x) >> 6;
    int lane = threadIdx.x & 63;
    if (d >= N) return;
    int a0 = __builtin_amdgcn_readfirstlane(starts[d]);
    int a1 = __builtin_amdgcn_readfirstlane(starts[d + 1]);
    int b0 = __builtin_amdgcn_readfirstlane(starts[N + d]);
    int b1 = __builtin_amdgcn_readfirstlane(starts[N + d + 1]);
    float pA = 0.f, qA1 = 0.f, qA2 = 0.f, pB = 0.f, qB1 = 0.f, qB2 = 0.f;
    for (int j = a0 + lane; j < a1; j += 64) {
        float4 s = sA[csr[j]];
        pA += s.x; qA1 += s.y; qA2 += s.z;
    }
    for (int j = b0 + lane; j < b1; j += 64) {
        float4 s = sB[csr[j]];
        pB += s.x; qB1 += s.y; qB2 += s.z;
    }
#pragma unroll
    for (int off = 32; off > 0; off >>= 1) {
        pA += __shfl_down(pA, off); qA1 += __shfl_down(qA1, off); qA2 += __shfl_down(qA2, off);
        pB += __shfl_down(pB, off); qB1 += __shfl_down(qB1, off); qB2 += __shfl_down(qB2, off);
    }
    if (lane == 0) {
        float da = dinv1[d], db = dinv2[d];
        float p  = da * pA + db * pB;
        float q1 = da * qA1 + db * qB1;
        float q2 = da * qA2 + db * qB2;
        float W3 = w3[0];
        outacc[d] += w1[0] * (pr1[d] + pr2[d]) + w2[0] * (p + c2v[0]);
        z1[d] = da * (W3 * (q1 + c2v[1]));   // pre-scaled by dinv1 for gather3's source role
        z2[d] = db * (W3 * (q2 + c2v[2]));
    }
}

// ================= gather3: out[d] = outacc[d] + dinv1[d]*sum z1'[src] + dinv2[d]*sum z2'[src] ====
__global__ __launch_bounds__(256) void gather3(const int* __restrict__ starts,
                                               const u32* __restrict__ csr,
                                               const float* __restrict__ z1,
                                               const float* __restrict__ z2,
                                               const float* __restrict__ dinv1,
                                               const float* __restrict__ dinv2,
                                               const float* __restrict__ outacc,
                                               float* __restrict__ out, int N) {
    int d = (blockIdx.x * blockDim.x + threadIdx.x) >> 6;
    int lane = threadIdx.x & 63;
    if (d >= N) return;
    int a0 = __builtin_amdgcn_readfirstlane(starts[d]);
    int a1 = __builtin_amdgcn_readfirstlane(starts[d + 1]);
    int b0 = __builtin_amdgcn_readfirstlane(starts[N + d]);
    int b1 = __builtin_amdgcn_readfirstlane(starts[N + d + 1]);
    float acc1 = 0.f, acc2 = 0.f;
    for (int j = a0 + lane; j < a1; j += 64) acc1 += z1[csr[j]];
    for (int j = b0 + lane; j < b1; j += 64) acc2 += z2[csr[j]];
#pragma unroll
    for (int off = 32; off > 0; off >>= 1) {
        acc1 += __shfl_down(acc1, off);
        acc2 += __shfl_down(acc2, off);
    }
    if (lane == 0) out[d] = outacc[d] + dinv1[d] * acc1 + dinv2[d] * acc2;
}

// ================= host =================
static inline char* carve(char*& p, size_t bytes) {
    char* r = p;
    p += (bytes + 255) & ~(size_t)255;
    return r;
}

extern "C" void kernel_launch(void* const* d_in, const int* in_sizes, int n_in,
                              void* d_out, int out_size, void* d_ws, size_t ws_size,
                              hipStream_t stream) {
    const float* x    = (const float*)d_in[0];
    const int*   ei1  = (const int*)d_in[1];
    const int*   ei2  = (const int*)d_in[2];
    const float* W_in = (const float*)d_in[3];  const float* b_in = (const float*)d_in[4];
    const float* W11  = (const float*)d_in[5];
    const float* b11  = (const float*)d_in[6];
    const float* W12  = (const float*)d_in[7];  const float* b12  = (const float*)d_in[8];
    const float* W21  = (const float*)d_in[9];  const float* b21  = (const float*)d_in[10];
    const float* W22  = (const float*)d_in[11]; const float* b22  = (const float*)d_in[12];
    const float* W31  = (const float*)d_in[13]; const float* b31  = (const float*)d_in[14];
    const float* W32  = (const float*)d_in[15]; const float* b32  = (const float*)d_in[16];
    const float* Wr0  = (const float*)d_in[17]; const float* br0  = (const float*)d_in[18];
    const float* Wr1  = (const float*)d_in[19]; const float* br1  = (const float*)d_in[20];
    const float* Wr2  = (const float*)d_in[21]; const float* br2  = (const float*)d_in[22];
    const float* Wr3  = (const float*)d_in[23]; const float* br3  = (const float*)d_in[24];
    const float* w0   = (const float*)d_in[25];
    const float* w1   = (const float*)d_in[26];
    const float* w2   = (const float*)d_in[27];
    const float* w3   = (const float*)d_in[28];

    const int N  = in_sizes[0] / 64;   // 50000
    const int E1 = in_sizes[1] / 2;    // 800000
    const int E2 = in_sizes[2] / 2;
    const int N2 = 2 * N;
    const int NB = (N + 127) >> 7;     // 128-bin buckets per set
    const int NP = 2 * NB * 256;       // pcnt element count (slices = 256)

    char* p = (char*)d_ws;
    float*  dinv1   = (float*)carve(p, (size_t)N * 4);
    float*  dinv2   = (float*)carve(p, (size_t)N * 4);
    int*    pcnt    = (int*)  carve(p, ((size_t)NP + 1) * 4);    // scanned in place -> poffs
    u32*    eord    = (u32*)  carve(p, (size_t)(E1 + E2) * 4);   // packed (r<<7 | c&127)
    int*    starts  = (int*)  carve(p, ((size_t)N2 + 1) * 4);
    int*    partial = (int*)  carve(p, 2048 * 4);
    float*  uws     = (float*)carve(p, 264 * 4);             // u31[128], u32[128], c3[1], c2v[3]
    float*  z       = (float*)carve(p, (size_t)N2 * 4);      // z1 | z2
    float*  pr      = (float*)carve(p, (size_t)N2 * 4);      // pr1 | pr2
    float4* sA      = (float4*)carve(p, (size_t)N * 16);
    float4* sB      = (float4*)carve(p, (size_t)N * 16);
    u32*    csr     = (u32*)  carve(p, (size_t)(E1 + E2) * 4);   // src index only
    u16*    P16     = (u16*)  carve(p, (size_t)N * 128 * 2);
    u16*    Y16     = (u16*)  carve(p, (size_t)N * 128 * 2);
    float*  outacc  = (float*)carve(p, (size_t)N * 4);
    float* u31 = uws, *u32v = uws + 128, *c3 = uws + 256, *c2v = uws + 257;
    float* z1 = z, *z2 = z + N;
    float* pr1 = pr, *pr2 = pr + N;
    (void)ws_size; (void)n_in; (void)out_size;

    const int B = 256;
    dim3 blk(B);
    int gMM  = (N + 63) / 64;
    int gGa  = (int)(((long long)N2 * 64 + B - 1) / B);
    int gG3  = (int)(((long long)N * 64 + B - 1) / B);
    int nbP  = (NP + 255) / 256;

    // ---- CSR build: radix counting sort (LDS atomics only) + u-precompute ----
    uprep<<<1, 128, 0, stream>>>(W31, W32, b31, b32, Wr3, br3, Wr2, b21, b22,
                                 u31, u32v, c3, c2v);
    histB<<<2 * 256, blk, 0, stream>>>(ei1, ei2, pcnt, NB, E1, E2);
    scan1<<<nbP, blk, 0, stream>>>(pcnt, partial, NP);
    scan2<<<1, 256, 0, stream>>>(partial, nbP, pcnt, NP);
    scan3<<<nbP, blk, 0, stream>>>(pcnt, partial, pcnt, NP);   // in-place exclusive scan
    part<<<2 * 256, blk, 0, stream>>>(ei1, ei2, pcnt, eord, NB, E1, E2);
    fill3<<<2 * NB, blk, 0, stream>>>(eord, pcnt, starts, csr, dinv1, dinv2, N, NB);

    // ---- fused input+layer-1 mms: R0 never leaves LDS; Y16 (dinv-scaled) + readout0 ----
    mmfirst<<<gMM, blk, 0, stream>>>(x, W_in, b_in, W11, W12, Y16, dinv1, dinv2,
                                     Wr0, br0, br1, br2, w0, w1, w2, w3, c3, outacc, N);
    gatherRO<<<gGa, blk, 0, stream>>>(starts, csr, Y16, b11, b12, dinv1, dinv2,
                                      P16, Wr1, pr1, pr2, N);

    // ---- layer 2: fused mm + projections (Y2 never materialized; sA/sB dinv-scaled) ----
    mmfma2p<<<gMM, blk, 0, stream>>>(P16, W21, W22, Wr2, u31, u32v, dinv1, dinv2, sA, sB, N);
    gatherS<<<gG3, blk, 0, stream>>>(starts, csr, sA, sB, pr1, pr2, dinv1, dinv2,
                                     w1, w2, w3, c2v, outacc, z1, z2, N);

    // ---- layer 3 (algebraic shortcut): out = outacc + dinv*gather(z') ----
    gather3<<<gG3, blk, 0, stream>>>(starts, csr, z1, z2, dinv1, dinv2, outacc, (float*)d_out, N);
}